// Round 1
// baseline (6692.535 us; speedup 1.0000x reference)
//
#include <hip/hip_runtime.h>
#include <math.h>

#define H 128

__device__ __forceinline__ float sigf(float x){ return 1.0f/(1.0f + __expf(-x)); }
__device__ __forceinline__ float eluf(float x){ return x > 0.0f ? x : (__expf(x) - 1.0f); }

// ---------------- embed: h = sigmoid(x @ emb_W), 16 nodes/block ----------------
__global__ __launch_bounds__(256) void embed_kernel(
    const float* __restrict__ x, const float* __restrict__ W, float* __restrict__ h_out)
{
  __shared__ float xs[16][129];
  int tid = threadIdx.x;
  int n0 = blockIdx.x * 16;
  for (int idx = tid; idx < 16*128; idx += 256) {
    int n = idx >> 7, k = idx & 127;
    xs[n][k] = x[(size_t)(n0+n)*H + k];
  }
  __syncthreads();
  int n = tid >> 4, c0 = (tid & 15) * 8;
  float acc[8];
  #pragma unroll
  for (int j = 0; j < 8; j++) acc[j] = 0.f;
  for (int k = 0; k < 128; k++) {
    float f = xs[n][k];
    float w[8];
    *(float4*)&w[0] = *(const float4*)&W[k*H + c0];
    *(float4*)&w[4] = *(const float4*)&W[k*H + c0 + 4];
    #pragma unroll
    for (int j = 0; j < 8; j++) acc[j] += f * w[j];
  }
  float o[8];
  #pragma unroll
  for (int j = 0; j < 8; j++) o[j] = sigf(acc[j]);
  float* dst = &h_out[(size_t)(n0+n)*H + c0];
  *(float4*)&dst[0] = *(float4*)&o[0];
  *(float4*)&dst[4] = *(float4*)&o[4];
}

// ---------------- edge kernel: fused fe-build + 4 GEMMs + gating + scatter ----------------
__global__ __launch_bounds__(256) void edge_kernel(
    const float* __restrict__ h_in, float* __restrict__ h_acc,
    const float* __restrict__ ed, const float* __restrict__ cs, const float* __restrict__ pw,
    const float* __restrict__ Wgate, const float* __restrict__ Wmlp,
    const float* __restrict__ W1, const float* __restrict__ W2g, const float* __restrict__ W2,
    const int* __restrict__ src, const int* __restrict__ tgt)
{
  __shared__ float fe[16][385];   // [edge][3H], padded
  __shared__ float csb[16][65];
  __shared__ float pwb[16][65];
  __shared__ int   s_src[16];
  __shared__ int   s_tgt[16];
  __shared__ float s_rcp[16];
  __shared__ float s_msk[16];

  int tid = threadIdx.x;
  int e0 = blockIdx.x * 16;

  if (tid < 16) {
    int e = e0 + tid;
    float r = ed[e];
    s_rcp[tid] = 1.0f / r;
    s_msk[tid] = (r < 8.0f) ? 1.0f : 0.0f;
    s_src[tid] = src[e];
    s_tgt[tid] = tgt[e];
  }
  __syncthreads();

  // build fe = [ni, nj, (ni-nj)/r]
  for (int idx = tid; idx < 16*128; idx += 256) {
    int e = idx >> 7, k = idx & 127;
    float a = h_in[(size_t)s_src[e]*H + k];
    float b = h_in[(size_t)s_tgt[e]*H + k];
    fe[e][k]       = a;
    fe[e][128 + k] = b;
    fe[e][256 + k] = (a - b) * s_rcp[e];
  }
  for (int idx = tid; idx < 16*64; idx += 256) {
    int e = idx >> 6, k = idx & 63;
    csb[e][k] = cs[(size_t)(e0+e)*64 + k];
    pwb[e][k] = pw[(size_t)(e0+e)*64 + k];
  }
  __syncthreads();

  // pw_gate: pwb <- pw * sigmoid(pw @ W2g)
  {
    int e = tid >> 4, k0 = (tid & 15) * 4;
    float a0=0.f, a1=0.f, a2=0.f, a3=0.f;
    for (int m = 0; m < 64; m++) {
      float p = pwb[e][m];
      float4 w = *(const float4*)&W2g[m*64 + k0];
      a0 += p*w.x; a1 += p*w.y; a2 += p*w.z; a3 += p*w.w;
    }
    float v0 = pwb[e][k0+0] * sigf(a0);
    float v1 = pwb[e][k0+1] * sigf(a1);
    float v2 = pwb[e][k0+2] * sigf(a2);
    float v3 = pwb[e][k0+3] * sigf(a3);
    __syncthreads();
    pwb[e][k0+0] = v0; pwb[e][k0+1] = v1; pwb[e][k0+2] = v2; pwb[e][k0+3] = v3;
    __syncthreads();
  }

  // main: per (edge, 8 cols): gate/mlp over 3H=384, z1+z2 over 64
  int e  = tid >> 4;
  int c0 = (tid & 15) * 8;
  float ag[8], am[8], az[8];
  #pragma unroll
  for (int j = 0; j < 8; j++) { ag[j] = 0.f; am[j] = 0.f; az[j] = 0.f; }

  for (int k = 0; k < 384; k++) {
    float f = fe[e][k];
    float wg[8], wm[8];
    *(float4*)&wg[0] = *(const float4*)&Wgate[k*H + c0];
    *(float4*)&wg[4] = *(const float4*)&Wgate[k*H + c0 + 4];
    *(float4*)&wm[0] = *(const float4*)&Wmlp[k*H + c0];
    *(float4*)&wm[4] = *(const float4*)&Wmlp[k*H + c0 + 4];
    #pragma unroll
    for (int j = 0; j < 8; j++) { ag[j] += f * wg[j]; am[j] += f * wm[j]; }
  }
  for (int k = 0; k < 64; k++) {
    float f1 = csb[e][k];
    float f2 = pwb[e][k];
    float w1[8], w2[8];
    *(float4*)&w1[0] = *(const float4*)&W1[k*H + c0];
    *(float4*)&w1[4] = *(const float4*)&W1[k*H + c0 + 4];
    *(float4*)&w2[0] = *(const float4*)&W2[k*H + c0];
    *(float4*)&w2[4] = *(const float4*)&W2[k*H + c0 + 4];
    #pragma unroll
    for (int j = 0; j < 8; j++) az[j] += f1 * w1[j] + f2 * w2[j];
  }

  float msk = s_msk[e];
  if (msk != 0.0f) {
    size_t srow = (size_t)s_src[e]*H + c0;
    #pragma unroll
    for (int j = 0; j < 8; j++) {
      float z = sigf(ag[j]) * eluf(am[j]) * az[j];
      atomicAdd(&h_acc[srow + j], z);
    }
  }
}

// ---------------- node kernel: zp=elu((h@p1)*(h@p2)) -> pooled; h_out=elu(h@psi) ----------------
__global__ __launch_bounds__(256) void node_kernel(
    const float* __restrict__ h_in,
    const float* __restrict__ p1, const float* __restrict__ p2, const float* __restrict__ psiW,
    const int* __restrict__ gidx, float* __restrict__ pooled, float* __restrict__ h_out)
{
  __shared__ float hs[16][129];
  int tid = threadIdx.x;
  int n0 = blockIdx.x * 16;
  for (int idx = tid; idx < 16*128; idx += 256) {
    int n = idx >> 7, k = idx & 127;
    hs[n][k] = h_in[(size_t)(n0+n)*H + k];
  }
  __syncthreads();
  int n = tid >> 4, c0 = (tid & 15) * 8;
  float a1[8], a2[8], a3[8];
  #pragma unroll
  for (int j = 0; j < 8; j++) { a1[j]=0.f; a2[j]=0.f; a3[j]=0.f; }
  for (int k = 0; k < 128; k++) {
    float f = hs[n][k];
    float w1[8], w2[8], w3[8];
    *(float4*)&w1[0] = *(const float4*)&p1[k*H + c0];
    *(float4*)&w1[4] = *(const float4*)&p1[k*H + c0 + 4];
    *(float4*)&w2[0] = *(const float4*)&p2[k*H + c0];
    *(float4*)&w2[4] = *(const float4*)&p2[k*H + c0 + 4];
    *(float4*)&w3[0] = *(const float4*)&psiW[k*H + c0];
    *(float4*)&w3[4] = *(const float4*)&psiW[k*H + c0 + 4];
    #pragma unroll
    for (int j = 0; j < 8; j++) { a1[j] += f*w1[j]; a2[j] += f*w2[j]; a3[j] += f*w3[j]; }
  }
  int g = gidx[n0 + n];
  float ho[8];
  #pragma unroll
  for (int j = 0; j < 8; j++) {
    float zp = eluf(a1[j] * a2[j]);
    atomicAdd(&pooled[g*H + c0 + j], zp);
    ho[j] = eluf(a3[j]);
  }
  float* dst = &h_out[(size_t)(n0+n)*H + c0];
  *(float4*)&dst[0] = *(float4*)&ho[0];
  *(float4*)&dst[4] = *(float4*)&ho[4];
}

// ---------------- final: y = elu(elu(pooled @ lr1) @ lr2) ----------------
__global__ __launch_bounds__(64) void final_kernel(
    const float* __restrict__ pooled, const float* __restrict__ lr1, const float* __restrict__ lr2,
    float* __restrict__ out)
{
  __shared__ float sp[128];
  __shared__ float y1[64];
  int g = blockIdx.x, tid = threadIdx.x;
  sp[tid]      = pooled[g*128 + tid];
  sp[tid + 64] = pooled[g*128 + 64 + tid];
  __syncthreads();
  float acc = 0.f;
  for (int k = 0; k < 128; k++) acc += sp[k] * lr1[k*64 + tid];
  y1[tid] = eluf(acc);
  __syncthreads();
  if (tid < 32) {
    float a2 = 0.f;
    for (int k = 0; k < 64; k++) a2 += y1[k] * lr2[k*32 + tid];
    out[g*32 + tid] = eluf(a2);
  }
}

extern "C" void kernel_launch(void* const* d_in, const int* in_sizes, int n_in,
                              void* d_out, int out_size, void* d_ws, size_t ws_size,
                              hipStream_t stream)
{
  const float* x    = (const float*)d_in[0];
  const float* ed   = (const float*)d_in[1];
  const float* cs   = (const float*)d_in[2];
  const float* pw   = (const float*)d_in[3];
  const float* embW = (const float*)d_in[4];
  const float* Wg   = (const float*)d_in[5];
  const float* Wm   = (const float*)d_in[6];
  const float* W1   = (const float*)d_in[7];
  const float* W2g  = (const float*)d_in[8];
  const float* W2   = (const float*)d_in[9];
  const float* p1   = (const float*)d_in[10];
  const float* p2   = (const float*)d_in[11];
  const float* psiW = (const float*)d_in[12];
  const float* lr1  = (const float*)d_in[13];
  const float* lr2  = (const float*)d_in[14];
  const int* esrc   = (const int*)d_in[15];
  const int* etgt   = (const int*)d_in[16];
  const int* gidx   = (const int*)d_in[17];

  float* h_a    = (float*)d_ws;                 // 10000*128
  float* h_b    = h_a + 10000*128;              // 10000*128
  float* pooled = h_b + 10000*128;              // 100*128

  hipMemsetAsync(pooled, 0, 100*128*sizeof(float), stream);
  embed_kernel<<<625, 256, 0, stream>>>(x, embW, h_a);

  for (int i = 0; i < 3; i++) {
    hipMemcpyAsync(h_b, h_a, (size_t)10000*128*sizeof(float),
                   hipMemcpyDeviceToDevice, stream);
    edge_kernel<<<160000/16, 256, 0, stream>>>(h_a, h_b, ed, cs, pw,
        Wg + i*384*128, Wm + i*384*128, W1 + i*64*128, W2g + i*64*64, W2 + i*64*128,
        esrc, etgt);
    node_kernel<<<625, 256, 0, stream>>>(h_b,
        p1 + i*128*128, p2 + i*128*128, psiW + i*128*128,
        gidx, pooled, h_a);
  }
  final_kernel<<<100, 64, 0, stream>>>(pooled, lr1, lr2, (float*)d_out);
}

// Round 2
// 2459.025 us; speedup vs baseline: 2.7216x; 2.7216x over previous
//
#include <hip/hip_runtime.h>
#include <math.h>

#define H 128

__device__ __forceinline__ float sigf(float x){ return 1.0f/(1.0f + __expf(-x)); }
__device__ __forceinline__ float eluf(float x){ return x > 0.0f ? x : (__expf(x) - 1.0f); }

// ---------------- embed: h = sigmoid(x @ emb_W), 16 nodes/block ----------------
__global__ __launch_bounds__(256) void embed_kernel(
    const float* __restrict__ x, const float* __restrict__ W, float* __restrict__ h_out)
{
  __shared__ float xs[16][129];
  int tid = threadIdx.x;
  int n0 = blockIdx.x * 16;
  for (int idx = tid; idx < 16*128; idx += 256) {
    int n = idx >> 7, k = idx & 127;
    xs[n][k] = x[(size_t)(n0+n)*H + k];
  }
  __syncthreads();
  int n = tid >> 4, c0 = (tid & 15) * 8;
  float acc[8];
  #pragma unroll
  for (int j = 0; j < 8; j++) acc[j] = 0.f;
  for (int k = 0; k < 128; k++) {
    float f = xs[n][k];
    float w[8];
    *(float4*)&w[0] = *(const float4*)&W[k*H + c0];
    *(float4*)&w[4] = *(const float4*)&W[k*H + c0 + 4];
    #pragma unroll
    for (int j = 0; j < 8; j++) acc[j] += f * w[j];
  }
  float o[8];
  #pragma unroll
  for (int j = 0; j < 8; j++) o[j] = sigf(acc[j]);
  float* dst = &h_out[(size_t)(n0+n)*H + c0];
  *(float4*)&dst[0] = *(float4*)&o[0];
  *(float4*)&dst[4] = *(float4*)&o[4];
}

// ---------------- nodeA: pack tables for factored edge GEMM ----------------
// spack[n] = [h@Wg(0:128) | h@Wg(256:384) | h@Wm(0:128) | h@Wm(256:384)]
// tpack[n] = [h@Wg(128:256)| h@Wg(256:384) | h@Wm(128:256)| h@Wm(256:384)]
__global__ __launch_bounds__(256) void nodeA_kernel(
    const float* __restrict__ h, const float* __restrict__ Wg, const float* __restrict__ Wm,
    float* __restrict__ spack, float* __restrict__ tpack)
{
  __shared__ float hs[16][129];
  int tid = threadIdx.x;
  int n0 = blockIdx.x * 16;
  for (int idx = tid; idx < 16*128; idx += 256) {
    int n = idx >> 7, k = idx & 127;
    hs[n][k] = h[(size_t)(n0+n)*H + k];
  }
  __syncthreads();
  int n = tid >> 4, c0 = (tid & 15) * 8;
  float aAg[8], aBg[8], aCg[8], aAm[8], aBm[8], aCm[8];
  #pragma unroll
  for (int j = 0; j < 8; j++) { aAg[j]=0.f; aBg[j]=0.f; aCg[j]=0.f; aAm[j]=0.f; aBm[j]=0.f; aCm[j]=0.f; }
  for (int k = 0; k < 128; k++) {
    float f = hs[n][k];
    float wAg[8], wBg[8], wCg[8], wAm[8], wBm[8], wCm[8];
    *(float4*)&wAg[0] = *(const float4*)&Wg[(      k)*H + c0];
    *(float4*)&wAg[4] = *(const float4*)&Wg[(      k)*H + c0 + 4];
    *(float4*)&wBg[0] = *(const float4*)&Wg[(128 + k)*H + c0];
    *(float4*)&wBg[4] = *(const float4*)&Wg[(128 + k)*H + c0 + 4];
    *(float4*)&wCg[0] = *(const float4*)&Wg[(256 + k)*H + c0];
    *(float4*)&wCg[4] = *(const float4*)&Wg[(256 + k)*H + c0 + 4];
    *(float4*)&wAm[0] = *(const float4*)&Wm[(      k)*H + c0];
    *(float4*)&wAm[4] = *(const float4*)&Wm[(      k)*H + c0 + 4];
    *(float4*)&wBm[0] = *(const float4*)&Wm[(128 + k)*H + c0];
    *(float4*)&wBm[4] = *(const float4*)&Wm[(128 + k)*H + c0 + 4];
    *(float4*)&wCm[0] = *(const float4*)&Wm[(256 + k)*H + c0];
    *(float4*)&wCm[4] = *(const float4*)&Wm[(256 + k)*H + c0 + 4];
    #pragma unroll
    for (int j = 0; j < 8; j++) {
      aAg[j] += f*wAg[j]; aBg[j] += f*wBg[j]; aCg[j] += f*wCg[j];
      aAm[j] += f*wAm[j]; aBm[j] += f*wBm[j]; aCm[j] += f*wCm[j];
    }
  }
  size_t so = (size_t)(n0+n)*512 + c0;
  *(float4*)&spack[so +   0] = *(float4*)&aAg[0]; *(float4*)&spack[so +   4] = *(float4*)&aAg[4];
  *(float4*)&spack[so + 128] = *(float4*)&aCg[0]; *(float4*)&spack[so + 132] = *(float4*)&aCg[4];
  *(float4*)&spack[so + 256] = *(float4*)&aAm[0]; *(float4*)&spack[so + 260] = *(float4*)&aAm[4];
  *(float4*)&spack[so + 384] = *(float4*)&aCm[0]; *(float4*)&spack[so + 388] = *(float4*)&aCm[4];
  *(float4*)&tpack[so +   0] = *(float4*)&aBg[0]; *(float4*)&tpack[so +   4] = *(float4*)&aBg[4];
  *(float4*)&tpack[so + 128] = *(float4*)&aCg[0]; *(float4*)&tpack[so + 132] = *(float4*)&aCg[4];
  *(float4*)&tpack[so + 256] = *(float4*)&aBm[0]; *(float4*)&tpack[so + 260] = *(float4*)&aBm[4];
  *(float4*)&tpack[so + 384] = *(float4*)&aCm[0]; *(float4*)&tpack[so + 388] = *(float4*)&aCm[4];
}

// ---------------- edge kernel: z1/z2 GEMMs + factored gate/mlp combine + scatter ----------------
__global__ __launch_bounds__(256) void edge_kernel(
    float* __restrict__ h_acc,
    const float* __restrict__ ed, const float* __restrict__ cs, const float* __restrict__ pw,
    const float* __restrict__ W1, const float* __restrict__ W2g, const float* __restrict__ W2,
    const int* __restrict__ src, const int* __restrict__ tgt,
    const float* __restrict__ spack, const float* __restrict__ tpack)
{
  __shared__ float csb[64][68];   // [k][e]
  __shared__ float pwb[64][68];   // [k][e]
  __shared__ float pwg[64][68];   // [k][e] gated pw
  __shared__ int   s_src[64];
  __shared__ int   s_tgt[64];
  __shared__ float s_rcp[64];
  __shared__ float s_msk[64];

  int tid = threadIdx.x;
  int e0 = blockIdx.x * 64;

  if (tid < 64) {
    float r = ed[e0 + tid];
    s_rcp[tid] = 1.0f / r;
    s_msk[tid] = (r < 8.0f) ? 1.0f : 0.0f;
    s_src[tid] = src[e0 + tid];
    s_tgt[tid] = tgt[e0 + tid];
  }

  // stage cs, pw transposed to [k][e]
  {
    int e = tid & 63, kq = tid >> 6;   // kq: 0..3, 16 k's each
    const float* csrow = &cs[(size_t)(e0+e)*64 + kq*16];
    const float* pwrow = &pw[(size_t)(e0+e)*64 + kq*16];
    float c4[16], p4[16];
    #pragma unroll
    for (int j = 0; j < 4; j++) {
      *(float4*)&c4[4*j] = *(const float4*)&csrow[4*j];
      *(float4*)&p4[4*j] = *(const float4*)&pwrow[4*j];
    }
    #pragma unroll
    for (int i = 0; i < 16; i++) {
      csb[kq*16 + i][e] = c4[i];
      pwb[kq*16 + i][e] = p4[i];
    }
  }
  __syncthreads();

  // pw_gate: pwg[k][e] = pwb[k][e] * sig(pw@W2g)[e][k]
  {
    int e = tid >> 2, c0 = (tid & 3) * 16;
    float acc[16];
    #pragma unroll
    for (int j = 0; j < 16; j++) acc[j] = 0.f;
    for (int k = 0; k < 64; k++) {
      float p = pwb[k][e];
      float w[16];
      *(float4*)&w[0]  = *(const float4*)&W2g[k*64 + c0];
      *(float4*)&w[4]  = *(const float4*)&W2g[k*64 + c0 + 4];
      *(float4*)&w[8]  = *(const float4*)&W2g[k*64 + c0 + 8];
      *(float4*)&w[12] = *(const float4*)&W2g[k*64 + c0 + 12];
      #pragma unroll
      for (int j = 0; j < 16; j++) acc[j] += p * w[j];
    }
    #pragma unroll
    for (int j = 0; j < 16; j++)
      pwg[c0 + j][e] = pwb[c0 + j][e] * sigf(acc[j]);
  }
  __syncthreads();

  // main: az[e][c] = cs@W1 + pwg@W2 ; thread = 4 edges x 8 cols
  int eg = tid >> 4, cg = tid & 15;
  int eb = eg * 4, c0 = cg * 8;
  float az[4][8];
  #pragma unroll
  for (int e = 0; e < 4; e++)
    #pragma unroll
    for (int j = 0; j < 8; j++) az[e][j] = 0.f;

  #pragma unroll 2
  for (int k = 0; k < 64; k++) {
    float4 cv = *(const float4*)&csb[k][eb];
    float4 pv = *(const float4*)&pwg[k][eb];
    float w1[8], w2[8];
    *(float4*)&w1[0] = *(const float4*)&W1[k*H + c0];
    *(float4*)&w1[4] = *(const float4*)&W1[k*H + c0 + 4];
    *(float4*)&w2[0] = *(const float4*)&W2[k*H + c0];
    *(float4*)&w2[4] = *(const float4*)&W2[k*H + c0 + 4];
    float ce[4] = {cv.x, cv.y, cv.z, cv.w};
    float pe[4] = {pv.x, pv.y, pv.z, pv.w};
    #pragma unroll
    for (int e = 0; e < 4; e++) {
      #pragma unroll
      for (int j = 0; j < 8; j++) az[e][j] += ce[e]*w1[j] + pe[e]*w2[j];
    }
  }

  // epilogue: factored gate/mlp logits via pack gathers, combine, scatter
  #pragma unroll
  for (int e = 0; e < 4; e++) {
    int ee = eb + e;
    float msk = s_msk[ee];
    if (msk == 0.f) continue;
    int sn = s_src[ee];
    int tn = s_tgt[ee];
    float rcp = s_rcp[ee];
    const float* sp = &spack[(size_t)sn*512 + c0];
    const float* tp = &tpack[(size_t)tn*512 + c0];
    float Ags[8], Cgs[8], Ams[8], Cms[8], Bgt[8], Cgt[8], Bmt[8], Cmt[8];
    *(float4*)&Ags[0] = *(const float4*)&sp[  0]; *(float4*)&Ags[4] = *(const float4*)&sp[  4];
    *(float4*)&Cgs[0] = *(const float4*)&sp[128]; *(float4*)&Cgs[4] = *(const float4*)&sp[132];
    *(float4*)&Ams[0] = *(const float4*)&sp[256]; *(float4*)&Ams[4] = *(const float4*)&sp[260];
    *(float4*)&Cms[0] = *(const float4*)&sp[384]; *(float4*)&Cms[4] = *(const float4*)&sp[388];
    *(float4*)&Bgt[0] = *(const float4*)&tp[  0]; *(float4*)&Bgt[4] = *(const float4*)&tp[  4];
    *(float4*)&Cgt[0] = *(const float4*)&tp[128]; *(float4*)&Cgt[4] = *(const float4*)&tp[132];
    *(float4*)&Bmt[0] = *(const float4*)&tp[256]; *(float4*)&Bmt[4] = *(const float4*)&tp[260];
    *(float4*)&Cmt[0] = *(const float4*)&tp[384]; *(float4*)&Cmt[4] = *(const float4*)&tp[388];
    float* dst = &h_acc[(size_t)sn*H + c0];
    #pragma unroll
    for (int j = 0; j < 8; j++) {
      float g = sigf(Ags[j] + Bgt[j] + rcp*(Cgs[j] - Cgt[j]));
      float m = eluf(Ams[j] + Bmt[j] + rcp*(Cms[j] - Cmt[j]));
      atomicAdd(&dst[j], g * m * az[e][j]);
    }
  }
}

// ---------------- node kernel: zp=elu((h@p1)*(h@p2)) -> pooled; h_out=elu(h@psi) ----------------
__global__ __launch_bounds__(256) void node_kernel(
    const float* __restrict__ h_in,
    const float* __restrict__ p1, const float* __restrict__ p2, const float* __restrict__ psiW,
    const int* __restrict__ gidx, float* __restrict__ pooled, float* __restrict__ h_out)
{
  __shared__ float hs[16][129];
  int tid = threadIdx.x;
  int n0 = blockIdx.x * 16;
  for (int idx = tid; idx < 16*128; idx += 256) {
    int n = idx >> 7, k = idx & 127;
    hs[n][k] = h_in[(size_t)(n0+n)*H + k];
  }
  __syncthreads();
  int n = tid >> 4, c0 = (tid & 15) * 8;
  float a1[8], a2[8], a3[8];
  #pragma unroll
  for (int j = 0; j < 8; j++) { a1[j]=0.f; a2[j]=0.f; a3[j]=0.f; }
  for (int k = 0; k < 128; k++) {
    float f = hs[n][k];
    float w1[8], w2[8], w3[8];
    *(float4*)&w1[0] = *(const float4*)&p1[k*H + c0];
    *(float4*)&w1[4] = *(const float4*)&p1[k*H + c0 + 4];
    *(float4*)&w2[0] = *(const float4*)&p2[k*H + c0];
    *(float4*)&w2[4] = *(const float4*)&p2[k*H + c0 + 4];
    *(float4*)&w3[0] = *(const float4*)&psiW[k*H + c0];
    *(float4*)&w3[4] = *(const float4*)&psiW[k*H + c0 + 4];
    #pragma unroll
    for (int j = 0; j < 8; j++) { a1[j] += f*w1[j]; a2[j] += f*w2[j]; a3[j] += f*w3[j]; }
  }
  int g = gidx[n0 + n];
  float ho[8];
  #pragma unroll
  for (int j = 0; j < 8; j++) {
    float zp = eluf(a1[j] * a2[j]);
    atomicAdd(&pooled[g*H + c0 + j], zp);
    ho[j] = eluf(a3[j]);
  }
  float* dst = &h_out[(size_t)(n0+n)*H + c0];
  *(float4*)&dst[0] = *(float4*)&ho[0];
  *(float4*)&dst[4] = *(float4*)&ho[4];
}

// ---------------- final: y = elu(elu(pooled @ lr1) @ lr2) ----------------
__global__ __launch_bounds__(64) void final_kernel(
    const float* __restrict__ pooled, const float* __restrict__ lr1, const float* __restrict__ lr2,
    float* __restrict__ out)
{
  __shared__ float sp[128];
  __shared__ float y1[64];
  int g = blockIdx.x, tid = threadIdx.x;
  sp[tid]      = pooled[g*128 + tid];
  sp[tid + 64] = pooled[g*128 + 64 + tid];
  __syncthreads();
  float acc = 0.f;
  for (int k = 0; k < 128; k++) acc += sp[k] * lr1[k*64 + tid];
  y1[tid] = eluf(acc);
  __syncthreads();
  if (tid < 32) {
    float a2 = 0.f;
    for (int k = 0; k < 64; k++) a2 += y1[k] * lr2[k*32 + tid];
    out[g*32 + tid] = eluf(a2);
  }
}

extern "C" void kernel_launch(void* const* d_in, const int* in_sizes, int n_in,
                              void* d_out, int out_size, void* d_ws, size_t ws_size,
                              hipStream_t stream)
{
  const float* x    = (const float*)d_in[0];
  const float* ed   = (const float*)d_in[1];
  const float* cs   = (const float*)d_in[2];
  const float* pw   = (const float*)d_in[3];
  const float* embW = (const float*)d_in[4];
  const float* Wg   = (const float*)d_in[5];
  const float* Wm   = (const float*)d_in[6];
  const float* W1   = (const float*)d_in[7];
  const float* W2g  = (const float*)d_in[8];
  const float* W2   = (const float*)d_in[9];
  const float* p1   = (const float*)d_in[10];
  const float* p2   = (const float*)d_in[11];
  const float* psiW = (const float*)d_in[12];
  const float* lr1  = (const float*)d_in[13];
  const float* lr2  = (const float*)d_in[14];
  const int* esrc   = (const int*)d_in[15];
  const int* etgt   = (const int*)d_in[16];
  const int* gidx   = (const int*)d_in[17];

  float* h_a    = (float*)d_ws;                 // 10000*128
  float* h_b    = h_a + 10000*128;              // 10000*128
  float* pooled = h_b + 10000*128;              // 100*128
  float* spack  = pooled + 100*128;             // 10000*512
  float* tpack  = spack + 10000*512;            // 10000*512

  hipMemsetAsync(pooled, 0, 100*128*sizeof(float), stream);
  embed_kernel<<<625, 256, 0, stream>>>(x, embW, h_a);

  for (int i = 0; i < 3; i++) {
    nodeA_kernel<<<625, 256, 0, stream>>>(h_a, Wg + i*384*128, Wm + i*384*128, spack, tpack);
    hipMemcpyAsync(h_b, h_a, (size_t)10000*128*sizeof(float),
                   hipMemcpyDeviceToDevice, stream);
    edge_kernel<<<160000/64, 256, 0, stream>>>(h_b, ed, cs, pw,
        W1 + i*64*128, W2g + i*64*64, W2 + i*64*128,
        esrc, etgt, spack, tpack);
    node_kernel<<<625, 256, 0, stream>>>(h_b,
        p1 + i*128*128, p2 + i*128*128, psiW + i*128*128,
        gidx, pooled, h_a);
  }
  final_kernel<<<100, 64, 0, stream>>>(pooled, lr1, lr2, (float*)d_out);
}

// Round 3
// 1859.497 us; speedup vs baseline: 3.5991x; 1.3224x over previous
//
#include <hip/hip_runtime.h>
#include <math.h>

#define H 128
#define N_NODES 10000
#define N_EDGES 160000

__device__ __forceinline__ float sigf(float x){ return 1.0f/(1.0f + __expf(-x)); }
__device__ __forceinline__ float eluf(float x){ return x > 0.0f ? x : (__expf(x) - 1.0f); }

__device__ __forceinline__ unsigned short f2bf(float f){
  unsigned int u = __float_as_uint(f);
  unsigned int r = (u + 0x7fffu + ((u >> 16) & 1u)) >> 16;
  return (unsigned short)r;
}
__device__ __forceinline__ float bf2f(unsigned short s){
  return __uint_as_float(((unsigned int)s) << 16);
}

// ---------------- embed: h = sigmoid(x @ emb_W), 16 nodes/block ----------------
__global__ __launch_bounds__(256) void embed_kernel(
    const float* __restrict__ x, const float* __restrict__ W, float* __restrict__ h_out)
{
  __shared__ float xs[16][129];
  int tid = threadIdx.x;
  int n0 = blockIdx.x * 16;
  for (int idx = tid; idx < 16*128; idx += 256) {
    int n = idx >> 7, k = idx & 127;
    xs[n][k] = x[(size_t)(n0+n)*H + k];
  }
  __syncthreads();
  int n = tid >> 4, c0 = (tid & 15) * 8;
  float acc[8];
  #pragma unroll
  for (int j = 0; j < 8; j++) acc[j] = 0.f;
  for (int k = 0; k < 128; k++) {
    float f = xs[n][k];
    float w[8];
    *(float4*)&w[0] = *(const float4*)&W[k*H + c0];
    *(float4*)&w[4] = *(const float4*)&W[k*H + c0 + 4];
    #pragma unroll
    for (int j = 0; j < 8; j++) acc[j] += f * w[j];
  }
  float o[8];
  #pragma unroll
  for (int j = 0; j < 8; j++) o[j] = sigf(acc[j]);
  float* dst = &h_out[(size_t)(n0+n)*H + c0];
  *(float4*)&dst[0] = *(float4*)&o[0];
  *(float4*)&dst[4] = *(float4*)&o[4];
}

// ---------------- edge sort by src: hist -> scan -> scatter ----------------
__global__ __launch_bounds__(256) void hist_kernel(
    const int* __restrict__ src, int* __restrict__ count)
{
  int e = blockIdx.x*256 + threadIdx.x;
  if (e < N_EDGES) atomicAdd(&count[src[e]], 1);
}

__global__ __launch_bounds__(256) void scan_kernel(
    const int* __restrict__ count, int* __restrict__ offsets)
{
  __shared__ int tmp[256];
  __shared__ int sbase;
  if (threadIdx.x == 0) sbase = 0;
  __syncthreads();
  for (int c0 = 0; c0 < N_NODES; c0 += 256) {
    int i = c0 + threadIdx.x;
    int v = (i < N_NODES) ? count[i] : 0;
    tmp[threadIdx.x] = v;
    __syncthreads();
    for (int off = 1; off < 256; off <<= 1) {
      int t = (threadIdx.x >= off) ? tmp[threadIdx.x - off] : 0;
      __syncthreads();
      tmp[threadIdx.x] += t;
      __syncthreads();
    }
    if (i < N_NODES) offsets[i] = sbase + tmp[threadIdx.x] - v;
    __syncthreads();
    if (threadIdx.x == 255) sbase += tmp[255];
    __syncthreads();
  }
  if (threadIdx.x == 0) offsets[N_NODES] = sbase;
}

__global__ __launch_bounds__(256) void scatter_kernel(
    const int* __restrict__ src, int* __restrict__ cursor, int* __restrict__ perm)
{
  int e = blockIdx.x*256 + threadIdx.x;
  if (e < N_EDGES) {
    int pos = atomicAdd(&cursor[src[e]], 1);
    perm[pos] = e;
  }
}

// ---------------- nodeA: pack tables for factored edge GEMM ----------------
__global__ __launch_bounds__(256) void nodeA_kernel(
    const float* __restrict__ h, const float* __restrict__ Wg, const float* __restrict__ Wm,
    float* __restrict__ spack, float* __restrict__ tpack)
{
  __shared__ float hs[16][129];
  int tid = threadIdx.x;
  int n0 = blockIdx.x * 16;
  for (int idx = tid; idx < 16*128; idx += 256) {
    int n = idx >> 7, k = idx & 127;
    hs[n][k] = h[(size_t)(n0+n)*H + k];
  }
  __syncthreads();
  int n = tid >> 4, c0 = (tid & 15) * 8;
  float aAg[8], aBg[8], aCg[8], aAm[8], aBm[8], aCm[8];
  #pragma unroll
  for (int j = 0; j < 8; j++) { aAg[j]=0.f; aBg[j]=0.f; aCg[j]=0.f; aAm[j]=0.f; aBm[j]=0.f; aCm[j]=0.f; }
  for (int k = 0; k < 128; k++) {
    float f = hs[n][k];
    float wAg[8], wBg[8], wCg[8], wAm[8], wBm[8], wCm[8];
    *(float4*)&wAg[0] = *(const float4*)&Wg[(      k)*H + c0];
    *(float4*)&wAg[4] = *(const float4*)&Wg[(      k)*H + c0 + 4];
    *(float4*)&wBg[0] = *(const float4*)&Wg[(128 + k)*H + c0];
    *(float4*)&wBg[4] = *(const float4*)&Wg[(128 + k)*H + c0 + 4];
    *(float4*)&wCg[0] = *(const float4*)&Wg[(256 + k)*H + c0];
    *(float4*)&wCg[4] = *(const float4*)&Wg[(256 + k)*H + c0 + 4];
    *(float4*)&wAm[0] = *(const float4*)&Wm[(      k)*H + c0];
    *(float4*)&wAm[4] = *(const float4*)&Wm[(      k)*H + c0 + 4];
    *(float4*)&wBm[0] = *(const float4*)&Wm[(128 + k)*H + c0];
    *(float4*)&wBm[4] = *(const float4*)&Wm[(128 + k)*H + c0 + 4];
    *(float4*)&wCm[0] = *(const float4*)&Wm[(256 + k)*H + c0];
    *(float4*)&wCm[4] = *(const float4*)&Wm[(256 + k)*H + c0 + 4];
    #pragma unroll
    for (int j = 0; j < 8; j++) {
      aAg[j] += f*wAg[j]; aBg[j] += f*wBg[j]; aCg[j] += f*wCg[j];
      aAm[j] += f*wAm[j]; aBm[j] += f*wBm[j]; aCm[j] += f*wCm[j];
    }
  }
  size_t so = (size_t)(n0+n)*512 + c0;
  *(float4*)&spack[so +   0] = *(float4*)&aAg[0]; *(float4*)&spack[so +   4] = *(float4*)&aAg[4];
  *(float4*)&spack[so + 128] = *(float4*)&aCg[0]; *(float4*)&spack[so + 132] = *(float4*)&aCg[4];
  *(float4*)&spack[so + 256] = *(float4*)&aAm[0]; *(float4*)&spack[so + 260] = *(float4*)&aAm[4];
  *(float4*)&spack[so + 384] = *(float4*)&aCm[0]; *(float4*)&spack[so + 388] = *(float4*)&aCm[4];
  *(float4*)&tpack[so +   0] = *(float4*)&aBg[0]; *(float4*)&tpack[so +   4] = *(float4*)&aBg[4];
  *(float4*)&tpack[so + 128] = *(float4*)&aCg[0]; *(float4*)&tpack[so + 132] = *(float4*)&aCg[4];
  *(float4*)&tpack[so + 256] = *(float4*)&aBm[0]; *(float4*)&tpack[so + 260] = *(float4*)&aBm[4];
  *(float4*)&tpack[so + 384] = *(float4*)&aCm[0]; *(float4*)&tpack[so + 388] = *(float4*)&aCm[4];
}

// ---------------- zgemm: az[pos] = cs[perm]@W1 + (pw*sig(pw@W2g))[perm]@W2, bf16 out ----------------
__global__ __launch_bounds__(256) void zgemm_kernel(
    const float* __restrict__ cs, const float* __restrict__ pw,
    const float* __restrict__ W1, const float* __restrict__ W2g, const float* __restrict__ W2,
    const int* __restrict__ perm, unsigned short* __restrict__ azb)
{
  __shared__ float csb[64][68];   // [k][e]
  __shared__ float pwb[64][68];
  __shared__ float pwg[64][68];

  int tid = threadIdx.x;
  int p0 = blockIdx.x * 64;

  // stage cs, pw rows (permuted) transposed to [k][e]
  {
    int e = tid & 63, kq = tid >> 6;   // kq: 0..3, 16 k's each
    int pe = perm[p0 + e];
    const float* csrow = &cs[(size_t)pe*64 + kq*16];
    const float* pwrow = &pw[(size_t)pe*64 + kq*16];
    float c4[16], p4[16];
    #pragma unroll
    for (int j = 0; j < 4; j++) {
      *(float4*)&c4[4*j] = *(const float4*)&csrow[4*j];
      *(float4*)&p4[4*j] = *(const float4*)&pwrow[4*j];
    }
    #pragma unroll
    for (int i = 0; i < 16; i++) {
      csb[kq*16 + i][e] = c4[i];
      pwb[kq*16 + i][e] = p4[i];
    }
  }
  __syncthreads();

  // pw_gate: pwg[k][e] = pwb[k][e] * sig(pw@W2g)[e][k]
  {
    int e = tid >> 2, c0 = (tid & 3) * 16;
    float acc[16];
    #pragma unroll
    for (int j = 0; j < 16; j++) acc[j] = 0.f;
    for (int k = 0; k < 64; k++) {
      float p = pwb[k][e];
      float w[16];
      *(float4*)&w[0]  = *(const float4*)&W2g[k*64 + c0];
      *(float4*)&w[4]  = *(const float4*)&W2g[k*64 + c0 + 4];
      *(float4*)&w[8]  = *(const float4*)&W2g[k*64 + c0 + 8];
      *(float4*)&w[12] = *(const float4*)&W2g[k*64 + c0 + 12];
      #pragma unroll
      for (int j = 0; j < 16; j++) acc[j] += p * w[j];
    }
    #pragma unroll
    for (int j = 0; j < 16; j++)
      pwg[c0 + j][e] = pwb[c0 + j][e] * sigf(acc[j]);
  }
  __syncthreads();

  // main: az[e][c] = cs@W1 + pwg@W2 ; thread = 4 edges x 8 cols
  int eg = tid >> 4, cg = tid & 15;
  int eb = eg * 4, c0 = cg * 8;
  float az[4][8];
  #pragma unroll
  for (int e = 0; e < 4; e++)
    #pragma unroll
    for (int j = 0; j < 8; j++) az[e][j] = 0.f;

  #pragma unroll 2
  for (int k = 0; k < 64; k++) {
    float4 cv = *(const float4*)&csb[k][eb];
    float4 pv = *(const float4*)&pwg[k][eb];
    float w1[8], w2[8];
    *(float4*)&w1[0] = *(const float4*)&W1[k*H + c0];
    *(float4*)&w1[4] = *(const float4*)&W1[k*H + c0 + 4];
    *(float4*)&w2[0] = *(const float4*)&W2[k*H + c0];
    *(float4*)&w2[4] = *(const float4*)&W2[k*H + c0 + 4];
    float ce[4] = {cv.x, cv.y, cv.z, cv.w};
    float pe[4] = {pv.x, pv.y, pv.z, pv.w};
    #pragma unroll
    for (int e = 0; e < 4; e++) {
      #pragma unroll
      for (int j = 0; j < 8; j++) az[e][j] += ce[e]*w1[j] + pe[e]*w2[j];
    }
  }

  // store bf16
  #pragma unroll
  for (int e = 0; e < 4; e++) {
    unsigned int w0 = (unsigned int)f2bf(az[e][0]) | ((unsigned int)f2bf(az[e][1]) << 16);
    unsigned int w1 = (unsigned int)f2bf(az[e][2]) | ((unsigned int)f2bf(az[e][3]) << 16);
    unsigned int w2 = (unsigned int)f2bf(az[e][4]) | ((unsigned int)f2bf(az[e][5]) << 16);
    unsigned int w3 = (unsigned int)f2bf(az[e][6]) | ((unsigned int)f2bf(az[e][7]) << 16);
    uint4 v = make_uint4(w0, w1, w2, w3);
    *(uint4*)&azb[(size_t)(p0 + eb + e)*H + c0] = v;
  }
}

// ---------------- combine: per src node, sum z over its edges, h_b = h_a + sum ----------------
__global__ __launch_bounds__(256) void combine_kernel(
    const float* __restrict__ h_in, float* __restrict__ h_out,
    const float* __restrict__ ed, const int* __restrict__ tgt,
    const int* __restrict__ offsets, const int* __restrict__ perm,
    const unsigned short* __restrict__ azb,
    const float* __restrict__ spack, const float* __restrict__ tpack)
{
  int tid = threadIdx.x;
  int unit = blockIdx.x*2 + (tid >> 7);
  int c = tid & 127;
  int n0 = unit * 4;
  for (int n = n0; n < n0 + 4; n++) {
    const float* sp = &spack[(size_t)n*512 + c];
    float Ags = sp[0], Cgs = sp[128], Ams = sp[256], Cms = sp[384];
    float acc = 0.f;
    int beg = offsets[n], end = offsets[n+1];
    for (int pos = beg; pos < end; pos += 4) {
      int bsz = end - pos; if (bsz > 4) bsz = 4;
      float azv[4], Bg[4], Cg[4], Bm[4], Cm[4], rc[4], mk[4];
      #pragma unroll
      for (int b = 0; b < 4; b++) {
        if (b < bsz) {
          int e = perm[pos + b];
          int tn = tgt[e];
          float r = ed[e];
          rc[b] = 1.0f / r;
          mk[b] = (r < 8.0f) ? 1.0f : 0.0f;
          azv[b] = bf2f(azb[(size_t)(pos + b)*H + c]);
          const float* tp = &tpack[(size_t)tn*512 + c];
          Bg[b] = tp[0]; Cg[b] = tp[128]; Bm[b] = tp[256]; Cm[b] = tp[384];
        }
      }
      #pragma unroll
      for (int b = 0; b < 4; b++) {
        if (b < bsz) {
          float g = sigf(Ags + Bg[b] + rc[b]*(Cgs - Cg[b]));
          float m = eluf(Ams + Bm[b] + rc[b]*(Cms - Cm[b]));
          acc += g * m * azv[b] * mk[b];
        }
      }
    }
    h_out[(size_t)n*H + c] = h_in[(size_t)n*H + c] + acc;
  }
}

// ---------------- node kernel: zp=elu((h@p1)*(h@p2)) -> pooled; h_out=elu(h@psi) ----------------
__global__ __launch_bounds__(256) void node_kernel(
    const float* __restrict__ h_in,
    const float* __restrict__ p1, const float* __restrict__ p2, const float* __restrict__ psiW,
    const int* __restrict__ gidx, float* __restrict__ pooled, float* __restrict__ h_out)
{
  __shared__ float hs[16][129];
  int tid = threadIdx.x;
  int n0 = blockIdx.x * 16;
  for (int idx = tid; idx < 16*128; idx += 256) {
    int n = idx >> 7, k = idx & 127;
    hs[n][k] = h_in[(size_t)(n0+n)*H + k];
  }
  __syncthreads();
  int n = tid >> 4, c0 = (tid & 15) * 8;
  float a1[8], a2[8], a3[8];
  #pragma unroll
  for (int j = 0; j < 8; j++) { a1[j]=0.f; a2[j]=0.f; a3[j]=0.f; }
  for (int k = 0; k < 128; k++) {
    float f = hs[n][k];
    float w1[8], w2[8], w3[8];
    *(float4*)&w1[0] = *(const float4*)&p1[k*H + c0];
    *(float4*)&w1[4] = *(const float4*)&p1[k*H + c0 + 4];
    *(float4*)&w2[0] = *(const float4*)&p2[k*H + c0];
    *(float4*)&w2[4] = *(const float4*)&p2[k*H + c0 + 4];
    *(float4*)&w3[0] = *(const float4*)&psiW[k*H + c0];
    *(float4*)&w3[4] = *(const float4*)&psiW[k*H + c0 + 4];
    #pragma unroll
    for (int j = 0; j < 8; j++) { a1[j] += f*w1[j]; a2[j] += f*w2[j]; a3[j] += f*w3[j]; }
  }
  int g = gidx[n0 + n];
  float ho[8];
  #pragma unroll
  for (int j = 0; j < 8; j++) {
    float zp = eluf(a1[j] * a2[j]);
    atomicAdd(&pooled[g*H + c0 + j], zp);
    ho[j] = eluf(a3[j]);
  }
  float* dst = &h_out[(size_t)(n0+n)*H + c0];
  *(float4*)&dst[0] = *(float4*)&ho[0];
  *(float4*)&dst[4] = *(float4*)&ho[4];
}

// ---------------- final: y = elu(elu(pooled @ lr1) @ lr2) ----------------
__global__ __launch_bounds__(64) void final_kernel(
    const float* __restrict__ pooled, const float* __restrict__ lr1, const float* __restrict__ lr2,
    float* __restrict__ out)
{
  __shared__ float sp[128];
  __shared__ float y1[64];
  int g = blockIdx.x, tid = threadIdx.x;
  sp[tid]      = pooled[g*128 + tid];
  sp[tid + 64] = pooled[g*128 + 64 + tid];
  __syncthreads();
  float acc = 0.f;
  for (int k = 0; k < 128; k++) acc += sp[k] * lr1[k*64 + tid];
  y1[tid] = eluf(acc);
  __syncthreads();
  if (tid < 32) {
    float a2 = 0.f;
    for (int k = 0; k < 64; k++) a2 += y1[k] * lr2[k*32 + tid];
    out[g*32 + tid] = eluf(a2);
  }
}

extern "C" void kernel_launch(void* const* d_in, const int* in_sizes, int n_in,
                              void* d_out, int out_size, void* d_ws, size_t ws_size,
                              hipStream_t stream)
{
  const float* x    = (const float*)d_in[0];
  const float* ed   = (const float*)d_in[1];
  const float* cs   = (const float*)d_in[2];
  const float* pw   = (const float*)d_in[3];
  const float* embW = (const float*)d_in[4];
  const float* Wg   = (const float*)d_in[5];
  const float* Wm   = (const float*)d_in[6];
  const float* W1   = (const float*)d_in[7];
  const float* W2g  = (const float*)d_in[8];
  const float* W2   = (const float*)d_in[9];
  const float* p1   = (const float*)d_in[10];
  const float* p2   = (const float*)d_in[11];
  const float* psiW = (const float*)d_in[12];
  const float* lr1  = (const float*)d_in[13];
  const float* lr2  = (const float*)d_in[14];
  const int* esrc   = (const int*)d_in[15];
  const int* etgt   = (const int*)d_in[16];
  const int* gidx   = (const int*)d_in[17];

  float* h_a    = (float*)d_ws;                 // 1,280,000 f
  float* h_b    = h_a + (size_t)N_NODES*H;      // 1,280,000 f
  float* pooled = h_b + (size_t)N_NODES*H;      // 12,800 f
  float* spack  = pooled + 100*H;               // 5,120,000 f
  float* tpack  = spack + (size_t)N_NODES*512;  // 5,120,000 f
  unsigned short* azb = (unsigned short*)(tpack + (size_t)N_NODES*512); // 20,480,000 us
  int* counts  = (int*)(azb + (size_t)N_EDGES*H);
  int* offsets = counts + N_NODES;              // N_NODES+1
  int* cursor  = offsets + N_NODES + 1;
  int* perm    = cursor + N_NODES;              // N_EDGES

  // edge sort by src (once)
  hipMemsetAsync(counts, 0, N_NODES*sizeof(int), stream);
  hipMemsetAsync(pooled, 0, 100*H*sizeof(float), stream);
  hist_kernel<<<(N_EDGES+255)/256, 256, 0, stream>>>(esrc, counts);
  scan_kernel<<<1, 256, 0, stream>>>(counts, offsets);
  hipMemcpyAsync(cursor, offsets, N_NODES*sizeof(int), hipMemcpyDeviceToDevice, stream);
  scatter_kernel<<<(N_EDGES+255)/256, 256, 0, stream>>>(esrc, cursor, perm);

  embed_kernel<<<625, 256, 0, stream>>>(x, embW, h_a);

  for (int i = 0; i < 3; i++) {
    nodeA_kernel<<<625, 256, 0, stream>>>(h_a, Wg + i*384*128, Wm + i*384*128, spack, tpack);
    zgemm_kernel<<<N_EDGES/64, 256, 0, stream>>>(cs, pw,
        W1 + i*64*128, W2g + i*64*64, W2 + i*64*128, perm, azb);
    combine_kernel<<<N_NODES/8, 256, 0, stream>>>(h_a, h_b, ed, etgt,
        offsets, perm, azb, spack, tpack);
    node_kernel<<<625, 256, 0, stream>>>(h_b,
        p1 + i*128*128, p2 + i*128*128, psiW + i*128*128,
        gidx, pooled, h_a);
  }
  final_kernel<<<100, 64, 0, stream>>>(pooled, lr1, lr2, (float*)d_out);
}

// Round 4
// 1354.025 us; speedup vs baseline: 4.9427x; 1.3733x over previous
//
#include <hip/hip_runtime.h>
#include <math.h>

#define H 128
#define N_NODES 10000
#define N_EDGES 160000

typedef float f32x4 __attribute__((ext_vector_type(4)));
typedef short s16x8 __attribute__((ext_vector_type(8)));

__device__ __forceinline__ float sigf(float x){ return 1.0f/(1.0f + __expf(-x)); }
__device__ __forceinline__ float eluf(float x){ return x > 0.0f ? x : (__expf(x) - 1.0f); }

__device__ __forceinline__ unsigned short f2bf(float f){
  unsigned int u = __float_as_uint(f);
  unsigned int r = (u + 0x7fffu + ((u >> 16) & 1u)) >> 16;
  return (unsigned short)r;
}
__device__ __forceinline__ float bf2f(unsigned short s){
  return __uint_as_float(((unsigned int)s) << 16);
}

__device__ __forceinline__ f32x4 MFMA16(s16x8 a, s16x8 b, f32x4 c){
  return __builtin_amdgcn_mfma_f32_16x16x32_bf16(a, b, c, 0, 0, 0);
}

__device__ __forceinline__ s16x8 loadA_f32(const float* p){
  float4 a = *(const float4*)p;
  float4 b = *(const float4*)(p+4);
  s16x8 r;
  r[0]=(short)f2bf(a.x); r[1]=(short)f2bf(a.y); r[2]=(short)f2bf(a.z); r[3]=(short)f2bf(a.w);
  r[4]=(short)f2bf(b.x); r[5]=(short)f2bf(b.y); r[6]=(short)f2bf(b.z); r[7]=(short)f2bf(b.w);
  return r;
}

// ---------------- embed: h = sigmoid(x @ emb_W), 16 nodes/block ----------------
__global__ __launch_bounds__(256) void embed_kernel(
    const float* __restrict__ x, const float* __restrict__ W, float* __restrict__ h_out)
{
  __shared__ float xs[16][129];
  int tid = threadIdx.x;
  int n0 = blockIdx.x * 16;
  for (int idx = tid; idx < 16*128; idx += 256) {
    int n = idx >> 7, k = idx & 127;
    xs[n][k] = x[(size_t)(n0+n)*H + k];
  }
  __syncthreads();
  int n = tid >> 4, c0 = (tid & 15) * 8;
  float acc[8];
  #pragma unroll
  for (int j = 0; j < 8; j++) acc[j] = 0.f;
  for (int k = 0; k < 128; k++) {
    float f = xs[n][k];
    float w[8];
    *(float4*)&w[0] = *(const float4*)&W[k*H + c0];
    *(float4*)&w[4] = *(const float4*)&W[k*H + c0 + 4];
    #pragma unroll
    for (int j = 0; j < 8; j++) acc[j] += f * w[j];
  }
  float o[8];
  #pragma unroll
  for (int j = 0; j < 8; j++) o[j] = sigf(acc[j]);
  float* dst = &h_out[(size_t)(n0+n)*H + c0];
  *(float4*)&dst[0] = *(float4*)&o[0];
  *(float4*)&dst[4] = *(float4*)&o[4];
}

// ---------------- edge sort by src: hist -> scan -> scatter ----------------
__global__ __launch_bounds__(256) void hist_kernel(
    const int* __restrict__ src, int* __restrict__ count)
{
  int e = blockIdx.x*256 + threadIdx.x;
  if (e < N_EDGES) atomicAdd(&count[src[e]], 1);
}

__global__ __launch_bounds__(256) void scan_kernel(
    const int* __restrict__ count, int* __restrict__ offsets)
{
  __shared__ int tmp[256];
  __shared__ int sbase;
  if (threadIdx.x == 0) sbase = 0;
  __syncthreads();
  for (int c0 = 0; c0 < N_NODES; c0 += 256) {
    int i = c0 + threadIdx.x;
    int v = (i < N_NODES) ? count[i] : 0;
    tmp[threadIdx.x] = v;
    __syncthreads();
    for (int off = 1; off < 256; off <<= 1) {
      int t = (threadIdx.x >= off) ? tmp[threadIdx.x - off] : 0;
      __syncthreads();
      tmp[threadIdx.x] += t;
      __syncthreads();
    }
    if (i < N_NODES) offsets[i] = sbase + tmp[threadIdx.x] - v;
    __syncthreads();
    if (threadIdx.x == 255) sbase += tmp[255];
    __syncthreads();
  }
  if (threadIdx.x == 0) offsets[N_NODES] = sbase;
}

__global__ __launch_bounds__(256) void scatter_kernel(
    const int* __restrict__ src, int* __restrict__ cursor, int* __restrict__ perm)
{
  int e = blockIdx.x*256 + threadIdx.x;
  if (e < N_EDGES) {
    int pos = atomicAdd(&cursor[src[e]], 1);
    perm[pos] = e;
  }
}

// ---------------- prep_weights: transpose W1,W2 (64x128) and W2g (64x64) to bf16 [col][k] ----------------
__global__ __launch_bounds__(256) void prep_weights(
    const float* __restrict__ W1, const float* __restrict__ W2, const float* __restrict__ W2g,
    unsigned short* __restrict__ w1t, unsigned short* __restrict__ w2t, unsigned short* __restrict__ w2gt)
{
  int idx = blockIdx.x*256 + threadIdx.x;
  if (idx < 3*8192) {
    int l = idx / 8192, r = idx % 8192;
    int c = r >> 6, k = r & 63;
    w1t[idx] = f2bf(W1[l*8192 + k*128 + c]);
    w2t[idx] = f2bf(W2[l*8192 + k*128 + c]);
  }
  int idx2 = idx - 3*8192;
  if (idx2 >= 0 && idx2 < 3*4096) {
    int l = idx2 / 4096, r = idx2 % 4096;
    int c = r >> 6, k = r & 63;
    w2gt[idx2] = f2bf(W2g[l*4096 + k*64 + c]);
  }
}

// ---------------- nodeA: pack tables for factored edge GEMM ----------------
__global__ __launch_bounds__(256) void nodeA_kernel(
    const float* __restrict__ h, const float* __restrict__ Wg, const float* __restrict__ Wm,
    float* __restrict__ spack, float* __restrict__ tpack)
{
  __shared__ float hs[16][129];
  int tid = threadIdx.x;
  int n0 = blockIdx.x * 16;
  for (int idx = tid; idx < 16*128; idx += 256) {
    int n = idx >> 7, k = idx & 127;
    hs[n][k] = h[(size_t)(n0+n)*H + k];
  }
  __syncthreads();
  int n = tid >> 4, c0 = (tid & 15) * 8;
  float aAg[8], aBg[8], aCg[8], aAm[8], aBm[8], aCm[8];
  #pragma unroll
  for (int j = 0; j < 8; j++) { aAg[j]=0.f; aBg[j]=0.f; aCg[j]=0.f; aAm[j]=0.f; aBm[j]=0.f; aCm[j]=0.f; }
  for (int k = 0; k < 128; k++) {
    float f = hs[n][k];
    float wAg[8], wBg[8], wCg[8], wAm[8], wBm[8], wCm[8];
    *(float4*)&wAg[0] = *(const float4*)&Wg[(      k)*H + c0];
    *(float4*)&wAg[4] = *(const float4*)&Wg[(      k)*H + c0 + 4];
    *(float4*)&wBg[0] = *(const float4*)&Wg[(128 + k)*H + c0];
    *(float4*)&wBg[4] = *(const float4*)&Wg[(128 + k)*H + c0 + 4];
    *(float4*)&wCg[0] = *(const float4*)&Wg[(256 + k)*H + c0];
    *(float4*)&wCg[4] = *(const float4*)&Wg[(256 + k)*H + c0 + 4];
    *(float4*)&wAm[0] = *(const float4*)&Wm[(      k)*H + c0];
    *(float4*)&wAm[4] = *(const float4*)&Wm[(      k)*H + c0 + 4];
    *(float4*)&wBm[0] = *(const float4*)&Wm[(128 + k)*H + c0];
    *(float4*)&wBm[4] = *(const float4*)&Wm[(128 + k)*H + c0 + 4];
    *(float4*)&wCm[0] = *(const float4*)&Wm[(256 + k)*H + c0];
    *(float4*)&wCm[4] = *(const float4*)&Wm[(256 + k)*H + c0 + 4];
    #pragma unroll
    for (int j = 0; j < 8; j++) {
      aAg[j] += f*wAg[j]; aBg[j] += f*wBg[j]; aCg[j] += f*wCg[j];
      aAm[j] += f*wAm[j]; aBm[j] += f*wBm[j]; aCm[j] += f*wCm[j];
    }
  }
  size_t so = (size_t)(n0+n)*512 + c0;
  *(float4*)&spack[so +   0] = *(float4*)&aAg[0]; *(float4*)&spack[so +   4] = *(float4*)&aAg[4];
  *(float4*)&spack[so + 128] = *(float4*)&aCg[0]; *(float4*)&spack[so + 132] = *(float4*)&aCg[4];
  *(float4*)&spack[so + 256] = *(float4*)&aAm[0]; *(float4*)&spack[so + 260] = *(float4*)&aAm[4];
  *(float4*)&spack[so + 384] = *(float4*)&aCm[0]; *(float4*)&spack[so + 388] = *(float4*)&aCm[4];
  *(float4*)&tpack[so +   0] = *(float4*)&aBg[0]; *(float4*)&tpack[so +   4] = *(float4*)&aBg[4];
  *(float4*)&tpack[so + 128] = *(float4*)&aCg[0]; *(float4*)&tpack[so + 132] = *(float4*)&aCg[4];
  *(float4*)&tpack[so + 256] = *(float4*)&aBm[0]; *(float4*)&tpack[so + 260] = *(float4*)&aBm[4];
  *(float4*)&tpack[so + 384] = *(float4*)&aCm[0]; *(float4*)&tpack[so + 388] = *(float4*)&aCm[4];
}

// ---------------- zgemm (MFMA): az = cs@W1 + (pw*sig(pw@W2g))@W2, bf16 out ----------------
// block = 64 edges (4 waves x 16 rows) x 128 cols
__global__ __launch_bounds__(256) void zgemm_mfma(
    const float* __restrict__ cs, const float* __restrict__ pw,
    const unsigned short* __restrict__ w1t, const unsigned short* __restrict__ w2t,
    const unsigned short* __restrict__ w2gt,
    const int* __restrict__ perm, unsigned short* __restrict__ azb)
{
  __shared__ unsigned short gate[64*64];   // sig(pw@W2g), XOR-swizzled

  int tid  = threadIdx.x;
  int wave = tid >> 6, lane = tid & 63;
  int row  = lane & 15, kg = lane >> 4;    // A: row, k-group
  int p0   = blockIdx.x * 64;

  int pos = p0 + wave*16 + row;
  int pe  = perm[pos];
  const float* csr = &cs[(size_t)pe*64];
  const float* pwr = &pw[(size_t)pe*64];

  s16x8 acs[2], apw[2];
  acs[0] = loadA_f32(csr + kg*8);
  acs[1] = loadA_f32(csr + 32 + kg*8);
  apw[0] = loadA_f32(pwr + kg*8);
  apw[1] = loadA_f32(pwr + 32 + kg*8);

  // phase 1: S1 = pw @ W2g  (N=64: 4 col-tiles, K=64: 2 steps)
  f32x4 acc1[4];
  #pragma unroll
  for (int nt = 0; nt < 4; nt++) { acc1[nt][0]=0.f; acc1[nt][1]=0.f; acc1[nt][2]=0.f; acc1[nt][3]=0.f; }
  #pragma unroll
  for (int nt = 0; nt < 4; nt++) {
    s16x8 b0 = *(const s16x8*)&w2gt[(size_t)(nt*16+row)*64 + kg*8];
    s16x8 b1 = *(const s16x8*)&w2gt[(size_t)(nt*16+row)*64 + 32 + kg*8];
    acc1[nt] = MFMA16(apw[0], b0, acc1[nt]);
    acc1[nt] = MFMA16(apw[1], b1, acc1[nt]);
  }

  // sigmoid -> gate LDS (C-layout scatter write, swizzled)
  #pragma unroll
  for (int nt = 0; nt < 4; nt++) {
    #pragma unroll
    for (int r = 0; r < 4; r++) {
      int grow = wave*16 + kg*4 + r;       // C row within block
      int gcol = nt*16 + row;              // C col
      int byt = (grow << 7) + (gcol << 1);
      byt ^= (grow & 7) << 4;
      *(unsigned short*)((char*)gate + byt) = f2bf(sigf(acc1[nt][r]));
    }
  }
  __syncthreads();

  // read gate in A-layout (b128), pwg frags = pw * gate
  s16x8 apg[2];
  #pragma unroll
  for (int ks = 0; ks < 2; ks++) {
    int arow = wave*16 + row;
    int byt = (arow << 7) + ks*64 + kg*16;
    byt ^= (arow & 7) << 4;
    s16x8 g = *(s16x8*)((char*)gate + byt);
    s16x8 o;
    #pragma unroll
    for (int j = 0; j < 8; j++) {
      float v = bf2f((unsigned short)apw[ks][j]) * bf2f((unsigned short)g[j]);
      o[j] = (short)f2bf(v);
    }
    apg[ks] = o;
  }

  // phase 2: az = cs@W1t + pwg@W2t (N=128: 8 tiles, K=64: 2 steps each)
  f32x4 acc2[8];
  #pragma unroll
  for (int nt = 0; nt < 8; nt++) { acc2[nt][0]=0.f; acc2[nt][1]=0.f; acc2[nt][2]=0.f; acc2[nt][3]=0.f; }
  #pragma unroll
  for (int nt = 0; nt < 8; nt++) {
    #pragma unroll
    for (int ks = 0; ks < 2; ks++) {
      s16x8 b1 = *(const s16x8*)&w1t[(size_t)(nt*16+row)*64 + ks*32 + kg*8];
      acc2[nt] = MFMA16(acs[ks], b1, acc2[nt]);
      s16x8 b2 = *(const s16x8*)&w2t[(size_t)(nt*16+row)*64 + ks*32 + kg*8];
      acc2[nt] = MFMA16(apg[ks], b2, acc2[nt]);
    }
  }

  // store bf16 az (C layout: col = lane&15 (+16*nt), row = kg*4 + r)
  #pragma unroll
  for (int nt = 0; nt < 8; nt++) {
    #pragma unroll
    for (int r = 0; r < 4; r++) {
      int crow = kg*4 + r;
      azb[(size_t)(p0 + wave*16 + crow)*H + nt*16 + row] = f2bf(acc2[nt][r]);
    }
  }
}

// ---------------- combine: per src node, sum z over its edges, h_b = h_a + sum ----------------
__global__ __launch_bounds__(256) void combine_kernel(
    const float* __restrict__ h_in, float* __restrict__ h_out,
    const float* __restrict__ ed, const int* __restrict__ tgt,
    const int* __restrict__ offsets, const int* __restrict__ perm,
    const unsigned short* __restrict__ azb,
    const float* __restrict__ spack, const float* __restrict__ tpack)
{
  int tid = threadIdx.x;
  int unit = blockIdx.x*2 + (tid >> 7);
  int c = tid & 127;
  int n0 = unit * 4;
  for (int n = n0; n < n0 + 4; n++) {
    const float* sp = &spack[(size_t)n*512 + c];
    float Ags = sp[0], Cgs = sp[128], Ams = sp[256], Cms = sp[384];
    float acc = 0.f;
    int beg = offsets[n], end = offsets[n+1];
    for (int pos = beg; pos < end; pos += 4) {
      int bsz = end - pos; if (bsz > 4) bsz = 4;
      float azv[4], Bg[4], Cg[4], Bm[4], Cm[4], rc[4], mk[4];
      #pragma unroll
      for (int b = 0; b < 4; b++) {
        if (b < bsz) {
          int e = perm[pos + b];
          int tn = tgt[e];
          float r = ed[e];
          rc[b] = 1.0f / r;
          mk[b] = (r < 8.0f) ? 1.0f : 0.0f;
          azv[b] = bf2f(azb[(size_t)(pos + b)*H + c]);
          const float* tp = &tpack[(size_t)tn*512 + c];
          Bg[b] = tp[0]; Cg[b] = tp[128]; Bm[b] = tp[256]; Cm[b] = tp[384];
        }
      }
      #pragma unroll
      for (int b = 0; b < 4; b++) {
        if (b < bsz) {
          float g = sigf(Ags + Bg[b] + rc[b]*(Cgs - Cg[b]));
          float m = eluf(Ams + Bm[b] + rc[b]*(Cms - Cm[b]));
          acc += g * m * azv[b] * mk[b];
        }
      }
    }
    h_out[(size_t)n*H + c] = h_in[(size_t)n*H + c] + acc;
  }
}

// ---------------- node kernel: zp=elu((h@p1)*(h@p2)) -> pooled; h_out=elu(h@psi) ----------------
__global__ __launch_bounds__(256) void node_kernel(
    const float* __restrict__ h_in,
    const float* __restrict__ p1, const float* __restrict__ p2, const float* __restrict__ psiW,
    const int* __restrict__ gidx, float* __restrict__ pooled, float* __restrict__ h_out)
{
  __shared__ float hs[16][129];
  int tid = threadIdx.x;
  int n0 = blockIdx.x * 16;
  for (int idx = tid; idx < 16*128; idx += 256) {
    int n = idx >> 7, k = idx & 127;
    hs[n][k] = h_in[(size_t)(n0+n)*H + k];
  }
  __syncthreads();
  int n = tid >> 4, c0 = (tid & 15) * 8;
  float a1[8], a2[8], a3[8];
  #pragma unroll
  for (int j = 0; j < 8; j++) { a1[j]=0.f; a2[j]=0.f; a3[j]=0.f; }
  for (int k = 0; k < 128; k++) {
    float f = hs[n][k];
    float w1[8], w2[8], w3[8];
    *(float4*)&w1[0] = *(const float4*)&p1[k*H + c0];
    *(float4*)&w1[4] = *(const float4*)&p1[k*H + c0 + 4];
    *(float4*)&w2[0] = *(const float4*)&p2[k*H + c0];
    *(float4*)&w2[4] = *(const float4*)&p2[k*H + c0 + 4];
    *(float4*)&w3[0] = *(const float4*)&psiW[k*H + c0];
    *(float4*)&w3[4] = *(const float4*)&psiW[k*H + c0 + 4];
    #pragma unroll
    for (int j = 0; j < 8; j++) { a1[j] += f*w1[j]; a2[j] += f*w2[j]; a3[j] += f*w3[j]; }
  }
  int g = gidx[n0 + n];
  float ho[8];
  #pragma unroll
  for (int j = 0; j < 8; j++) {
    float zp = eluf(a1[j] * a2[j]);
    atomicAdd(&pooled[g*H + c0 + j], zp);
    ho[j] = eluf(a3[j]);
  }
  float* dst = &h_out[(size_t)(n0+n)*H + c0];
  *(float4*)&dst[0] = *(float4*)&ho[0];
  *(float4*)&dst[4] = *(float4*)&ho[4];
}

// ---------------- final: y = elu(elu(pooled @ lr1) @ lr2) ----------------
__global__ __launch_bounds__(64) void final_kernel(
    const float* __restrict__ pooled, const float* __restrict__ lr1, const float* __restrict__ lr2,
    float* __restrict__ out)
{
  __shared__ float sp[128];
  __shared__ float y1[64];
  int g = blockIdx.x, tid = threadIdx.x;
  sp[tid]      = pooled[g*128 + tid];
  sp[tid + 64] = pooled[g*128 + 64 + tid];
  __syncthreads();
  float acc = 0.f;
  for (int k = 0; k < 128; k++) acc += sp[k] * lr1[k*64 + tid];
  y1[tid] = eluf(acc);
  __syncthreads();
  if (tid < 32) {
    float a2 = 0.f;
    for (int k = 0; k < 64; k++) a2 += y1[k] * lr2[k*32 + tid];
    out[g*32 + tid] = eluf(a2);
  }
}

extern "C" void kernel_launch(void* const* d_in, const int* in_sizes, int n_in,
                              void* d_out, int out_size, void* d_ws, size_t ws_size,
                              hipStream_t stream)
{
  const float* x    = (const float*)d_in[0];
  const float* ed   = (const float*)d_in[1];
  const float* cs   = (const float*)d_in[2];
  const float* pw   = (const float*)d_in[3];
  const float* embW = (const float*)d_in[4];
  const float* Wg   = (const float*)d_in[5];
  const float* Wm   = (const float*)d_in[6];
  const float* W1   = (const float*)d_in[7];
  const float* W2g  = (const float*)d_in[8];
  const float* W2   = (const float*)d_in[9];
  const float* p1   = (const float*)d_in[10];
  const float* p2   = (const float*)d_in[11];
  const float* psiW = (const float*)d_in[12];
  const float* lr1  = (const float*)d_in[13];
  const float* lr2  = (const float*)d_in[14];
  const int* esrc   = (const int*)d_in[15];
  const int* etgt   = (const int*)d_in[16];
  const int* gidx   = (const int*)d_in[17];

  float* h_a    = (float*)d_ws;                 // 1,280,000 f
  float* h_b    = h_a + (size_t)N_NODES*H;      // 1,280,000 f
  float* pooled = h_b + (size_t)N_NODES*H;      // 12,800 f
  float* spack  = pooled + 100*H;               // 5,120,000 f
  float* tpack  = spack + (size_t)N_NODES*512;  // 5,120,000 f
  unsigned short* azb = (unsigned short*)(tpack + (size_t)N_NODES*512); // 20,480,000 us
  int* counts  = (int*)(azb + (size_t)N_EDGES*H);
  int* offsets = counts + N_NODES;              // N_NODES+1
  int* cursor  = offsets + N_NODES + 1;
  int* perm    = cursor + N_NODES;              // N_EDGES
  unsigned short* w1t  = (unsigned short*)(perm + N_EDGES); // 3*8192
  unsigned short* w2t  = w1t + 3*8192;
  unsigned short* w2gt = w2t + 3*8192;          // 3*4096

  // edge sort by src (once) + weight transposes (once)
  hipMemsetAsync(counts, 0, N_NODES*sizeof(int), stream);
  hipMemsetAsync(pooled, 0, 100*H*sizeof(float), stream);
  hist_kernel<<<(N_EDGES+255)/256, 256, 0, stream>>>(esrc, counts);
  scan_kernel<<<1, 256, 0, stream>>>(counts, offsets);
  hipMemcpyAsync(cursor, offsets, N_NODES*sizeof(int), hipMemcpyDeviceToDevice, stream);
  scatter_kernel<<<(N_EDGES+255)/256, 256, 0, stream>>>(esrc, cursor, perm);
  prep_weights<<<144, 256, 0, stream>>>(W1, W2, W2g, w1t, w2t, w2gt);

  embed_kernel<<<625, 256, 0, stream>>>(x, embW, h_a);

  for (int i = 0; i < 3; i++) {
    nodeA_kernel<<<625, 256, 0, stream>>>(h_a, Wg + i*384*128, Wm + i*384*128, spack, tpack);
    zgemm_mfma<<<N_EDGES/64, 256, 0, stream>>>(cs, pw,
        w1t + i*8192, w2t + i*8192, w2gt + i*4096, perm, azb);
    combine_kernel<<<N_NODES/8, 256, 0, stream>>>(h_a, h_b, ed, etgt,
        offsets, perm, azb, spack, tpack);
    node_kernel<<<625, 256, 0, stream>>>(h_b,
        p1 + i*128*128, p2 + i*128*128, psiW + i*128*128,
        gidx, pooled, h_a);
  }
  final_kernel<<<100, 64, 0, stream>>>(pooled, lr1, lr2, (float*)d_out);
}

// Round 5
// 729.486 us; speedup vs baseline: 9.1743x; 1.8561x over previous
//
#include <hip/hip_runtime.h>
#include <math.h>

#define H 128
#define N_NODES 10000
#define N_EDGES 160000

typedef float f32x4 __attribute__((ext_vector_type(4)));
typedef short s16x8 __attribute__((ext_vector_type(8)));

__device__ __forceinline__ float sigf(float x){ return 1.0f/(1.0f + __expf(-x)); }
__device__ __forceinline__ float eluf(float x){ return x > 0.0f ? x : (__expf(x) - 1.0f); }

__device__ __forceinline__ unsigned short f2bf(float f){
  unsigned int u = __float_as_uint(f);
  unsigned int r = (u + 0x7fffu + ((u >> 16) & 1u)) >> 16;
  return (unsigned short)r;
}
__device__ __forceinline__ float bf2f(unsigned short s){
  return __uint_as_float(((unsigned int)s) << 16);
}

__device__ __forceinline__ f32x4 MFMA16(s16x8 a, s16x8 b, f32x4 c){
  return __builtin_amdgcn_mfma_f32_16x16x32_bf16(a, b, c, 0, 0, 0);
}

__device__ __forceinline__ s16x8 loadA_f32(const float* p){
  float4 a = *(const float4*)p;
  float4 b = *(const float4*)(p+4);
  s16x8 r;
  r[0]=(short)f2bf(a.x); r[1]=(short)f2bf(a.y); r[2]=(short)f2bf(a.z); r[3]=(short)f2bf(a.w);
  r[4]=(short)f2bf(b.x); r[5]=(short)f2bf(b.y); r[6]=(short)f2bf(b.z); r[7]=(short)f2bf(b.w);
  return r;
}

// ---------------- embed: h = sigmoid(x @ emb_W), 16 nodes/block ----------------
__global__ __launch_bounds__(256) void embed_kernel(
    const float* __restrict__ x, const float* __restrict__ W, float* __restrict__ h_out)
{
  __shared__ float xs[16][129];
  int tid = threadIdx.x;
  int n0 = blockIdx.x * 16;
  for (int idx = tid; idx < 16*128; idx += 256) {
    int n = idx >> 7, k = idx & 127;
    xs[n][k] = x[(size_t)(n0+n)*H + k];
  }
  __syncthreads();
  int n = tid >> 4, c0 = (tid & 15) * 8;
  float acc[8];
  #pragma unroll
  for (int j = 0; j < 8; j++) acc[j] = 0.f;
  for (int k = 0; k < 128; k++) {
    float f = xs[n][k];
    float w[8];
    *(float4*)&w[0] = *(const float4*)&W[k*H + c0];
    *(float4*)&w[4] = *(const float4*)&W[k*H + c0 + 4];
    #pragma unroll
    for (int j = 0; j < 8; j++) acc[j] += f * w[j];
  }
  float o[8];
  #pragma unroll
  for (int j = 0; j < 8; j++) o[j] = sigf(acc[j]);
  float* dst = &h_out[(size_t)(n0+n)*H + c0];
  *(float4*)&dst[0] = *(float4*)&o[0];
  *(float4*)&dst[4] = *(float4*)&o[4];
}

// ---------------- edge sort by src: hist -> scan -> scatter ----------------
__global__ __launch_bounds__(256) void hist_kernel(
    const int* __restrict__ src, int* __restrict__ count)
{
  int e = blockIdx.x*256 + threadIdx.x;
  if (e < N_EDGES) atomicAdd(&count[src[e]], 1);
}

__global__ __launch_bounds__(256) void scan_kernel(
    const int* __restrict__ count, int* __restrict__ offsets)
{
  __shared__ int tmp[256];
  __shared__ int sbase;
  if (threadIdx.x == 0) sbase = 0;
  __syncthreads();
  for (int c0 = 0; c0 < N_NODES; c0 += 256) {
    int i = c0 + threadIdx.x;
    int v = (i < N_NODES) ? count[i] : 0;
    tmp[threadIdx.x] = v;
    __syncthreads();
    for (int off = 1; off < 256; off <<= 1) {
      int t = (threadIdx.x >= off) ? tmp[threadIdx.x - off] : 0;
      __syncthreads();
      tmp[threadIdx.x] += t;
      __syncthreads();
    }
    if (i < N_NODES) offsets[i] = sbase + tmp[threadIdx.x] - v;
    __syncthreads();
    if (threadIdx.x == 255) sbase += tmp[255];
    __syncthreads();
  }
  if (threadIdx.x == 0) offsets[N_NODES] = sbase;
}

__global__ __launch_bounds__(256) void scatter_kernel(
    const int* __restrict__ src, int* __restrict__ cursor, int* __restrict__ perm)
{
  int e = blockIdx.x*256 + threadIdx.x;
  if (e < N_EDGES) {
    int pos = atomicAdd(&cursor[src[e]], 1);
    perm[pos] = e;
  }
}

// ---------------- prep_weights: transpose W1,W2 (64x128) and W2g (64x64) to bf16 [col][k] ----------------
__global__ __launch_bounds__(256) void prep_weights(
    const float* __restrict__ W1, const float* __restrict__ W2, const float* __restrict__ W2g,
    unsigned short* __restrict__ w1t, unsigned short* __restrict__ w2t, unsigned short* __restrict__ w2gt)
{
  int idx = blockIdx.x*256 + threadIdx.x;
  if (idx < 3*8192) {
    int l = idx / 8192, r = idx % 8192;
    int c = r >> 6, k = r & 63;
    w1t[idx] = f2bf(W1[l*8192 + k*128 + c]);
    w2t[idx] = f2bf(W2[l*8192 + k*128 + c]);
  }
  int idx2 = idx - 3*8192;
  if (idx2 >= 0 && idx2 < 3*4096) {
    int l = idx2 / 4096, r = idx2 % 4096;
    int c = r >> 6, k = r & 63;
    w2gt[idx2] = f2bf(W2g[l*4096 + k*64 + c]);
  }
}

// ---------------- prep_nodew: bf16 [col][k] transposes for node GEMMs ----------------
// wnt[l][j][k], j in 0..767: j<384 -> Wg[(j>>7)*128 + k][j&127]; else Wm same for j-384
// wpt[l][j][k], j in 0..383: j<128 -> p1[k][j]; j<256 -> p2[k][j-128]; else psi[k][j-256]
__global__ __launch_bounds__(256) void prep_nodew(
    const float* __restrict__ Wg, const float* __restrict__ Wm,
    const float* __restrict__ p1, const float* __restrict__ p2, const float* __restrict__ psiW,
    unsigned short* __restrict__ wnt, unsigned short* __restrict__ wpt)
{
  int idx = blockIdx.x*256 + threadIdx.x;
  if (idx < 3*98304) {
    int l = idx / 98304, r = idx % 98304;
    int j = r >> 7, k = r & 127;
    float v;
    if (j < 384) v = Wg[l*49152 + (j>>7)*16384 + k*128 + (j&127)];
    else { int jj = j - 384; v = Wm[l*49152 + (jj>>7)*16384 + k*128 + (jj&127)]; }
    wnt[idx] = f2bf(v);
  } else {
    int idx2 = idx - 3*98304;
    if (idx2 < 3*49152) {
      int l = idx2 / 49152, r = idx2 % 49152;
      int j = r >> 7, k = r & 127;
      float v;
      if (j < 128)      v = p1 [l*16384 + k*128 + j];
      else if (j < 256) v = p2 [l*16384 + k*128 + (j-128)];
      else              v = psiW[l*16384 + k*128 + (j-256)];
      wpt[idx2] = f2bf(v);
    }
  }
}

// ---------------- nodeA (MFMA): pack[n][0..767] = h@[Wg||Wm] slices ----------------
// block = 64 nodes (4 waves x 16), N=768 in 6 chunks of 8 col-tiles
__global__ __launch_bounds__(256) void nodeA_mfma(
    const float* __restrict__ h, const unsigned short* __restrict__ wnt,
    float* __restrict__ pack)
{
  int tid = threadIdx.x, wave = tid >> 6, lane = tid & 63;
  int row = lane & 15, kg = lane >> 4;
  int nbase = blockIdx.x*64 + wave*16;
  int nA = nbase + row;
  int nclamp = nA < N_NODES ? nA : N_NODES-1;
  const float* hr = &h[(size_t)nclamp*H];
  s16x8 a[4];
  #pragma unroll
  for (int ks = 0; ks < 4; ks++) a[ks] = loadA_f32(hr + ks*32 + kg*8);

  #pragma unroll
  for (int ch = 0; ch < 6; ch++) {
    f32x4 acc[8];
    #pragma unroll
    for (int t = 0; t < 8; t++) { acc[t][0]=0.f; acc[t][1]=0.f; acc[t][2]=0.f; acc[t][3]=0.f; }
    #pragma unroll
    for (int t = 0; t < 8; t++) {
      int col = (ch*8 + t)*16 + row;
      #pragma unroll
      for (int ks = 0; ks < 4; ks++) {
        s16x8 b = *(const s16x8*)&wnt[(size_t)col*128 + ks*32 + kg*8];
        acc[t] = MFMA16(a[ks], b, acc[t]);
      }
    }
    #pragma unroll
    for (int t = 0; t < 8; t++) {
      int col = (ch*8 + t)*16 + row;
      #pragma unroll
      for (int r = 0; r < 4; r++) {
        int nc = nbase + kg*4 + r;
        if (nc < N_NODES) pack[(size_t)nc*768 + col] = acc[t][r];
      }
    }
  }
}

// ---------------- zgemm (MFMA): az = cs@W1 + (pw*sig(pw@W2g))@W2, bf16 out ----------------
__global__ __launch_bounds__(256) void zgemm_mfma(
    const float* __restrict__ cs, const float* __restrict__ pw,
    const unsigned short* __restrict__ w1t, const unsigned short* __restrict__ w2t,
    const unsigned short* __restrict__ w2gt,
    const int* __restrict__ perm, unsigned short* __restrict__ azb)
{
  __shared__ unsigned short gate[64*64];   // sig(pw@W2g), XOR-swizzled

  int tid  = threadIdx.x;
  int wave = tid >> 6, lane = tid & 63;
  int row  = lane & 15, kg = lane >> 4;
  int p0   = blockIdx.x * 64;

  int pos = p0 + wave*16 + row;
  int pe  = perm[pos];
  const float* csr = &cs[(size_t)pe*64];
  const float* pwr = &pw[(size_t)pe*64];

  s16x8 acs[2], apw[2];
  acs[0] = loadA_f32(csr + kg*8);
  acs[1] = loadA_f32(csr + 32 + kg*8);
  apw[0] = loadA_f32(pwr + kg*8);
  apw[1] = loadA_f32(pwr + 32 + kg*8);

  // phase 1: S1 = pw @ W2g
  f32x4 acc1[4];
  #pragma unroll
  for (int nt = 0; nt < 4; nt++) { acc1[nt][0]=0.f; acc1[nt][1]=0.f; acc1[nt][2]=0.f; acc1[nt][3]=0.f; }
  #pragma unroll
  for (int nt = 0; nt < 4; nt++) {
    s16x8 b0 = *(const s16x8*)&w2gt[(size_t)(nt*16+row)*64 + kg*8];
    s16x8 b1 = *(const s16x8*)&w2gt[(size_t)(nt*16+row)*64 + 32 + kg*8];
    acc1[nt] = MFMA16(apw[0], b0, acc1[nt]);
    acc1[nt] = MFMA16(apw[1], b1, acc1[nt]);
  }

  // sigmoid -> gate LDS (C-layout scatter write, swizzled)
  #pragma unroll
  for (int nt = 0; nt < 4; nt++) {
    #pragma unroll
    for (int r = 0; r < 4; r++) {
      int grow = wave*16 + kg*4 + r;
      int gcol = nt*16 + row;
      int byt = (grow << 7) + (gcol << 1);
      byt ^= (grow & 7) << 4;
      *(unsigned short*)((char*)gate + byt) = f2bf(sigf(acc1[nt][r]));
    }
  }
  __syncthreads();

  // read gate in A-layout (b128), pwg frags = pw * gate
  s16x8 apg[2];
  #pragma unroll
  for (int ks = 0; ks < 2; ks++) {
    int arow = wave*16 + row;
    int byt = (arow << 7) + ks*64 + kg*16;
    byt ^= (arow & 7) << 4;
    s16x8 g = *(s16x8*)((char*)gate + byt);
    s16x8 o;
    #pragma unroll
    for (int j = 0; j < 8; j++) {
      float v = bf2f((unsigned short)apw[ks][j]) * bf2f((unsigned short)g[j]);
      o[j] = (short)f2bf(v);
    }
    apg[ks] = o;
  }

  // phase 2: az = cs@W1t + pwg@W2t
  f32x4 acc2[8];
  #pragma unroll
  for (int nt = 0; nt < 8; nt++) { acc2[nt][0]=0.f; acc2[nt][1]=0.f; acc2[nt][2]=0.f; acc2[nt][3]=0.f; }
  #pragma unroll
  for (int nt = 0; nt < 8; nt++) {
    #pragma unroll
    for (int ks = 0; ks < 2; ks++) {
      s16x8 b1 = *(const s16x8*)&w1t[(size_t)(nt*16+row)*64 + ks*32 + kg*8];
      acc2[nt] = MFMA16(acs[ks], b1, acc2[nt]);
      s16x8 b2 = *(const s16x8*)&w2t[(size_t)(nt*16+row)*64 + ks*32 + kg*8];
      acc2[nt] = MFMA16(apg[ks], b2, acc2[nt]);
    }
  }

  // store bf16 az
  #pragma unroll
  for (int nt = 0; nt < 8; nt++) {
    #pragma unroll
    for (int r = 0; r < 4; r++) {
      int crow = kg*4 + r;
      azb[(size_t)(p0 + wave*16 + crow)*H + nt*16 + row] = f2bf(acc2[nt][r]);
    }
  }
}

// ---------------- combine: per src node, sum z over its edges, h_b = h_a + sum ----------------
__global__ __launch_bounds__(256) void combine_kernel(
    const float* __restrict__ h_in, float* __restrict__ h_out,
    const float* __restrict__ ed, const int* __restrict__ tgt,
    const int* __restrict__ offsets, const int* __restrict__ perm,
    const unsigned short* __restrict__ azb,
    const float* __restrict__ pack)
{
  int tid = threadIdx.x;
  int unit = blockIdx.x*2 + (tid >> 7);
  int c = tid & 127;
  int n0 = unit * 4;
  for (int n = n0; n < n0 + 4; n++) {
    const float* pn = &pack[(size_t)n*768 + c];
    float Ags = pn[0], Cgs = pn[256], Ams = pn[384], Cms = pn[640];
    float acc = 0.f;
    int beg = offsets[n], end = offsets[n+1];
    for (int pos = beg; pos < end; pos += 4) {
      int bsz = end - pos; if (bsz > 4) bsz = 4;
      float azv[4], Bg[4], Cg[4], Bm[4], Cm[4], rc[4], mk[4];
      #pragma unroll
      for (int b = 0; b < 4; b++) {
        if (b < bsz) {
          int e = perm[pos + b];
          int tn = tgt[e];
          float r = ed[e];
          rc[b] = 1.0f / r;
          mk[b] = (r < 8.0f) ? 1.0f : 0.0f;
          azv[b] = bf2f(azb[(size_t)(pos + b)*H + c]);
          const float* tp = &pack[(size_t)tn*768 + c];
          Bg[b] = tp[128]; Cg[b] = tp[256]; Bm[b] = tp[512]; Cm[b] = tp[640];
        }
      }
      #pragma unroll
      for (int b = 0; b < 4; b++) {
        if (b < bsz) {
          float g = sigf(Ags + Bg[b] + rc[b]*(Cgs - Cg[b]));
          float m = eluf(Ams + Bm[b] + rc[b]*(Cms - Cm[b]));
          acc += g * m * azv[b] * mk[b];
        }
      }
    }
    h_out[(size_t)n*H + c] = h_in[(size_t)n*H + c] + acc;
  }
}

// ---------------- node (MFMA): zp=elu((h@p1)*(h@p2)) -> pooled; h_out=elu(h@psi) ----------------
__global__ __launch_bounds__(256) void node_mfma(
    const float* __restrict__ h_in, const unsigned short* __restrict__ wpt,
    const int* __restrict__ gidx, float* __restrict__ pooled, float* __restrict__ h_out)
{
  int tid = threadIdx.x, wave = tid >> 6, lane = tid & 63;
  int row = lane & 15, kg = lane >> 4;
  int nbase = blockIdx.x*64 + wave*16;
  int nA = nbase + row;
  int nclamp = nA < N_NODES ? nA : N_NODES-1;
  const float* hr = &h_in[(size_t)nclamp*H];
  s16x8 a[4];
  #pragma unroll
  for (int ks = 0; ks < 4; ks++) a[ks] = loadA_f32(hr + ks*32 + kg*8);

  f32x4 acc1[8], acc2[8], acc3[8];
  #pragma unroll
  for (int t = 0; t < 8; t++) {
    #pragma unroll
    for (int r = 0; r < 4; r++) { acc1[t][r]=0.f; acc2[t][r]=0.f; acc3[t][r]=0.f; }
  }
  #pragma unroll
  for (int t = 0; t < 8; t++) {
    int col = t*16 + row;
    #pragma unroll
    for (int ks = 0; ks < 4; ks++) {
      s16x8 b1 = *(const s16x8*)&wpt[(size_t)(col      )*128 + ks*32 + kg*8];
      s16x8 b2 = *(const s16x8*)&wpt[(size_t)(col + 128)*128 + ks*32 + kg*8];
      s16x8 b3 = *(const s16x8*)&wpt[(size_t)(col + 256)*128 + ks*32 + kg*8];
      acc1[t] = MFMA16(a[ks], b1, acc1[t]);
      acc2[t] = MFMA16(a[ks], b2, acc2[t]);
      acc3[t] = MFMA16(a[ks], b3, acc3[t]);
    }
  }

  #pragma unroll
  for (int r = 0; r < 4; r++) {
    int nc = nbase + kg*4 + r;
    if (nc >= N_NODES) continue;
    int g = gidx[nc];
    #pragma unroll
    for (int t = 0; t < 8; t++) {
      int col = t*16 + row;
      float zp = eluf(acc1[t][r] * acc2[t][r]);
      atomicAdd(&pooled[g*H + col], zp);
      h_out[(size_t)nc*H + col] = eluf(acc3[t][r]);
    }
  }
}

// ---------------- final: y = elu(elu(pooled @ lr1) @ lr2) ----------------
__global__ __launch_bounds__(64) void final_kernel(
    const float* __restrict__ pooled, const float* __restrict__ lr1, const float* __restrict__ lr2,
    float* __restrict__ out)
{
  __shared__ float sp[128];
  __shared__ float y1[64];
  int g = blockIdx.x, tid = threadIdx.x;
  sp[tid]      = pooled[g*128 + tid];
  sp[tid + 64] = pooled[g*128 + 64 + tid];
  __syncthreads();
  float acc = 0.f;
  for (int k = 0; k < 128; k++) acc += sp[k] * lr1[k*64 + tid];
  y1[tid] = eluf(acc);
  __syncthreads();
  if (tid < 32) {
    float a2 = 0.f;
    for (int k = 0; k < 64; k++) a2 += y1[k] * lr2[k*32 + tid];
    out[g*32 + tid] = eluf(a2);
  }
}

extern "C" void kernel_launch(void* const* d_in, const int* in_sizes, int n_in,
                              void* d_out, int out_size, void* d_ws, size_t ws_size,
                              hipStream_t stream)
{
  const float* x    = (const float*)d_in[0];
  const float* ed   = (const float*)d_in[1];
  const float* cs   = (const float*)d_in[2];
  const float* pw   = (const float*)d_in[3];
  const float* embW = (const float*)d_in[4];
  const float* Wg   = (const float*)d_in[5];
  const float* Wm   = (const float*)d_in[6];
  const float* W1   = (const float*)d_in[7];
  const float* W2g  = (const float*)d_in[8];
  const float* W2   = (const float*)d_in[9];
  const float* p1   = (const float*)d_in[10];
  const float* p2   = (const float*)d_in[11];
  const float* psiW = (const float*)d_in[12];
  const float* lr1  = (const float*)d_in[13];
  const float* lr2  = (const float*)d_in[14];
  const int* esrc   = (const int*)d_in[15];
  const int* etgt   = (const int*)d_in[16];
  const int* gidx   = (const int*)d_in[17];

  float* h_a    = (float*)d_ws;                 // 1,280,000 f
  float* h_b    = h_a + (size_t)N_NODES*H;      // 1,280,000 f
  float* pooled = h_b + (size_t)N_NODES*H;      // 12,800 f
  float* pack   = pooled + 100*H;               // 7,680,000 f
  unsigned short* azb = (unsigned short*)(pack + (size_t)N_NODES*768); // 20,480,000 us
  int* counts  = (int*)(azb + (size_t)N_EDGES*H);
  int* offsets = counts + N_NODES;              // N_NODES+1
  int* cursor  = offsets + N_NODES + 1;
  int* perm    = cursor + N_NODES;              // N_EDGES
  unsigned short* w1t  = (unsigned short*)(perm + N_EDGES); // 3*8192
  unsigned short* w2t  = w1t + 3*8192;
  unsigned short* w2gt = w2t + 3*8192;          // 3*4096
  unsigned short* wnt  = w2gt + 3*4096;         // 3*98304
  unsigned short* wpt  = wnt + 3*98304;         // 3*49152

  // one-time: edge sort by src + weight transposes
  hipMemsetAsync(counts, 0, N_NODES*sizeof(int), stream);
  hipMemsetAsync(pooled, 0, 100*H*sizeof(float), stream);
  hist_kernel<<<(N_EDGES+255)/256, 256, 0, stream>>>(esrc, counts);
  scan_kernel<<<1, 256, 0, stream>>>(counts, offsets);
  hipMemcpyAsync(cursor, offsets, N_NODES*sizeof(int), hipMemcpyDeviceToDevice, stream);
  scatter_kernel<<<(N_EDGES+255)/256, 256, 0, stream>>>(esrc, cursor, perm);
  prep_weights<<<144, 256, 0, stream>>>(W1, W2, W2g, w1t, w2t, w2gt);
  prep_nodew<<<(3*98304 + 3*49152 + 255)/256, 256, 0, stream>>>(Wg, Wm, p1, p2, psiW, wnt, wpt);

  embed_kernel<<<625, 256, 0, stream>>>(x, embW, h_a);

  for (int i = 0; i < 3; i++) {
    nodeA_mfma<<<(N_NODES+63)/64, 256, 0, stream>>>(h_a, wnt + i*98304, pack);
    zgemm_mfma<<<N_EDGES/64, 256, 0, stream>>>(cs, pw,
        w1t + i*8192, w2t + i*8192, w2gt + i*4096, perm, azb);
    combine_kernel<<<N_NODES/8, 256, 0, stream>>>(h_a, h_b, ed, etgt,
        offsets, perm, azb, pack);
    node_mfma<<<(N_NODES+63)/64, 256, 0, stream>>>(h_b, wpt + i*49152, gidx, pooled, h_a);
  }
  final_kernel<<<100, 64, 0, stream>>>(pooled, lr1, lr2, (float*)d_out);
}

// Round 6
// 603.975 us; speedup vs baseline: 11.0808x; 1.2078x over previous
//
#include <hip/hip_runtime.h>
#include <math.h>

#define H 128
#define N_NODES 10000
#define N_EDGES 160000

typedef float f32x4 __attribute__((ext_vector_type(4)));
typedef short s16x8 __attribute__((ext_vector_type(8)));

__device__ __forceinline__ float sigf(float x){ return 1.0f/(1.0f + __expf(-x)); }
__device__ __forceinline__ float eluf(float x){ return x > 0.0f ? x : (__expf(x) - 1.0f); }

__device__ __forceinline__ unsigned short f2bf(float f){
  unsigned int u = __float_as_uint(f);
  unsigned int r = (u + 0x7fffu + ((u >> 16) & 1u)) >> 16;
  return (unsigned short)r;
}
__device__ __forceinline__ float bf2f(unsigned short s){
  return __uint_as_float(((unsigned int)s) << 16);
}

__device__ __forceinline__ f32x4 MFMA16(s16x8 a, s16x8 b, f32x4 c){
  return __builtin_amdgcn_mfma_f32_16x16x32_bf16(a, b, c, 0, 0, 0);
}

__device__ __forceinline__ s16x8 loadA_f32(const float* p){
  float4 a = *(const float4*)p;
  float4 b = *(const float4*)(p+4);
  s16x8 r;
  r[0]=(short)f2bf(a.x); r[1]=(short)f2bf(a.y); r[2]=(short)f2bf(a.z); r[3]=(short)f2bf(a.w);
  r[4]=(short)f2bf(b.x); r[5]=(short)f2bf(b.y); r[6]=(short)f2bf(b.z); r[7]=(short)f2bf(b.w);
  return r;
}

// ---------------- embed: h = sigmoid(x @ emb_W), 16 nodes/block ----------------
__global__ __launch_bounds__(256) void embed_kernel(
    const float* __restrict__ x, const float* __restrict__ W, float* __restrict__ h_out)
{
  __shared__ float xs[16][129];
  int tid = threadIdx.x;
  int n0 = blockIdx.x * 16;
  for (int idx = tid; idx < 16*128; idx += 256) {
    int n = idx >> 7, k = idx & 127;
    xs[n][k] = x[(size_t)(n0+n)*H + k];
  }
  __syncthreads();
  int n = tid >> 4, c0 = (tid & 15) * 8;
  float acc[8];
  #pragma unroll
  for (int j = 0; j < 8; j++) acc[j] = 0.f;
  for (int k = 0; k < 128; k++) {
    float f = xs[n][k];
    float w[8];
    *(float4*)&w[0] = *(const float4*)&W[k*H + c0];
    *(float4*)&w[4] = *(const float4*)&W[k*H + c0 + 4];
    #pragma unroll
    for (int j = 0; j < 8; j++) acc[j] += f * w[j];
  }
  float o[8];
  #pragma unroll
  for (int j = 0; j < 8; j++) o[j] = sigf(acc[j]);
  float* dst = &h_out[(size_t)(n0+n)*H + c0];
  *(float4*)&dst[0] = *(float4*)&o[0];
  *(float4*)&dst[4] = *(float4*)&o[4];
}

// ---------------- edge sort by src: hist -> scan -> scatter ----------------
__global__ __launch_bounds__(256) void hist_kernel(
    const int* __restrict__ src, int* __restrict__ count)
{
  int e = blockIdx.x*256 + threadIdx.x;
  if (e < N_EDGES) atomicAdd(&count[src[e]], 1);
}

__global__ __launch_bounds__(256) void scan_kernel(
    const int* __restrict__ count, int* __restrict__ offsets)
{
  __shared__ int tmp[256];
  __shared__ int sbase;
  if (threadIdx.x == 0) sbase = 0;
  __syncthreads();
  for (int c0 = 0; c0 < N_NODES; c0 += 256) {
    int i = c0 + threadIdx.x;
    int v = (i < N_NODES) ? count[i] : 0;
    tmp[threadIdx.x] = v;
    __syncthreads();
    for (int off = 1; off < 256; off <<= 1) {
      int t = (threadIdx.x >= off) ? tmp[threadIdx.x - off] : 0;
      __syncthreads();
      tmp[threadIdx.x] += t;
      __syncthreads();
    }
    if (i < N_NODES) offsets[i] = sbase + tmp[threadIdx.x] - v;
    __syncthreads();
    if (threadIdx.x == 255) sbase += tmp[255];
    __syncthreads();
  }
  if (threadIdx.x == 0) offsets[N_NODES] = sbase;
}

// scatter + de-indirect: perm (for zgemm), permuted tgt and edge_distance (for combine)
__global__ __launch_bounds__(256) void scatter_kernel(
    const int* __restrict__ src, const int* __restrict__ tgt, const float* __restrict__ ed,
    int* __restrict__ cursor, int* __restrict__ perm,
    int* __restrict__ tgtp, float* __restrict__ edp)
{
  int e = blockIdx.x*256 + threadIdx.x;
  if (e < N_EDGES) {
    int pos = atomicAdd(&cursor[src[e]], 1);
    perm[pos] = e;
    tgtp[pos] = tgt[e];
    edp[pos]  = ed[e];
  }
}

// ---------------- prep_weights: transpose W1,W2 (64x128) and W2g (64x64) to bf16 [col][k] ----------------
__global__ __launch_bounds__(256) void prep_weights(
    const float* __restrict__ W1, const float* __restrict__ W2, const float* __restrict__ W2g,
    unsigned short* __restrict__ w1t, unsigned short* __restrict__ w2t, unsigned short* __restrict__ w2gt)
{
  int idx = blockIdx.x*256 + threadIdx.x;
  if (idx < 3*8192) {
    int l = idx / 8192, r = idx % 8192;
    int c = r >> 6, k = r & 63;
    w1t[idx] = f2bf(W1[l*8192 + k*128 + c]);
    w2t[idx] = f2bf(W2[l*8192 + k*128 + c]);
  }
  int idx2 = idx - 3*8192;
  if (idx2 >= 0 && idx2 < 3*4096) {
    int l = idx2 / 4096, r = idx2 % 4096;
    int c = r >> 6, k = r & 63;
    w2gt[idx2] = f2bf(W2g[l*4096 + k*64 + c]);
  }
}

// ---------------- prep_nodew: bf16 [col][k] transposes for node GEMMs ----------------
__global__ __launch_bounds__(256) void prep_nodew(
    const float* __restrict__ Wg, const float* __restrict__ Wm,
    const float* __restrict__ p1, const float* __restrict__ p2, const float* __restrict__ psiW,
    unsigned short* __restrict__ wnt, unsigned short* __restrict__ wpt)
{
  int idx = blockIdx.x*256 + threadIdx.x;
  if (idx < 3*98304) {
    int l = idx / 98304, r = idx % 98304;
    int j = r >> 7, k = r & 127;
    float v;
    if (j < 384) v = Wg[l*49152 + (j>>7)*16384 + k*128 + (j&127)];
    else { int jj = j - 384; v = Wm[l*49152 + (jj>>7)*16384 + k*128 + (jj&127)]; }
    wnt[idx] = f2bf(v);
  } else {
    int idx2 = idx - 3*98304;
    if (idx2 < 3*49152) {
      int l = idx2 / 49152, r = idx2 % 49152;
      int j = r >> 7, k = r & 127;
      float v;
      if (j < 128)      v = p1 [l*16384 + k*128 + j];
      else if (j < 256) v = p2 [l*16384 + k*128 + (j-128)];
      else              v = psiW[l*16384 + k*128 + (j-256)];
      wpt[idx2] = f2bf(v);
    }
  }
}

// ---------------- nodeA (MFMA): bf16 interleaved pack tables ----------------
// chunk ch -> slice: 0=Ag(s0) 1=Bg(t0) 2=Cg(s1,t1) 3=Am(s2) 4=Bm(t2) 5=Cm(s3,t3)
// spackb[n][c][4] = {Ag,Cg,Am,Cm}; tpackb[n][c][4] = {Bg,Cg,Bm,Cm}
__global__ __launch_bounds__(256) void nodeA_mfma(
    const float* __restrict__ h, const unsigned short* __restrict__ wnt,
    unsigned short* __restrict__ spackb, unsigned short* __restrict__ tpackb)
{
  int tid = threadIdx.x, wave = tid >> 6, lane = tid & 63;
  int row = lane & 15, kg = lane >> 4;
  int nbase = blockIdx.x*64 + wave*16;
  int nA = nbase + row;
  int nclamp = nA < N_NODES ? nA : N_NODES-1;
  const float* hr = &h[(size_t)nclamp*H];
  s16x8 a[4];
  #pragma unroll
  for (int ks = 0; ks < 4; ks++) a[ks] = loadA_f32(hr + ks*32 + kg*8);

  #pragma unroll
  for (int ch = 0; ch < 6; ch++) {
    f32x4 acc[8];
    #pragma unroll
    for (int t = 0; t < 8; t++) { acc[t][0]=0.f; acc[t][1]=0.f; acc[t][2]=0.f; acc[t][3]=0.f; }
    #pragma unroll
    for (int t = 0; t < 8; t++) {
      int col = (ch*8 + t)*16 + row;
      #pragma unroll
      for (int ks = 0; ks < 4; ks++) {
        s16x8 b = *(const s16x8*)&wnt[(size_t)col*128 + ks*32 + kg*8];
        acc[t] = MFMA16(a[ks], b, acc[t]);
      }
    }
    #pragma unroll
    for (int t = 0; t < 8; t++) {
      int c = t*16 + row;   // 0..127 within slice
      #pragma unroll
      for (int r = 0; r < 4; r++) {
        int nc = nbase + kg*4 + r;
        if (nc >= N_NODES) continue;
        unsigned short bv = f2bf(acc[t][r]);
        size_t base = (size_t)nc*512 + c*4;
        if (ch == 0)      spackb[base + 0] = bv;
        else if (ch == 1) tpackb[base + 0] = bv;
        else if (ch == 2) { spackb[base + 1] = bv; tpackb[base + 1] = bv; }
        else if (ch == 3) spackb[base + 2] = bv;
        else if (ch == 4) tpackb[base + 2] = bv;
        else              { spackb[base + 3] = bv; tpackb[base + 3] = bv; }
      }
    }
  }
}

// ---------------- zgemm (MFMA): az = cs@W1 + (pw*sig(pw@W2g))@W2, bf16 out ----------------
__global__ __launch_bounds__(256) void zgemm_mfma(
    const float* __restrict__ cs, const float* __restrict__ pw,
    const unsigned short* __restrict__ w1t, const unsigned short* __restrict__ w2t,
    const unsigned short* __restrict__ w2gt,
    const int* __restrict__ perm, unsigned short* __restrict__ azb)
{
  __shared__ unsigned short gate[64*64];   // sig(pw@W2g), XOR-swizzled

  int tid  = threadIdx.x;
  int wave = tid >> 6, lane = tid & 63;
  int row  = lane & 15, kg = lane >> 4;
  int p0   = blockIdx.x * 64;

  int pos = p0 + wave*16 + row;
  int pe  = perm[pos];
  const float* csr = &cs[(size_t)pe*64];
  const float* pwr = &pw[(size_t)pe*64];

  s16x8 acs[2], apw[2];
  acs[0] = loadA_f32(csr + kg*8);
  acs[1] = loadA_f32(csr + 32 + kg*8);
  apw[0] = loadA_f32(pwr + kg*8);
  apw[1] = loadA_f32(pwr + 32 + kg*8);

  // phase 1: S1 = pw @ W2g
  f32x4 acc1[4];
  #pragma unroll
  for (int nt = 0; nt < 4; nt++) { acc1[nt][0]=0.f; acc1[nt][1]=0.f; acc1[nt][2]=0.f; acc1[nt][3]=0.f; }
  #pragma unroll
  for (int nt = 0; nt < 4; nt++) {
    s16x8 b0 = *(const s16x8*)&w2gt[(size_t)(nt*16+row)*64 + kg*8];
    s16x8 b1 = *(const s16x8*)&w2gt[(size_t)(nt*16+row)*64 + 32 + kg*8];
    acc1[nt] = MFMA16(apw[0], b0, acc1[nt]);
    acc1[nt] = MFMA16(apw[1], b1, acc1[nt]);
  }

  // sigmoid -> gate LDS (C-layout scatter write, swizzled)
  #pragma unroll
  for (int nt = 0; nt < 4; nt++) {
    #pragma unroll
    for (int r = 0; r < 4; r++) {
      int grow = wave*16 + kg*4 + r;
      int gcol = nt*16 + row;
      int byt = (grow << 7) + (gcol << 1);
      byt ^= (grow & 7) << 4;
      *(unsigned short*)((char*)gate + byt) = f2bf(sigf(acc1[nt][r]));
    }
  }
  __syncthreads();

  // read gate in A-layout (b128), pwg frags = pw * gate
  s16x8 apg[2];
  #pragma unroll
  for (int ks = 0; ks < 2; ks++) {
    int arow = wave*16 + row;
    int byt = (arow << 7) + ks*64 + kg*16;
    byt ^= (arow & 7) << 4;
    s16x8 g = *(s16x8*)((char*)gate + byt);
    s16x8 o;
    #pragma unroll
    for (int j = 0; j < 8; j++) {
      float v = bf2f((unsigned short)apw[ks][j]) * bf2f((unsigned short)g[j]);
      o[j] = (short)f2bf(v);
    }
    apg[ks] = o;
  }

  // phase 2: az = cs@W1t + pwg@W2t
  f32x4 acc2[8];
  #pragma unroll
  for (int nt = 0; nt < 8; nt++) { acc2[nt][0]=0.f; acc2[nt][1]=0.f; acc2[nt][2]=0.f; acc2[nt][3]=0.f; }
  #pragma unroll
  for (int nt = 0; nt < 8; nt++) {
    #pragma unroll
    for (int ks = 0; ks < 2; ks++) {
      s16x8 b1 = *(const s16x8*)&w1t[(size_t)(nt*16+row)*64 + ks*32 + kg*8];
      acc2[nt] = MFMA16(acs[ks], b1, acc2[nt]);
      s16x8 b2 = *(const s16x8*)&w2t[(size_t)(nt*16+row)*64 + ks*32 + kg*8];
      acc2[nt] = MFMA16(apg[ks], b2, acc2[nt]);
    }
  }

  // store bf16 az
  #pragma unroll
  for (int nt = 0; nt < 8; nt++) {
    #pragma unroll
    for (int r = 0; r < 4; r++) {
      int crow = kg*4 + r;
      azb[(size_t)(p0 + wave*16 + crow)*H + nt*16 + row] = f2bf(acc2[nt][r]);
    }
  }
}

// ---------------- combine v2: 1 wave per node, lane = 2 cols ----------------
__global__ __launch_bounds__(256) void combine_kernel(
    const float* __restrict__ h_in, float* __restrict__ h_out,
    const float* __restrict__ edp, const int* __restrict__ tgtp,
    const int* __restrict__ offsets,
    const unsigned short* __restrict__ azb,
    const unsigned short* __restrict__ spackb, const unsigned short* __restrict__ tpackb)
{
  int tid = threadIdx.x;
  int n = blockIdx.x*4 + (tid >> 6);
  if (n >= N_NODES) return;
  int l = tid & 63;

  s16x8 sp = *(const s16x8*)&spackb[(size_t)n*512 + l*8];
  float Ags0 = bf2f((unsigned short)sp[0]), Cgs0 = bf2f((unsigned short)sp[1]);
  float Ams0 = bf2f((unsigned short)sp[2]), Cms0 = bf2f((unsigned short)sp[3]);
  float Ags1 = bf2f((unsigned short)sp[4]), Cgs1 = bf2f((unsigned short)sp[5]);
  float Ams1 = bf2f((unsigned short)sp[6]), Cms1 = bf2f((unsigned short)sp[7]);

  float acc0 = 0.f, acc1 = 0.f;
  int beg = offsets[n], end = offsets[n+1];
  for (int pos = beg; pos < end; pos += 4) {
    int bsz = end - pos; if (bsz > 4) bsz = 4;
    s16x8 tp[4]; ushort2 az[4]; float rc[4], mk[4];
    #pragma unroll
    for (int b = 0; b < 4; b++) {
      if (b < bsz) {
        int tn = tgtp[pos + b];
        float r = edp[pos + b];
        rc[b] = 1.0f / r;
        mk[b] = (r < 8.0f) ? 1.0f : 0.0f;
        tp[b] = *(const s16x8*)&tpackb[(size_t)tn*512 + l*8];
        az[b] = *(const ushort2*)&azb[(size_t)(pos + b)*H + 2*l];
      }
    }
    #pragma unroll
    for (int b = 0; b < 4; b++) {
      if (b < bsz) {
        float Bg0 = bf2f((unsigned short)tp[b][0]), Cg0 = bf2f((unsigned short)tp[b][1]);
        float Bm0 = bf2f((unsigned short)tp[b][2]), Cm0 = bf2f((unsigned short)tp[b][3]);
        float Bg1 = bf2f((unsigned short)tp[b][4]), Cg1 = bf2f((unsigned short)tp[b][5]);
        float Bm1 = bf2f((unsigned short)tp[b][6]), Cm1 = bf2f((unsigned short)tp[b][7]);
        float g0 = sigf(Ags0 + Bg0 + rc[b]*(Cgs0 - Cg0));
        float m0 = eluf(Ams0 + Bm0 + rc[b]*(Cms0 - Cm0));
        acc0 += g0 * m0 * bf2f(az[b].x) * mk[b];
        float g1 = sigf(Ags1 + Bg1 + rc[b]*(Cgs1 - Cg1));
        float m1 = eluf(Ams1 + Bm1 + rc[b]*(Cms1 - Cm1));
        acc1 += g1 * m1 * bf2f(az[b].y) * mk[b];
      }
    }
  }
  size_t o = (size_t)n*H + 2*l;
  h_out[o]     = h_in[o]     + acc0;
  h_out[o + 1] = h_in[o + 1] + acc1;
}

// ---------------- node (MFMA): zp=elu((h@p1)*(h@p2)) -> pooled; h_out=elu(h@psi) ----------------
__global__ __launch_bounds__(256) void node_mfma(
    const float* __restrict__ h_in, const unsigned short* __restrict__ wpt,
    const int* __restrict__ gidx, float* __restrict__ pooled, float* __restrict__ h_out)
{
  int tid = threadIdx.x, wave = tid >> 6, lane = tid & 63;
  int row = lane & 15, kg = lane >> 4;
  int nbase = blockIdx.x*64 + wave*16;
  int nA = nbase + row;
  int nclamp = nA < N_NODES ? nA : N_NODES-1;
  const float* hr = &h_in[(size_t)nclamp*H];
  s16x8 a[4];
  #pragma unroll
  for (int ks = 0; ks < 4; ks++) a[ks] = loadA_f32(hr + ks*32 + kg*8);

  f32x4 acc1[8], acc2[8], acc3[8];
  #pragma unroll
  for (int t = 0; t < 8; t++) {
    #pragma unroll
    for (int r = 0; r < 4; r++) { acc1[t][r]=0.f; acc2[t][r]=0.f; acc3[t][r]=0.f; }
  }
  #pragma unroll
  for (int t = 0; t < 8; t++) {
    int col = t*16 + row;
    #pragma unroll
    for (int ks = 0; ks < 4; ks++) {
      s16x8 b1 = *(const s16x8*)&wpt[(size_t)(col      )*128 + ks*32 + kg*8];
      s16x8 b2 = *(const s16x8*)&wpt[(size_t)(col + 128)*128 + ks*32 + kg*8];
      s16x8 b3 = *(const s16x8*)&wpt[(size_t)(col + 256)*128 + ks*32 + kg*8];
      acc1[t] = MFMA16(a[ks], b1, acc1[t]);
      acc2[t] = MFMA16(a[ks], b2, acc2[t]);
      acc3[t] = MFMA16(a[ks], b3, acc3[t]);
    }
  }

  int nc0 = nbase + kg*4;
  int g0 = (nc0     < N_NODES) ? gidx[nc0]     : -1;
  int g3 = (nc0 + 3 < N_NODES) ? gidx[nc0 + 3] : -2;
  if (g0 == g3) {
    // common case: all 4 nodes in range, same graph -> 1 atomic per col
    #pragma unroll
    for (int t = 0; t < 8; t++) {
      int col = t*16 + row;
      float s = 0.f;
      #pragma unroll
      for (int r = 0; r < 4; r++) s += eluf(acc1[t][r] * acc2[t][r]);
      atomicAdd(&pooled[g0*H + col], s);
      #pragma unroll
      for (int r = 0; r < 4; r++)
        h_out[(size_t)(nc0 + r)*H + col] = eluf(acc3[t][r]);
    }
  } else {
    #pragma unroll
    for (int r = 0; r < 4; r++) {
      int nc = nc0 + r;
      if (nc >= N_NODES) continue;
      int g = gidx[nc];
      #pragma unroll
      for (int t = 0; t < 8; t++) {
        int col = t*16 + row;
        float zp = eluf(acc1[t][r] * acc2[t][r]);
        atomicAdd(&pooled[g*H + col], zp);
        h_out[(size_t)nc*H + col] = eluf(acc3[t][r]);
      }
    }
  }
}

// ---------------- final: y = elu(elu(pooled @ lr1) @ lr2) ----------------
__global__ __launch_bounds__(64) void final_kernel(
    const float* __restrict__ pooled, const float* __restrict__ lr1, const float* __restrict__ lr2,
    float* __restrict__ out)
{
  __shared__ float sp[128];
  __shared__ float y1[64];
  int g = blockIdx.x, tid = threadIdx.x;
  sp[tid]      = pooled[g*128 + tid];
  sp[tid + 64] = pooled[g*128 + 64 + tid];
  __syncthreads();
  float acc = 0.f;
  for (int k = 0; k < 128; k++) acc += sp[k] * lr1[k*64 + tid];
  y1[tid] = eluf(acc);
  __syncthreads();
  if (tid < 32) {
    float a2 = 0.f;
    for (int k = 0; k < 64; k++) a2 += y1[k] * lr2[k*32 + tid];
    out[g*32 + tid] = eluf(a2);
  }
}

extern "C" void kernel_launch(void* const* d_in, const int* in_sizes, int n_in,
                              void* d_out, int out_size, void* d_ws, size_t ws_size,
                              hipStream_t stream)
{
  const float* x    = (const float*)d_in[0];
  const float* ed   = (const float*)d_in[1];
  const float* cs   = (const float*)d_in[2];
  const float* pw   = (const float*)d_in[3];
  const float* embW = (const float*)d_in[4];
  const float* Wg   = (const float*)d_in[5];
  const float* Wm   = (const float*)d_in[6];
  const float* W1   = (const float*)d_in[7];
  const float* W2g  = (const float*)d_in[8];
  const float* W2   = (const float*)d_in[9];
  const float* p1   = (const float*)d_in[10];
  const float* p2   = (const float*)d_in[11];
  const float* psiW = (const float*)d_in[12];
  const float* lr1  = (const float*)d_in[13];
  const float* lr2  = (const float*)d_in[14];
  const int* esrc   = (const int*)d_in[15];
  const int* etgt   = (const int*)d_in[16];
  const int* gidx   = (const int*)d_in[17];

  float* h_a    = (float*)d_ws;                 // 1,280,000 f
  float* h_b    = h_a + (size_t)N_NODES*H;      // 1,280,000 f
  float* pooled = h_b + (size_t)N_NODES*H;      // 12,800 f
  unsigned short* spackb = (unsigned short*)(pooled + 100*H); // N_NODES*512 us
  unsigned short* tpackb = spackb + (size_t)N_NODES*512;      // N_NODES*512 us
  unsigned short* azb    = tpackb + (size_t)N_NODES*512;      // N_EDGES*128 us
  int* counts  = (int*)(azb + (size_t)N_EDGES*H);
  int* offsets = counts + N_NODES;              // N_NODES+1
  int* cursor  = offsets + N_NODES + 1;
  int* perm    = cursor + N_NODES;              // N_EDGES
  int* tgtp    = perm + N_EDGES;                // N_EDGES
  float* edp   = (float*)(tgtp + N_EDGES);      // N_EDGES
  unsigned short* w1t  = (unsigned short*)(edp + N_EDGES); // 3*8192
  unsigned short* w2t  = w1t + 3*8192;
  unsigned short* w2gt = w2t + 3*8192;          // 3*4096
  unsigned short* wnt  = w2gt + 3*4096;         // 3*98304
  unsigned short* wpt  = wnt + 3*98304;         // 3*49152

  // one-time: edge sort by src + de-indirect + weight transposes
  hipMemsetAsync(counts, 0, N_NODES*sizeof(int), stream);
  hipMemsetAsync(pooled, 0, 100*H*sizeof(float), stream);
  hist_kernel<<<(N_EDGES+255)/256, 256, 0, stream>>>(esrc, counts);
  scan_kernel<<<1, 256, 0, stream>>>(counts, offsets);
  hipMemcpyAsync(cursor, offsets, N_NODES*sizeof(int), hipMemcpyDeviceToDevice, stream);
  scatter_kernel<<<(N_EDGES+255)/256, 256, 0, stream>>>(esrc, etgt, ed, cursor, perm, tgtp, edp);
  prep_weights<<<144, 256, 0, stream>>>(W1, W2, W2g, w1t, w2t, w2gt);
  prep_nodew<<<(3*98304 + 3*49152 + 255)/256, 256, 0, stream>>>(Wg, Wm, p1, p2, psiW, wnt, wpt);

  embed_kernel<<<625, 256, 0, stream>>>(x, embW, h_a);

  for (int i = 0; i < 3; i++) {
    nodeA_mfma<<<(N_NODES+63)/64, 256, 0, stream>>>(h_a, wnt + i*98304, spackb, tpackb);
    zgemm_mfma<<<N_EDGES/64, 256, 0, stream>>>(cs, pw,
        w1t + i*8192, w2t + i*8192, w2gt + i*4096, perm, azb);
    combine_kernel<<<(N_NODES+3)/4, 256, 0, stream>>>(h_a, h_b, edp, tgtp,
        offsets, azb, spackb, tpackb);
    node_mfma<<<(N_NODES+63)/64, 256, 0, stream>>>(h_b, wpt + i*49152, gidx, pooled, h_a);
  }
  final_kernel<<<100, 64, 0, stream>>>(pooled, lr1, lr2, (float*)d_out);
}

// Round 7
// 576.801 us; speedup vs baseline: 11.6028x; 1.0471x over previous
//
#include <hip/hip_runtime.h>
#include <math.h>

#define H 128
#define N_NODES 10000
#define N_EDGES 160000

typedef float f32x4 __attribute__((ext_vector_type(4)));
typedef short s16x8 __attribute__((ext_vector_type(8)));

__device__ __forceinline__ float sigf(float x){ return 1.0f/(1.0f + __expf(-x)); }
__device__ __forceinline__ float eluf(float x){ return x > 0.0f ? x : (__expf(x) - 1.0f); }

__device__ __forceinline__ unsigned short f2bf(float f){
  unsigned int u = __float_as_uint(f);
  unsigned int r = (u + 0x7fffu + ((u >> 16) & 1u)) >> 16;
  return (unsigned short)r;
}
__device__ __forceinline__ float bf2f(unsigned short s){
  return __uint_as_float(((unsigned int)s) << 16);
}

__device__ __forceinline__ f32x4 MFMA16(s16x8 a, s16x8 b, f32x4 c){
  return __builtin_amdgcn_mfma_f32_16x16x32_bf16(a, b, c, 0, 0, 0);
}

__device__ __forceinline__ s16x8 loadA_f32(const float* p){
  float4 a = *(const float4*)p;
  float4 b = *(const float4*)(p+4);
  s16x8 r;
  r[0]=(short)f2bf(a.x); r[1]=(short)f2bf(a.y); r[2]=(short)f2bf(a.z); r[3]=(short)f2bf(a.w);
  r[4]=(short)f2bf(b.x); r[5]=(short)f2bf(b.y); r[6]=(short)f2bf(b.z); r[7]=(short)f2bf(b.w);
  return r;
}

// ---------------- edge sort by src: hist -> scan -> scatter ----------------
__global__ __launch_bounds__(256) void hist_kernel(
    const int* __restrict__ src, int* __restrict__ count)
{
  int e = blockIdx.x*256 + threadIdx.x;
  if (e < N_EDGES) atomicAdd(&count[src[e]], 1);
}

__global__ __launch_bounds__(256) void scan_kernel(
    const int* __restrict__ count, int* __restrict__ offsets)
{
  __shared__ int tmp[256];
  __shared__ int sbase;
  if (threadIdx.x == 0) sbase = 0;
  __syncthreads();
  for (int c0 = 0; c0 < N_NODES; c0 += 256) {
    int i = c0 + threadIdx.x;
    int v = (i < N_NODES) ? count[i] : 0;
    tmp[threadIdx.x] = v;
    __syncthreads();
    for (int off = 1; off < 256; off <<= 1) {
      int t = (threadIdx.x >= off) ? tmp[threadIdx.x - off] : 0;
      __syncthreads();
      tmp[threadIdx.x] += t;
      __syncthreads();
    }
    if (i < N_NODES) offsets[i] = sbase + tmp[threadIdx.x] - v;
    __syncthreads();
    if (threadIdx.x == 255) sbase += tmp[255];
    __syncthreads();
  }
  if (threadIdx.x == 0) offsets[N_NODES] = sbase;
}

__global__ __launch_bounds__(256) void scatter_kernel(
    const int* __restrict__ src, const int* __restrict__ tgt, const float* __restrict__ ed,
    int* __restrict__ cursor, int* __restrict__ perm,
    int* __restrict__ srcp, int* __restrict__ tgtp, float* __restrict__ edp)
{
  int e = blockIdx.x*256 + threadIdx.x;
  if (e < N_EDGES) {
    int s = src[e];
    int pos = atomicAdd(&cursor[s], 1);
    perm[pos] = e;
    srcp[pos] = s;
    tgtp[pos] = tgt[e];
    edp[pos]  = ed[e];
  }
}

// ---------------- prep_weights: W1,W2,W2g,embW -> bf16 [col][k] ----------------
__global__ __launch_bounds__(256) void prep_weights(
    const float* __restrict__ W1, const float* __restrict__ W2, const float* __restrict__ W2g,
    const float* __restrict__ embW,
    unsigned short* __restrict__ w1t, unsigned short* __restrict__ w2t,
    unsigned short* __restrict__ w2gt, unsigned short* __restrict__ embt)
{
  int idx = blockIdx.x*256 + threadIdx.x;
  if (idx < 3*8192) {
    int l = idx / 8192, r = idx % 8192;
    int c = r >> 6, k = r & 63;
    w1t[idx] = f2bf(W1[l*8192 + k*128 + c]);
    w2t[idx] = f2bf(W2[l*8192 + k*128 + c]);
  } else if (idx < 3*8192 + 3*4096) {
    int idx2 = idx - 3*8192;
    int l = idx2 / 4096, r = idx2 % 4096;
    int c = r >> 6, k = r & 63;
    w2gt[idx2] = f2bf(W2g[l*4096 + k*64 + c]);
  } else {
    int idx3 = idx - (3*8192 + 3*4096);
    if (idx3 < 16384) {
      int c = idx3 >> 7, k = idx3 & 127;
      embt[idx3] = f2bf(embW[k*128 + c]);
    }
  }
}

// ---------------- prep_nodew: bf16 [col][k] transposes for node GEMMs ----------------
__global__ __launch_bounds__(256) void prep_nodew(
    const float* __restrict__ Wg, const float* __restrict__ Wm,
    const float* __restrict__ p1, const float* __restrict__ p2, const float* __restrict__ psiW,
    unsigned short* __restrict__ wnt, unsigned short* __restrict__ wpt)
{
  int idx = blockIdx.x*256 + threadIdx.x;
  if (idx < 3*98304) {
    int l = idx / 98304, r = idx % 98304;
    int j = r >> 7, k = r & 127;
    float v;
    if (j < 384) v = Wg[l*49152 + (j>>7)*16384 + k*128 + (j&127)];
    else { int jj = j - 384; v = Wm[l*49152 + (jj>>7)*16384 + k*128 + (jj&127)]; }
    wnt[idx] = f2bf(v);
  } else {
    int idx2 = idx - 3*98304;
    if (idx2 < 3*49152) {
      int l = idx2 / 49152, r = idx2 % 49152;
      int j = r >> 7, k = r & 127;
      float v;
      if (j < 128)      v = p1 [l*16384 + k*128 + j];
      else if (j < 256) v = p2 [l*16384 + k*128 + (j-128)];
      else              v = psiW[l*16384 + k*128 + (j-256)];
      wpt[idx2] = f2bf(v);
    }
  }
}

// ---------------- embed (MFMA): h = sigmoid(x @ emb_W), 32 nodes/block ----------------
__global__ __launch_bounds__(256) void embed_mfma(
    const float* __restrict__ x, const unsigned short* __restrict__ embt,
    float* __restrict__ h_out)
{
  int tid = threadIdx.x, wave = tid >> 6, lane = tid & 63;
  int row = lane & 15, kg = lane >> 4;
  int nbase = blockIdx.x*32 + (wave & 1)*16;
  int hf = (wave >> 1) * 64;
  int nA = nbase + row;
  int nclamp = nA < N_NODES ? nA : N_NODES-1;
  const float* xr = &x[(size_t)nclamp*H];
  s16x8 a[4];
  #pragma unroll
  for (int ks = 0; ks < 4; ks++) a[ks] = loadA_f32(xr + ks*32 + kg*8);

  f32x4 acc[4];
  #pragma unroll
  for (int t = 0; t < 4; t++) { acc[t][0]=0.f; acc[t][1]=0.f; acc[t][2]=0.f; acc[t][3]=0.f; }
  #pragma unroll
  for (int t = 0; t < 4; t++) {
    int col = hf + t*16 + row;
    #pragma unroll
    for (int ks = 0; ks < 4; ks++) {
      s16x8 b = *(const s16x8*)&embt[(size_t)col*128 + ks*32 + kg*8];
      acc[t] = MFMA16(a[ks], b, acc[t]);
    }
  }
  #pragma unroll
  for (int r = 0; r < 4; r++) {
    int nc = nbase + kg*4 + r;
    if (nc >= N_NODES) continue;
    #pragma unroll
    for (int t = 0; t < 4; t++) {
      int col = hf + t*16 + row;
      h_out[(size_t)nc*H + col] = sigf(acc[t][r]);
    }
  }
}

// ---------------- nodeA (MFMA): bf16 interleaved pack tables, split grid ----------------
// spackb[n][c][4] = {Ag,Cg,Am,Cm}; tpackb[n][c][4] = {Bg,Cg,Bm,Cm}
__global__ __launch_bounds__(256) void nodeA_mfma(
    const float* __restrict__ h, const unsigned short* __restrict__ wnt,
    unsigned short* __restrict__ spackb, unsigned short* __restrict__ tpackb)
{
  int tid = threadIdx.x, wave = tid >> 6, lane = tid & 63;
  int row = lane & 15, kg = lane >> 4;
  int nbase = blockIdx.x*32 + (wave & 1)*16;
  int ch0 = (wave >> 1) * 3;
  int nA = nbase + row;
  int nclamp = nA < N_NODES ? nA : N_NODES-1;
  const float* hr = &h[(size_t)nclamp*H];
  s16x8 a[4];
  #pragma unroll
  for (int ks = 0; ks < 4; ks++) a[ks] = loadA_f32(hr + ks*32 + kg*8);

  #pragma unroll
  for (int ci = 0; ci < 3; ci++) {
    int ch = ch0 + ci;
    f32x4 acc[8];
    #pragma unroll
    for (int t = 0; t < 8; t++) { acc[t][0]=0.f; acc[t][1]=0.f; acc[t][2]=0.f; acc[t][3]=0.f; }
    #pragma unroll
    for (int t = 0; t < 8; t++) {
      int col = (ch*8 + t)*16 + row;
      #pragma unroll
      for (int ks = 0; ks < 4; ks++) {
        s16x8 b = *(const s16x8*)&wnt[(size_t)col*128 + ks*32 + kg*8];
        acc[t] = MFMA16(a[ks], b, acc[t]);
      }
    }
    #pragma unroll
    for (int t = 0; t < 8; t++) {
      int c = t*16 + row;   // 0..127 within slice
      #pragma unroll
      for (int r = 0; r < 4; r++) {
        int nc = nbase + kg*4 + r;
        if (nc >= N_NODES) continue;
        unsigned short bv = f2bf(acc[t][r]);
        size_t base = (size_t)nc*512 + c*4;
        if (ch == 0)      spackb[base + 0] = bv;
        else if (ch == 1) tpackb[base + 0] = bv;
        else if (ch == 2) { spackb[base + 1] = bv; tpackb[base + 1] = bv; }
        else if (ch == 3) spackb[base + 2] = bv;
        else if (ch == 4) tpackb[base + 2] = bv;
        else              { spackb[base + 3] = bv; tpackb[base + 3] = bv; }
      }
    }
  }
}

// ---------------- fused edge: z-GEMM (MFMA) + gate/mlp combine + per-node accumulate ----------------
// block = 64 consecutive pos (src-sorted). Phase A/B: MFMA az. Phase C: az->LDS.
// Phase D: wave q handles edges q*16..q*16+15; lane = 2 cols; segment-accumulate; atomicAdd h_acc.
__global__ __launch_bounds__(256) void fused_edge(
    float* __restrict__ h_acc,
    const float* __restrict__ cs, const float* __restrict__ pw,
    const unsigned short* __restrict__ w1t, const unsigned short* __restrict__ w2t,
    const unsigned short* __restrict__ w2gt,
    const int* __restrict__ perm, const int* __restrict__ srcp, const int* __restrict__ tgtp,
    const float* __restrict__ edp,
    const unsigned short* __restrict__ spackb, const unsigned short* __restrict__ tpackb)
{
  __shared__ unsigned short gate[64*64];   // 8 KB, XOR-swizzled
  __shared__ float zbuf[64][130];          // 33.3 KB
  __shared__ int   src_s[64];
  __shared__ int   tgt_s[64];
  __shared__ float rcp_s[64];
  __shared__ float msk_s[64];

  int tid  = threadIdx.x;
  int wave = tid >> 6, lane = tid & 63;
  int row  = lane & 15, kg = lane >> 4;
  int p0   = blockIdx.x * 64;

  if (tid < 64) {
    float r = edp[p0 + tid];
    rcp_s[tid] = 1.0f / r;
    msk_s[tid] = (r < 8.0f) ? 1.0f : 0.0f;
    src_s[tid] = srcp[p0 + tid];
    tgt_s[tid] = tgtp[p0 + tid];
  }

  int pe  = perm[p0 + wave*16 + row];
  const float* csr = &cs[(size_t)pe*64];
  const float* pwr = &pw[(size_t)pe*64];

  s16x8 acs[2], apw[2];
  acs[0] = loadA_f32(csr + kg*8);
  acs[1] = loadA_f32(csr + 32 + kg*8);
  apw[0] = loadA_f32(pwr + kg*8);
  apw[1] = loadA_f32(pwr + 32 + kg*8);

  // phase A: S1 = pw @ W2g
  f32x4 acc1[4];
  #pragma unroll
  for (int nt = 0; nt < 4; nt++) { acc1[nt][0]=0.f; acc1[nt][1]=0.f; acc1[nt][2]=0.f; acc1[nt][3]=0.f; }
  #pragma unroll
  for (int nt = 0; nt < 4; nt++) {
    s16x8 b0 = *(const s16x8*)&w2gt[(size_t)(nt*16+row)*64 + kg*8];
    s16x8 b1 = *(const s16x8*)&w2gt[(size_t)(nt*16+row)*64 + 32 + kg*8];
    acc1[nt] = MFMA16(apw[0], b0, acc1[nt]);
    acc1[nt] = MFMA16(apw[1], b1, acc1[nt]);
  }

  // sigmoid -> gate LDS (C-layout scatter write, swizzled)
  #pragma unroll
  for (int nt = 0; nt < 4; nt++) {
    #pragma unroll
    for (int r = 0; r < 4; r++) {
      int grow = wave*16 + kg*4 + r;
      int gcol = nt*16 + row;
      int byt = (grow << 7) + (gcol << 1);
      byt ^= (grow & 7) << 4;
      *(unsigned short*)((char*)gate + byt) = f2bf(sigf(acc1[nt][r]));
    }
  }
  __syncthreads();

  // read gate in A-layout, pwg frags = pw * gate
  s16x8 apg[2];
  #pragma unroll
  for (int ks = 0; ks < 2; ks++) {
    int arow = wave*16 + row;
    int byt = (arow << 7) + ks*64 + kg*16;
    byt ^= (arow & 7) << 4;
    s16x8 g = *(s16x8*)((char*)gate + byt);
    s16x8 o;
    #pragma unroll
    for (int j = 0; j < 8; j++) {
      float v = bf2f((unsigned short)apw[ks][j]) * bf2f((unsigned short)g[j]);
      o[j] = (short)f2bf(v);
    }
    apg[ks] = o;
  }

  // phase B: az = cs@W1t + pwg@W2t
  f32x4 acc2[8];
  #pragma unroll
  for (int nt = 0; nt < 8; nt++) { acc2[nt][0]=0.f; acc2[nt][1]=0.f; acc2[nt][2]=0.f; acc2[nt][3]=0.f; }
  #pragma unroll
  for (int nt = 0; nt < 8; nt++) {
    #pragma unroll
    for (int ks = 0; ks < 2; ks++) {
      s16x8 b1 = *(const s16x8*)&w1t[(size_t)(nt*16+row)*64 + ks*32 + kg*8];
      acc2[nt] = MFMA16(acs[ks], b1, acc2[nt]);
      s16x8 b2 = *(const s16x8*)&w2t[(size_t)(nt*16+row)*64 + ks*32 + kg*8];
      acc2[nt] = MFMA16(apg[ks], b2, acc2[nt]);
    }
  }

  // phase C: az -> LDS zbuf (C layout: edge = wave*16 + kg*4 + r, col = nt*16 + row)
  #pragma unroll
  for (int nt = 0; nt < 8; nt++) {
    #pragma unroll
    for (int r = 0; r < 4; r++) {
      zbuf[wave*16 + kg*4 + r][nt*16 + row] = acc2[nt][r];
    }
  }
  __syncthreads();

  // phase D: wave handles its 16 edges; lane = cols {2l, 2l+1}; src-segmented accumulate
  {
    int q = wave;          // wave == quarter
    int l = lane;
    int e0 = q*16;
    int cur = src_s[e0];
    s16x8 sp = *(const s16x8*)&spackb[(size_t)cur*512 + l*8];
    float Ags0 = bf2f((unsigned short)sp[0]), Cgs0 = bf2f((unsigned short)sp[1]);
    float Ams0 = bf2f((unsigned short)sp[2]), Cms0 = bf2f((unsigned short)sp[3]);
    float Ags1 = bf2f((unsigned short)sp[4]), Cgs1 = bf2f((unsigned short)sp[5]);
    float Ams1 = bf2f((unsigned short)sp[6]), Cms1 = bf2f((unsigned short)sp[7]);
    float acc0 = 0.f, accB = 0.f;
    #pragma unroll 4
    for (int e = e0; e < e0 + 16; e++) {
      int sn = src_s[e];
      if (sn != cur) {   // wave-uniform branch (src-sorted)
        atomicAdd(&h_acc[(size_t)cur*H + 2*l],     acc0);
        atomicAdd(&h_acc[(size_t)cur*H + 2*l + 1], accB);
        acc0 = 0.f; accB = 0.f; cur = sn;
        sp = *(const s16x8*)&spackb[(size_t)cur*512 + l*8];
        Ags0 = bf2f((unsigned short)sp[0]); Cgs0 = bf2f((unsigned short)sp[1]);
        Ams0 = bf2f((unsigned short)sp[2]); Cms0 = bf2f((unsigned short)sp[3]);
        Ags1 = bf2f((unsigned short)sp[4]); Cgs1 = bf2f((unsigned short)sp[5]);
        Ams1 = bf2f((unsigned short)sp[6]); Cms1 = bf2f((unsigned short)sp[7]);
      }
      int tn = tgt_s[e];
      float rc = rcp_s[e], mk = msk_s[e];
      s16x8 tp = *(const s16x8*)&tpackb[(size_t)tn*512 + l*8];
      float z0 = zbuf[e][2*l], z1 = zbuf[e][2*l + 1];
      float Bg0 = bf2f((unsigned short)tp[0]), Cg0 = bf2f((unsigned short)tp[1]);
      float Bm0 = bf2f((unsigned short)tp[2]), Cm0 = bf2f((unsigned short)tp[3]);
      float Bg1 = bf2f((unsigned short)tp[4]), Cg1 = bf2f((unsigned short)tp[5]);
      float Bm1 = bf2f((unsigned short)tp[6]), Cm1 = bf2f((unsigned short)tp[7]);
      float g0 = sigf(Ags0 + Bg0 + rc*(Cgs0 - Cg0));
      float m0 = eluf(Ams0 + Bm0 + rc*(Cms0 - Cm0));
      acc0 += g0 * m0 * z0 * mk;
      float g1 = sigf(Ags1 + Bg1 + rc*(Cgs1 - Cg1));
      float m1 = eluf(Ams1 + Bm1 + rc*(Cms1 - Cm1));
      accB += g1 * m1 * z1 * mk;
    }
    atomicAdd(&h_acc[(size_t)cur*H + 2*l],     acc0);
    atomicAdd(&h_acc[(size_t)cur*H + 2*l + 1], accB);
  }
}

// ---------------- node (MFMA): zp=elu((h@p1)*(h@p2)) -> pooled; h_out=elu(h@psi), split grid ----------------
__global__ __launch_bounds__(256) void node_mfma(
    const float* __restrict__ h_in, const unsigned short* __restrict__ wpt,
    const int* __restrict__ gidx, float* __restrict__ pooled, float* __restrict__ h_out)
{
  int tid = threadIdx.x, wave = tid >> 6, lane = tid & 63;
  int row = lane & 15, kg = lane >> 4;
  int nbase = blockIdx.x*32 + (wave & 1)*16;
  int hf = (wave >> 1) * 64;
  int nA = nbase + row;
  int nclamp = nA < N_NODES ? nA : N_NODES-1;
  const float* hr = &h_in[(size_t)nclamp*H];
  s16x8 a[4];
  #pragma unroll
  for (int ks = 0; ks < 4; ks++) a[ks] = loadA_f32(hr + ks*32 + kg*8);

  f32x4 acc1[4], acc2[4], acc3[4];
  #pragma unroll
  for (int t = 0; t < 4; t++) {
    #pragma unroll
    for (int r = 0; r < 4; r++) { acc1[t][r]=0.f; acc2[t][r]=0.f; acc3[t][r]=0.f; }
  }
  #pragma unroll
  for (int t = 0; t < 4; t++) {
    int col = hf + t*16 + row;
    #pragma unroll
    for (int ks = 0; ks < 4; ks++) {
      s16x8 b1 = *(const s16x8*)&wpt[(size_t)(col      )*128 + ks*32 + kg*8];
      s16x8 b2 = *(const s16x8*)&wpt[(size_t)(col + 128)*128 + ks*32 + kg*8];
      s16x8 b3 = *(const s16x8*)&wpt[(size_t)(col + 256)*128 + ks*32 + kg*8];
      acc1[t] = MFMA16(a[ks], b1, acc1[t]);
      acc2[t] = MFMA16(a[ks], b2, acc2[t]);
      acc3[t] = MFMA16(a[ks], b3, acc3[t]);
    }
  }

  int nc0 = nbase + kg*4;
  int g0 = (nc0     < N_NODES) ? gidx[nc0]     : -1;
  int g3 = (nc0 + 3 < N_NODES) ? gidx[nc0 + 3] : -2;
  if (g0 == g3) {
    #pragma unroll
    for (int t = 0; t < 4; t++) {
      int col = hf + t*16 + row;
      float s = 0.f;
      #pragma unroll
      for (int r = 0; r < 4; r++) s += eluf(acc1[t][r] * acc2[t][r]);
      atomicAdd(&pooled[g0*H + col], s);
      #pragma unroll
      for (int r = 0; r < 4; r++)
        h_out[(size_t)(nc0 + r)*H + col] = eluf(acc3[t][r]);
    }
  } else {
    #pragma unroll
    for (int r = 0; r < 4; r++) {
      int nc = nc0 + r;
      if (nc >= N_NODES) continue;
      int g = gidx[nc];
      #pragma unroll
      for (int t = 0; t < 4; t++) {
        int col = hf + t*16 + row;
        float zp = eluf(acc1[t][r] * acc2[t][r]);
        atomicAdd(&pooled[g*H + col], zp);
        h_out[(size_t)nc*H + col] = eluf(acc3[t][r]);
      }
    }
  }
}

// ---------------- final: y = elu(elu(pooled @ lr1) @ lr2) ----------------
__global__ __launch_bounds__(64) void final_kernel(
    const float* __restrict__ pooled, const float* __restrict__ lr1, const float* __restrict__ lr2,
    float* __restrict__ out)
{
  __shared__ float sp[128];
  __shared__ float y1[64];
  int g = blockIdx.x, tid = threadIdx.x;
  sp[tid]      = pooled[g*128 + tid];
  sp[tid + 64] = pooled[g*128 + 64 + tid];
  __syncthreads();
  float acc = 0.f;
  for (int k = 0; k < 128; k++) acc += sp[k] * lr1[k*64 + tid];
  y1[tid] = eluf(acc);
  __syncthreads();
  if (tid < 32) {
    float a2 = 0.f;
    for (int k = 0; k < 64; k++) a2 += y1[k] * lr2[k*32 + tid];
    out[g*32 + tid] = eluf(a2);
  }
}

extern "C" void kernel_launch(void* const* d_in, const int* in_sizes, int n_in,
                              void* d_out, int out_size, void* d_ws, size_t ws_size,
                              hipStream_t stream)
{
  const float* x    = (const float*)d_in[0];
  const float* ed   = (const float*)d_in[1];
  const float* cs   = (const float*)d_in[2];
  const float* pw   = (const float*)d_in[3];
  const float* embW = (const float*)d_in[4];
  const float* Wg   = (const float*)d_in[5];
  const float* Wm   = (const float*)d_in[6];
  const float* W1   = (const float*)d_in[7];
  const float* W2g  = (const float*)d_in[8];
  const float* W2   = (const float*)d_in[9];
  const float* p1   = (const float*)d_in[10];
  const float* p2   = (const float*)d_in[11];
  const float* psiW = (const float*)d_in[12];
  const float* lr1  = (const float*)d_in[13];
  const float* lr2  = (const float*)d_in[14];
  const int* esrc   = (const int*)d_in[15];
  const int* etgt   = (const int*)d_in[16];
  const int* gidx   = (const int*)d_in[17];

  float* h_a    = (float*)d_ws;                 // 1,280,000 f
  float* h_b    = h_a + (size_t)N_NODES*H;      // 1,280,000 f
  float* pooled = h_b + (size_t)N_NODES*H;      // 12,800 f
  unsigned short* spackb = (unsigned short*)(pooled + 100*H); // N_NODES*512 us
  unsigned short* tpackb = spackb + (size_t)N_NODES*512;      // N_NODES*512 us
  int* counts  = (int*)(tpackb + (size_t)N_NODES*512);
  int* offsets = counts + N_NODES;              // N_NODES+1
  int* cursor  = offsets + N_NODES + 1;
  int* perm    = cursor + N_NODES;              // N_EDGES
  int* srcp    = perm + N_EDGES;                // N_EDGES
  int* tgtp    = srcp + N_EDGES;                // N_EDGES
  float* edp   = (float*)(tgtp + N_EDGES);      // N_EDGES
  unsigned short* w1t  = (unsigned short*)(edp + N_EDGES); // 3*8192
  unsigned short* w2t  = w1t + 3*8192;
  unsigned short* w2gt = w2t + 3*8192;          // 3*4096
  unsigned short* embt = w2gt + 3*4096;         // 16384
  unsigned short* wnt  = embt + 16384;          // 3*98304
  unsigned short* wpt  = wnt + 3*98304;         // 3*49152

  // one-time: edge sort by src + de-indirect + weight transposes
  hipMemsetAsync(counts, 0, N_NODES*sizeof(int), stream);
  hipMemsetAsync(pooled, 0, 100*H*sizeof(float), stream);
  hist_kernel<<<(N_EDGES+255)/256, 256, 0, stream>>>(esrc, counts);
  scan_kernel<<<1, 256, 0, stream>>>(counts, offsets);
  hipMemcpyAsync(cursor, offsets, N_NODES*sizeof(int), hipMemcpyDeviceToDevice, stream);
  scatter_kernel<<<(N_EDGES+255)/256, 256, 0, stream>>>(esrc, etgt, ed, cursor, perm, srcp, tgtp, edp);
  prep_weights<<<208, 256, 0, stream>>>(W1, W2, W2g, embW, w1t, w2t, w2gt, embt);
  prep_nodew<<<(3*98304 + 3*49152 + 255)/256, 256, 0, stream>>>(Wg, Wm, p1, p2, psiW, wnt, wpt);

  embed_mfma<<<(N_NODES+31)/32, 256, 0, stream>>>(x, embt, h_a);

  for (int i = 0; i < 3; i++) {
    hipMemcpyAsync(h_b, h_a, (size_t)N_NODES*H*sizeof(float),
                   hipMemcpyDeviceToDevice, stream);
    nodeA_mfma<<<(N_NODES+31)/32, 256, 0, stream>>>(h_a, wnt + i*98304, spackb, tpackb);
    fused_edge<<<N_EDGES/64, 256, 0, stream>>>(h_b, cs, pw,
        w1t + i*8192, w2t + i*8192, w2gt + i*4096,
        perm, srcp, tgtp, edp, spackb, tpackb);
    node_mfma<<<(N_NODES+31)/32, 256, 0, stream>>>(h_b, wpt + i*49152, gidx, pooled, h_a);
  }
  final_kernel<<<100, 64, 0, stream>>>(pooled, lr1, lr2, (float*)d_out);
}

// Round 8
// 519.831 us; speedup vs baseline: 12.8745x; 1.1096x over previous
//
#include <hip/hip_runtime.h>
#include <math.h>

#define H 128
#define N_NODES 10000
#define N_EDGES 160000

typedef float f32x4 __attribute__((ext_vector_type(4)));
typedef short s16x8 __attribute__((ext_vector_type(8)));

__device__ __forceinline__ float sigf(float x){ return 1.0f/(1.0f + __expf(-x)); }
__device__ __forceinline__ float eluf(float x){ return x > 0.0f ? x : (__expf(x) - 1.0f); }

__device__ __forceinline__ unsigned short f2bf(float f){
  unsigned int u = __float_as_uint(f);
  unsigned int r = (u + 0x7fffu + ((u >> 16) & 1u)) >> 16;
  return (unsigned short)r;
}
__device__ __forceinline__ float bf2f(unsigned short s){
  return __uint_as_float(((unsigned int)s) << 16);
}

__device__ __forceinline__ f32x4 MFMA16(s16x8 a, s16x8 b, f32x4 c){
  return __builtin_amdgcn_mfma_f32_16x16x32_bf16(a, b, c, 0, 0, 0);
}

__device__ __forceinline__ s16x8 loadA_f32(const float* p){
  float4 a = *(const float4*)p;
  float4 b = *(const float4*)(p+4);
  s16x8 r;
  r[0]=(short)f2bf(a.x); r[1]=(short)f2bf(a.y); r[2]=(short)f2bf(a.z); r[3]=(short)f2bf(a.w);
  r[4]=(short)f2bf(b.x); r[5]=(short)f2bf(b.y); r[6]=(short)f2bf(b.z); r[7]=(short)f2bf(b.w);
  return r;
}

// ---------------- edge sort by src: hist -> scan -> scatter ----------------
__global__ __launch_bounds__(256) void hist_kernel(
    const int* __restrict__ src, int* __restrict__ count)
{
  int e = blockIdx.x*256 + threadIdx.x;
  if (e < N_EDGES) atomicAdd(&count[src[e]], 1);
}

__global__ __launch_bounds__(256) void scan_kernel(
    const int* __restrict__ count, int* __restrict__ offsets)
{
  __shared__ int tmp[256];
  __shared__ int sbase;
  if (threadIdx.x == 0) sbase = 0;
  __syncthreads();
  for (int c0 = 0; c0 < N_NODES; c0 += 256) {
    int i = c0 + threadIdx.x;
    int v = (i < N_NODES) ? count[i] : 0;
    tmp[threadIdx.x] = v;
    __syncthreads();
    for (int off = 1; off < 256; off <<= 1) {
      int t = (threadIdx.x >= off) ? tmp[threadIdx.x - off] : 0;
      __syncthreads();
      tmp[threadIdx.x] += t;
      __syncthreads();
    }
    if (i < N_NODES) offsets[i] = sbase + tmp[threadIdx.x] - v;
    __syncthreads();
    if (threadIdx.x == 255) sbase += tmp[255];
    __syncthreads();
  }
  if (threadIdx.x == 0) offsets[N_NODES] = sbase;
}

__global__ __launch_bounds__(256) void scatter_kernel(
    const int* __restrict__ src, const int* __restrict__ tgt, const float* __restrict__ ed,
    int* __restrict__ cursor, int* __restrict__ perm,
    int* __restrict__ srcp, int* __restrict__ tgtp, float* __restrict__ edp)
{
  int e = blockIdx.x*256 + threadIdx.x;
  if (e < N_EDGES) {
    int s = src[e];
    int pos = atomicAdd(&cursor[s], 1);
    perm[pos] = e;
    srcp[pos] = s;
    tgtp[pos] = tgt[e];
    edp[pos]  = ed[e];
  }
}

// ---------------- prep_edges: permuted bf16 copies of cs, pw ----------------
__global__ __launch_bounds__(256) void prep_edges(
    const float* __restrict__ cs, const float* __restrict__ pw, const int* __restrict__ perm,
    unsigned short* __restrict__ csb, unsigned short* __restrict__ pwb)
{
  int idx = blockIdx.x*256 + threadIdx.x;   // over N_EDGES*8
  if (idx >= N_EDGES*8) return;
  int pos = idx >> 3, kc = idx & 7;
  int e = perm[pos];
  s16x8 c = loadA_f32(&cs[(size_t)e*64 + kc*8]);
  s16x8 p = loadA_f32(&pw[(size_t)e*64 + kc*8]);
  *(s16x8*)&csb[(size_t)pos*64 + kc*8] = c;
  *(s16x8*)&pwb[(size_t)pos*64 + kc*8] = p;
}

// ---------------- prep_weights: W1,W2,W2g,embW -> bf16 [col][k] ----------------
__global__ __launch_bounds__(256) void prep_weights(
    const float* __restrict__ W1, const float* __restrict__ W2, const float* __restrict__ W2g,
    const float* __restrict__ embW,
    unsigned short* __restrict__ w1t, unsigned short* __restrict__ w2t,
    unsigned short* __restrict__ w2gt, unsigned short* __restrict__ embt)
{
  int idx = blockIdx.x*256 + threadIdx.x;
  if (idx < 3*8192) {
    int l = idx / 8192, r = idx % 8192;
    int c = r >> 6, k = r & 63;
    w1t[idx] = f2bf(W1[l*8192 + k*128 + c]);
    w2t[idx] = f2bf(W2[l*8192 + k*128 + c]);
  } else if (idx < 3*8192 + 3*4096) {
    int idx2 = idx - 3*8192;
    int l = idx2 / 4096, r = idx2 % 4096;
    int c = r >> 6, k = r & 63;
    w2gt[idx2] = f2bf(W2g[l*4096 + k*64 + c]);
  } else {
    int idx3 = idx - (3*8192 + 3*4096);
    if (idx3 < 16384) {
      int c = idx3 >> 7, k = idx3 & 127;
      embt[idx3] = f2bf(embW[k*128 + c]);
    }
  }
}

// ---------------- prep_nodew: bf16 [col][k] transposes for node GEMMs ----------------
__global__ __launch_bounds__(256) void prep_nodew(
    const float* __restrict__ Wg, const float* __restrict__ Wm,
    const float* __restrict__ p1, const float* __restrict__ p2, const float* __restrict__ psiW,
    unsigned short* __restrict__ wnt, unsigned short* __restrict__ wpt)
{
  int idx = blockIdx.x*256 + threadIdx.x;
  if (idx < 3*98304) {
    int l = idx / 98304, r = idx % 98304;
    int j = r >> 7, k = r & 127;
    float v;
    if (j < 384) v = Wg[l*49152 + (j>>7)*16384 + k*128 + (j&127)];
    else { int jj = j - 384; v = Wm[l*49152 + (jj>>7)*16384 + k*128 + (jj&127)]; }
    wnt[idx] = f2bf(v);
  } else {
    int idx2 = idx - 3*98304;
    if (idx2 < 3*49152) {
      int l = idx2 / 49152, r = idx2 % 49152;
      int j = r >> 7, k = r & 127;
      float v;
      if (j < 128)      v = p1 [l*16384 + k*128 + j];
      else if (j < 256) v = p2 [l*16384 + k*128 + (j-128)];
      else              v = psiW[l*16384 + k*128 + (j-256)];
      wpt[idx2] = f2bf(v);
    }
  }
}

// ---------------- embed (MFMA): h = sigmoid(x @ emb_W), writes both h buffers ----------------
__global__ __launch_bounds__(256) void embed_mfma(
    const float* __restrict__ x, const unsigned short* __restrict__ embt,
    float* __restrict__ h_out, float* __restrict__ h_out2)
{
  int tid = threadIdx.x, wave = tid >> 6, lane = tid & 63;
  int row = lane & 15, kg = lane >> 4;
  int nbase = blockIdx.x*32 + (wave & 1)*16;
  int hf = (wave >> 1) * 64;
  int nA = nbase + row;
  int nclamp = nA < N_NODES ? nA : N_NODES-1;
  const float* xr = &x[(size_t)nclamp*H];
  s16x8 a[4];
  #pragma unroll
  for (int ks = 0; ks < 4; ks++) a[ks] = loadA_f32(xr + ks*32 + kg*8);

  f32x4 acc[4];
  #pragma unroll
  for (int t = 0; t < 4; t++) { acc[t][0]=0.f; acc[t][1]=0.f; acc[t][2]=0.f; acc[t][3]=0.f; }
  #pragma unroll
  for (int t = 0; t < 4; t++) {
    int col = hf + t*16 + row;
    #pragma unroll
    for (int ks = 0; ks < 4; ks++) {
      s16x8 b = *(const s16x8*)&embt[(size_t)col*128 + ks*32 + kg*8];
      acc[t] = MFMA16(a[ks], b, acc[t]);
    }
  }
  #pragma unroll
  for (int r = 0; r < 4; r++) {
    int nc = nbase + kg*4 + r;
    if (nc >= N_NODES) continue;
    #pragma unroll
    for (int t = 0; t < 4; t++) {
      int col = hf + t*16 + row;
      float v = sigf(acc[t][r]);
      h_out [(size_t)nc*H + col] = v;
      h_out2[(size_t)nc*H + col] = v;
    }
  }
}

// ---------------- nodeA (MFMA): bf16 interleaved pack tables, split grid ----------------
// spackb[n][c][4] = {Ag,Cg,Am,Cm}; tpackb[n][c][4] = {Bg,Cg,Bm,Cm}
__global__ __launch_bounds__(256) void nodeA_mfma(
    const float* __restrict__ h, const unsigned short* __restrict__ wnt,
    unsigned short* __restrict__ spackb, unsigned short* __restrict__ tpackb)
{
  int tid = threadIdx.x, wave = tid >> 6, lane = tid & 63;
  int row = lane & 15, kg = lane >> 4;
  int nbase = blockIdx.x*32 + (wave & 1)*16;
  int ch0 = (wave >> 1) * 3;
  int nA = nbase + row;
  int nclamp = nA < N_NODES ? nA : N_NODES-1;
  const float* hr = &h[(size_t)nclamp*H];
  s16x8 a[4];
  #pragma unroll
  for (int ks = 0; ks < 4; ks++) a[ks] = loadA_f32(hr + ks*32 + kg*8);

  #pragma unroll
  for (int ci = 0; ci < 3; ci++) {
    int ch = ch0 + ci;
    f32x4 acc[8];
    #pragma unroll
    for (int t = 0; t < 8; t++) { acc[t][0]=0.f; acc[t][1]=0.f; acc[t][2]=0.f; acc[t][3]=0.f; }
    #pragma unroll
    for (int t = 0; t < 8; t++) {
      int col = (ch*8 + t)*16 + row;
      #pragma unroll
      for (int ks = 0; ks < 4; ks++) {
        s16x8 b = *(const s16x8*)&wnt[(size_t)col*128 + ks*32 + kg*8];
        acc[t] = MFMA16(a[ks], b, acc[t]);
      }
    }
    #pragma unroll
    for (int t = 0; t < 8; t++) {
      int c = t*16 + row;   // 0..127 within slice
      #pragma unroll
      for (int r = 0; r < 4; r++) {
        int nc = nbase + kg*4 + r;
        if (nc >= N_NODES) continue;
        unsigned short bv = f2bf(acc[t][r]);
        size_t base = (size_t)nc*512 + c*4;
        if (ch == 0)      spackb[base + 0] = bv;
        else if (ch == 1) tpackb[base + 0] = bv;
        else if (ch == 2) { spackb[base + 1] = bv; tpackb[base + 1] = bv; }
        else if (ch == 3) spackb[base + 2] = bv;
        else if (ch == 4) tpackb[base + 2] = bv;
        else              { spackb[base + 3] = bv; tpackb[base + 3] = bv; }
      }
    }
  }
}

// ---------------- fused edge v2: bf16 A-streams, bf16 zbuf, batched phase D ----------------
__global__ __launch_bounds__(256) void fused_edge(
    float* __restrict__ h_acc,
    const unsigned short* __restrict__ csb, const unsigned short* __restrict__ pwb,
    const unsigned short* __restrict__ w1t, const unsigned short* __restrict__ w2t,
    const unsigned short* __restrict__ w2gt,
    const int* __restrict__ srcp, const int* __restrict__ tgtp,
    const float* __restrict__ edp,
    const unsigned short* __restrict__ spackb, const unsigned short* __restrict__ tpackb)
{
  __shared__ unsigned short gate[64*64];     // 8 KB, XOR-swizzled
  __shared__ unsigned short zb[64][132];     // 16.5 KB bf16 z
  __shared__ int   src_s[64];
  __shared__ int   tgt_s[64];
  __shared__ float rcp_s[64];
  __shared__ float msk_s[64];

  int tid  = threadIdx.x;
  int wave = tid >> 6, lane = tid & 63;
  int row  = lane & 15, kg = lane >> 4;
  int p0   = blockIdx.x * 64;

  if (tid < 64) {
    float r = edp[p0 + tid];
    rcp_s[tid] = 1.0f / r;
    msk_s[tid] = (r < 8.0f) ? 1.0f : 0.0f;
    src_s[tid] = srcp[p0 + tid];
    tgt_s[tid] = tgtp[p0 + tid];
  }

  int pos = p0 + wave*16 + row;
  s16x8 acs[2], apw[2];
  acs[0] = *(const s16x8*)&csb[(size_t)pos*64 + kg*8];
  acs[1] = *(const s16x8*)&csb[(size_t)pos*64 + 32 + kg*8];
  apw[0] = *(const s16x8*)&pwb[(size_t)pos*64 + kg*8];
  apw[1] = *(const s16x8*)&pwb[(size_t)pos*64 + 32 + kg*8];

  // phase A: S1 = pw @ W2g
  f32x4 acc1[4];
  #pragma unroll
  for (int nt = 0; nt < 4; nt++) { acc1[nt][0]=0.f; acc1[nt][1]=0.f; acc1[nt][2]=0.f; acc1[nt][3]=0.f; }
  #pragma unroll
  for (int nt = 0; nt < 4; nt++) {
    s16x8 b0 = *(const s16x8*)&w2gt[(size_t)(nt*16+row)*64 + kg*8];
    s16x8 b1 = *(const s16x8*)&w2gt[(size_t)(nt*16+row)*64 + 32 + kg*8];
    acc1[nt] = MFMA16(apw[0], b0, acc1[nt]);
    acc1[nt] = MFMA16(apw[1], b1, acc1[nt]);
  }

  // sigmoid -> gate LDS (C-layout scatter write, swizzled)
  #pragma unroll
  for (int nt = 0; nt < 4; nt++) {
    #pragma unroll
    for (int r = 0; r < 4; r++) {
      int grow = wave*16 + kg*4 + r;
      int gcol = nt*16 + row;
      int byt = (grow << 7) + (gcol << 1);
      byt ^= (grow & 7) << 4;
      *(unsigned short*)((char*)gate + byt) = f2bf(sigf(acc1[nt][r]));
    }
  }
  __syncthreads();

  // read gate in A-layout, pwg frags = pw * gate
  s16x8 apg[2];
  #pragma unroll
  for (int ks = 0; ks < 2; ks++) {
    int arow = wave*16 + row;
    int byt = (arow << 7) + ks*64 + kg*16;
    byt ^= (arow & 7) << 4;
    s16x8 g = *(s16x8*)((char*)gate + byt);
    s16x8 o;
    #pragma unroll
    for (int j = 0; j < 8; j++) {
      float v = bf2f((unsigned short)apw[ks][j]) * bf2f((unsigned short)g[j]);
      o[j] = (short)f2bf(v);
    }
    apg[ks] = o;
  }

  // phase B: az = cs@W1t + pwg@W2t
  f32x4 acc2[8];
  #pragma unroll
  for (int nt = 0; nt < 8; nt++) { acc2[nt][0]=0.f; acc2[nt][1]=0.f; acc2[nt][2]=0.f; acc2[nt][3]=0.f; }
  #pragma unroll
  for (int nt = 0; nt < 8; nt++) {
    #pragma unroll
    for (int ks = 0; ks < 2; ks++) {
      s16x8 b1 = *(const s16x8*)&w1t[(size_t)(nt*16+row)*64 + ks*32 + kg*8];
      acc2[nt] = MFMA16(acs[ks], b1, acc2[nt]);
      s16x8 b2 = *(const s16x8*)&w2t[(size_t)(nt*16+row)*64 + ks*32 + kg*8];
      acc2[nt] = MFMA16(apg[ks], b2, acc2[nt]);
    }
  }

  // phase C: az -> LDS zb bf16 (C layout: edge = wave*16 + kg*4 + r, col = nt*16 + row)
  #pragma unroll
  for (int nt = 0; nt < 8; nt++) {
    #pragma unroll
    for (int r = 0; r < 4; r++) {
      zb[wave*16 + kg*4 + r][nt*16 + row] = f2bf(acc2[nt][r]);
    }
  }
  __syncthreads();

  // phase D: wave handles its 16 edges in batches of 4; lane = cols {2l, 2l+1}
  {
    int l = lane;
    int e0 = wave*16;
    int cur = src_s[e0];
    s16x8 sp = *(const s16x8*)&spackb[(size_t)cur*512 + l*8];
    float Ags0 = bf2f((unsigned short)sp[0]), Cgs0 = bf2f((unsigned short)sp[1]);
    float Ams0 = bf2f((unsigned short)sp[2]), Cms0 = bf2f((unsigned short)sp[3]);
    float Ags1 = bf2f((unsigned short)sp[4]), Cgs1 = bf2f((unsigned short)sp[5]);
    float Ams1 = bf2f((unsigned short)sp[6]), Cms1 = bf2f((unsigned short)sp[7]);
    float acc0 = 0.f, accB = 0.f;
    for (int eb = e0; eb < e0 + 16; eb += 4) {
      s16x8 tp[4]; unsigned int zz[4];
      #pragma unroll
      for (int b = 0; b < 4; b++) {
        int e = eb + b;
        tp[b] = *(const s16x8*)&tpackb[(size_t)tgt_s[e]*512 + l*8];
        zz[b] = *(const unsigned int*)&zb[e][2*l];
      }
      #pragma unroll
      for (int b = 0; b < 4; b++) {
        int e = eb + b;
        int sn = src_s[e];
        if (sn != cur) {   // wave-uniform (src-sorted)
          atomicAdd(&h_acc[(size_t)cur*H + 2*l],     acc0);
          atomicAdd(&h_acc[(size_t)cur*H + 2*l + 1], accB);
          acc0 = 0.f; accB = 0.f; cur = sn;
          sp = *(const s16x8*)&spackb[(size_t)cur*512 + l*8];
          Ags0 = bf2f((unsigned short)sp[0]); Cgs0 = bf2f((unsigned short)sp[1]);
          Ams0 = bf2f((unsigned short)sp[2]); Cms0 = bf2f((unsigned short)sp[3]);
          Ags1 = bf2f((unsigned short)sp[4]); Cgs1 = bf2f((unsigned short)sp[5]);
          Ams1 = bf2f((unsigned short)sp[6]); Cms1 = bf2f((unsigned short)sp[7]);
        }
        float rc = rcp_s[e], mk = msk_s[e];
        float z0 = bf2f((unsigned short)(zz[b] & 0xffffu));
        float z1 = bf2f((unsigned short)(zz[b] >> 16));
        float Bg0 = bf2f((unsigned short)tp[b][0]), Cg0 = bf2f((unsigned short)tp[b][1]);
        float Bm0 = bf2f((unsigned short)tp[b][2]), Cm0 = bf2f((unsigned short)tp[b][3]);
        float Bg1 = bf2f((unsigned short)tp[b][4]), Cg1 = bf2f((unsigned short)tp[b][5]);
        float Bm1 = bf2f((unsigned short)tp[b][6]), Cm1 = bf2f((unsigned short)tp[b][7]);
        float g0 = sigf(Ags0 + Bg0 + rc*(Cgs0 - Cg0));
        float m0 = eluf(Ams0 + Bm0 + rc*(Cms0 - Cm0));
        acc0 += g0 * m0 * z0 * mk;
        float g1 = sigf(Ags1 + Bg1 + rc*(Cgs1 - Cg1));
        float m1 = eluf(Ams1 + Bm1 + rc*(Cms1 - Cm1));
        accB += g1 * m1 * z1 * mk;
      }
    }
    atomicAdd(&h_acc[(size_t)cur*H + 2*l],     acc0);
    atomicAdd(&h_acc[(size_t)cur*H + 2*l + 1], accB);
  }
}

// ---------------- node (MFMA): zp -> pooled; h_out = elu(h@psi) to both buffers ----------------
__global__ __launch_bounds__(256) void node_mfma(
    const float* __restrict__ h_in, const unsigned short* __restrict__ wpt,
    const int* __restrict__ gidx, float* __restrict__ pooled,
    float* __restrict__ h_out, float* __restrict__ h_out2)
{
  int tid = threadIdx.x, wave = tid >> 6, lane = tid & 63;
  int row = lane & 15, kg = lane >> 4;
  int nbase = blockIdx.x*32 + (wave & 1)*16;
  int hf = (wave >> 1) * 64;
  int nA = nbase + row;
  int nclamp = nA < N_NODES ? nA : N_NODES-1;
  const float* hr = &h_in[(size_t)nclamp*H];
  s16x8 a[4];
  #pragma unroll
  for (int ks = 0; ks < 4; ks++) a[ks] = loadA_f32(hr + ks*32 + kg*8);

  f32x4 acc1[4], acc2[4], acc3[4];
  #pragma unroll
  for (int t = 0; t < 4; t++) {
    #pragma unroll
    for (int r = 0; r < 4; r++) { acc1[t][r]=0.f; acc2[t][r]=0.f; acc3[t][r]=0.f; }
  }
  #pragma unroll
  for (int t = 0; t < 4; t++) {
    int col = hf + t*16 + row;
    #pragma unroll
    for (int ks = 0; ks < 4; ks++) {
      s16x8 b1 = *(const s16x8*)&wpt[(size_t)(col      )*128 + ks*32 + kg*8];
      s16x8 b2 = *(const s16x8*)&wpt[(size_t)(col + 128)*128 + ks*32 + kg*8];
      s16x8 b3 = *(const s16x8*)&wpt[(size_t)(col + 256)*128 + ks*32 + kg*8];
      acc1[t] = MFMA16(a[ks], b1, acc1[t]);
      acc2[t] = MFMA16(a[ks], b2, acc2[t]);
      acc3[t] = MFMA16(a[ks], b3, acc3[t]);
    }
  }

  int nc0 = nbase + kg*4;
  int g0 = (nc0     < N_NODES) ? gidx[nc0]     : -1;
  int g3 = (nc0 + 3 < N_NODES) ? gidx[nc0 + 3] : -2;
  if (g0 == g3) {
    #pragma unroll
    for (int t = 0; t < 4; t++) {
      int col = hf + t*16 + row;
      float s = 0.f;
      #pragma unroll
      for (int r = 0; r < 4; r++) s += eluf(acc1[t][r] * acc2[t][r]);
      atomicAdd(&pooled[g0*H + col], s);
      #pragma unroll
      for (int r = 0; r < 4; r++) {
        float v = eluf(acc3[t][r]);
        h_out [(size_t)(nc0 + r)*H + col] = v;
        h_out2[(size_t)(nc0 + r)*H + col] = v;
      }
    }
  } else {
    #pragma unroll
    for (int r = 0; r < 4; r++) {
      int nc = nc0 + r;
      if (nc >= N_NODES) continue;
      int g = gidx[nc];
      #pragma unroll
      for (int t = 0; t < 4; t++) {
        int col = hf + t*16 + row;
        float zp = eluf(acc1[t][r] * acc2[t][r]);
        atomicAdd(&pooled[g*H + col], zp);
        float v = eluf(acc3[t][r]);
        h_out [(size_t)nc*H + col] = v;
        h_out2[(size_t)nc*H + col] = v;
      }
    }
  }
}

// ---------------- final: y = elu(elu(pooled @ lr1) @ lr2) ----------------
__global__ __launch_bounds__(64) void final_kernel(
    const float* __restrict__ pooled, const float* __restrict__ lr1, const float* __restrict__ lr2,
    float* __restrict__ out)
{
  __shared__ float sp[128];
  __shared__ float y1[64];
  int g = blockIdx.x, tid = threadIdx.x;
  sp[tid]      = pooled[g*128 + tid];
  sp[tid + 64] = pooled[g*128 + 64 + tid];
  __syncthreads();
  float acc = 0.f;
  for (int k = 0; k < 128; k++) acc += sp[k] * lr1[k*64 + tid];
  y1[tid] = eluf(acc);
  __syncthreads();
  if (tid < 32) {
    float a2 = 0.f;
    for (int k = 0; k < 64; k++) a2 += y1[k] * lr2[k*32 + tid];
    out[g*32 + tid] = eluf(a2);
  }
}

extern "C" void kernel_launch(void* const* d_in, const int* in_sizes, int n_in,
                              void* d_out, int out_size, void* d_ws, size_t ws_size,
                              hipStream_t stream)
{
  const float* x    = (const float*)d_in[0];
  const float* ed   = (const float*)d_in[1];
  const float* cs   = (const float*)d_in[2];
  const float* pw   = (const float*)d_in[3];
  const float* embW = (const float*)d_in[4];
  const float* Wg   = (const float*)d_in[5];
  const float* Wm   = (const float*)d_in[6];
  const float* W1   = (const float*)d_in[7];
  const float* W2g  = (const float*)d_in[8];
  const float* W2   = (const float*)d_in[9];
  const float* p1   = (const float*)d_in[10];
  const float* p2   = (const float*)d_in[11];
  const float* psiW = (const float*)d_in[12];
  const float* lr1  = (const float*)d_in[13];
  const float* lr2  = (const float*)d_in[14];
  const int* esrc   = (const int*)d_in[15];
  const int* etgt   = (const int*)d_in[16];
  const int* gidx   = (const int*)d_in[17];

  float* h_a    = (float*)d_ws;                 // 1,280,000 f
  float* h_b    = h_a + (size_t)N_NODES*H;      // 1,280,000 f
  float* pooled = h_b + (size_t)N_NODES*H;      // 12,800 f
  unsigned short* spackb = (unsigned short*)(pooled + 100*H); // N_NODES*512 us
  unsigned short* tpackb = spackb + (size_t)N_NODES*512;      // N_NODES*512 us
  int* counts  = (int*)(tpackb + (size_t)N_NODES*512);
  int* offsets = counts + N_NODES;              // N_NODES+1
  int* cursor  = offsets + N_NODES + 1;
  int* perm    = cursor + N_NODES;              // N_EDGES
  int* srcp    = perm + N_EDGES;                // N_EDGES
  int* tgtp    = srcp + N_EDGES;                // N_EDGES
  float* edp   = (float*)(tgtp + N_EDGES);      // N_EDGES
  unsigned short* w1t  = (unsigned short*)(edp + N_EDGES); // 3*8192
  unsigned short* w2t  = w1t + 3*8192;
  unsigned short* w2gt = w2t + 3*8192;          // 3*4096
  unsigned short* embt = w2gt + 3*4096;         // 16384
  unsigned short* wnt  = embt + 16384;          // 3*98304
  unsigned short* wpt  = wnt + 3*98304;         // 3*49152
  unsigned short* csb  = wpt + 3*49152;         // N_EDGES*64
  unsigned short* pwb  = csb + (size_t)N_EDGES*64; // N_EDGES*64

  // one-time: edge sort by src + de-indirect + bf16 conversions
  hipMemsetAsync(counts, 0, N_NODES*sizeof(int), stream);
  hipMemsetAsync(pooled, 0, 100*H*sizeof(float), stream);
  hist_kernel<<<(N_EDGES+255)/256, 256, 0, stream>>>(esrc, counts);
  scan_kernel<<<1, 256, 0, stream>>>(counts, offsets);
  hipMemcpyAsync(cursor, offsets, N_NODES*sizeof(int), hipMemcpyDeviceToDevice, stream);
  scatter_kernel<<<(N_EDGES+255)/256, 256, 0, stream>>>(esrc, etgt, ed, cursor, perm, srcp, tgtp, edp);
  prep_edges<<<N_EDGES*8/256, 256, 0, stream>>>(cs, pw, perm, csb, pwb);
  prep_weights<<<208, 256, 0, stream>>>(W1, W2, W2g, embW, w1t, w2t, w2gt, embt);
  prep_nodew<<<(3*98304 + 3*49152 + 255)/256, 256, 0, stream>>>(Wg, Wm, p1, p2, psiW, wnt, wpt);

  embed_mfma<<<(N_NODES+31)/32, 256, 0, stream>>>(x, embt, h_a, h_b);

  for (int i = 0; i < 3; i++) {
    nodeA_mfma<<<(N_NODES+31)/32, 256, 0, stream>>>(h_a, wnt + i*98304, spackb, tpackb);
    fused_edge<<<N_EDGES/64, 256, 0, stream>>>(h_b, csb, pwb,
        w1t + i*8192, w2t + i*8192, w2gt + i*4096,
        srcp, tgtp, edp, spackb, tpackb);
    node_mfma<<<(N_NODES+31)/32, 256, 0, stream>>>(h_b, wpt + i*49152, gidx, pooled, h_a, h_b);
  }
  final_kernel<<<100, 64, 0, stream>>>(pooled, lr1, lr2, (float*)d_out);
}

// Round 9
// 493.441 us; speedup vs baseline: 13.5630x; 1.0535x over previous
//
#include <hip/hip_runtime.h>
#include <math.h>

#define H 128
#define N_NODES 10000
#define N_EDGES 160000

typedef float f32x4 __attribute__((ext_vector_type(4)));
typedef short s16x8 __attribute__((ext_vector_type(8)));

__device__ __forceinline__ float sigf(float x){ return 1.0f/(1.0f + __expf(-x)); }
__device__ __forceinline__ float eluf(float x){ return x > 0.0f ? x : (__expf(x) - 1.0f); }

__device__ __forceinline__ unsigned short f2bf(float f){
  unsigned int u = __float_as_uint(f);
  unsigned int r = (u + 0x7fffu + ((u >> 16) & 1u)) >> 16;
  return (unsigned short)r;
}
__device__ __forceinline__ float bf2f(unsigned short s){
  return __uint_as_float(((unsigned int)s) << 16);
}

__device__ __forceinline__ f32x4 MFMA16(s16x8 a, s16x8 b, f32x4 c){
  return __builtin_amdgcn_mfma_f32_16x16x32_bf16(a, b, c, 0, 0, 0);
}

__device__ __forceinline__ s16x8 loadA_f32(const float* p){
  float4 a = *(const float4*)p;
  float4 b = *(const float4*)(p+4);
  s16x8 r;
  r[0]=(short)f2bf(a.x); r[1]=(short)f2bf(a.y); r[2]=(short)f2bf(a.z); r[3]=(short)f2bf(a.w);
  r[4]=(short)f2bf(b.x); r[5]=(short)f2bf(b.y); r[6]=(short)f2bf(b.z); r[7]=(short)f2bf(b.w);
  return r;
}

// ---------------- edge sort by src: hist -> scan -> scatter ----------------
__global__ __launch_bounds__(256) void hist_kernel(
    const int* __restrict__ src, int* __restrict__ count)
{
  int e = blockIdx.x*256 + threadIdx.x;
  if (e < N_EDGES) atomicAdd(&count[src[e]], 1);
}

__global__ __launch_bounds__(256) void scan_kernel(
    const int* __restrict__ count, int* __restrict__ offsets)
{
  __shared__ int tmp[256];
  __shared__ int sbase;
  if (threadIdx.x == 0) sbase = 0;
  __syncthreads();
  for (int c0 = 0; c0 < N_NODES; c0 += 256) {
    int i = c0 + threadIdx.x;
    int v = (i < N_NODES) ? count[i] : 0;
    tmp[threadIdx.x] = v;
    __syncthreads();
    for (int off = 1; off < 256; off <<= 1) {
      int t = (threadIdx.x >= off) ? tmp[threadIdx.x - off] : 0;
      __syncthreads();
      tmp[threadIdx.x] += t;
      __syncthreads();
    }
    if (i < N_NODES) offsets[i] = sbase + tmp[threadIdx.x] - v;
    __syncthreads();
    if (threadIdx.x == 255) sbase += tmp[255];
    __syncthreads();
  }
  if (threadIdx.x == 0) offsets[N_NODES] = sbase;
}

__global__ __launch_bounds__(256) void scatter_kernel(
    const int* __restrict__ src, const int* __restrict__ tgt, const float* __restrict__ ed,
    int* __restrict__ cursor, int* __restrict__ perm,
    int* __restrict__ srcp, int* __restrict__ tgtp, float* __restrict__ edp)
{
  int e = blockIdx.x*256 + threadIdx.x;
  if (e < N_EDGES) {
    int s = src[e];
    int pos = atomicAdd(&cursor[s], 1);
    perm[pos] = e;
    srcp[pos] = s;
    tgtp[pos] = tgt[e];
    edp[pos]  = ed[e];
  }
}

// ---------------- prep_edges: permuted bf16 copies of cs, pw ----------------
__global__ __launch_bounds__(256) void prep_edges(
    const float* __restrict__ cs, const float* __restrict__ pw, const int* __restrict__ perm,
    unsigned short* __restrict__ csb, unsigned short* __restrict__ pwb)
{
  int idx = blockIdx.x*256 + threadIdx.x;   // over N_EDGES*8
  if (idx >= N_EDGES*8) return;
  int pos = idx >> 3, kc = idx & 7;
  int e = perm[pos];
  s16x8 c = loadA_f32(&cs[(size_t)e*64 + kc*8]);
  s16x8 p = loadA_f32(&pw[(size_t)e*64 + kc*8]);
  *(s16x8*)&csb[(size_t)pos*64 + kc*8] = c;
  *(s16x8*)&pwb[(size_t)pos*64 + kc*8] = p;
}

// ---------------- prep_weights: W1,W2,W2g,embW -> bf16 [col][k] ----------------
__global__ __launch_bounds__(256) void prep_weights(
    const float* __restrict__ W1, const float* __restrict__ W2, const float* __restrict__ W2g,
    const float* __restrict__ embW,
    unsigned short* __restrict__ w1t, unsigned short* __restrict__ w2t,
    unsigned short* __restrict__ w2gt, unsigned short* __restrict__ embt)
{
  int idx = blockIdx.x*256 + threadIdx.x;
  if (idx < 3*8192) {
    int l = idx / 8192, r = idx % 8192;
    int c = r >> 6, k = r & 63;
    w1t[idx] = f2bf(W1[l*8192 + k*128 + c]);
    w2t[idx] = f2bf(W2[l*8192 + k*128 + c]);
  } else if (idx < 3*8192 + 3*4096) {
    int idx2 = idx - 3*8192;
    int l = idx2 / 4096, r = idx2 % 4096;
    int c = r >> 6, k = r & 63;
    w2gt[idx2] = f2bf(W2g[l*4096 + k*64 + c]);
  } else {
    int idx3 = idx - (3*8192 + 3*4096);
    if (idx3 < 16384) {
      int c = idx3 >> 7, k = idx3 & 127;
      embt[idx3] = f2bf(embW[k*128 + c]);
    }
  }
}

// ---------------- prep_nodew: bf16 [col][k] transposes for node GEMMs ----------------
__global__ __launch_bounds__(256) void prep_nodew(
    const float* __restrict__ Wg, const float* __restrict__ Wm,
    const float* __restrict__ p1, const float* __restrict__ p2, const float* __restrict__ psiW,
    unsigned short* __restrict__ wnt, unsigned short* __restrict__ wpt)
{
  int idx = blockIdx.x*256 + threadIdx.x;
  if (idx < 3*98304) {
    int l = idx / 98304, r = idx % 98304;
    int j = r >> 7, k = r & 127;
    float v;
    if (j < 384) v = Wg[l*49152 + (j>>7)*16384 + k*128 + (j&127)];
    else { int jj = j - 384; v = Wm[l*49152 + (jj>>7)*16384 + k*128 + (jj&127)]; }
    wnt[idx] = f2bf(v);
  } else {
    int idx2 = idx - 3*98304;
    if (idx2 < 3*49152) {
      int l = idx2 / 49152, r = idx2 % 49152;
      int j = r >> 7, k = r & 127;
      float v;
      if (j < 128)      v = p1 [l*16384 + k*128 + j];
      else if (j < 256) v = p2 [l*16384 + k*128 + (j-128)];
      else              v = psiW[l*16384 + k*128 + (j-256)];
      wpt[idx2] = f2bf(v);
    }
  }
}

// ---------------- embed (MFMA): h = sigmoid(x @ emb_W) ----------------
__global__ __launch_bounds__(256) void embed_mfma(
    const float* __restrict__ x, const unsigned short* __restrict__ embt,
    float* __restrict__ h_out)
{
  int tid = threadIdx.x, wave = tid >> 6, lane = tid & 63;
  int row = lane & 15, kg = lane >> 4;
  int nbase = blockIdx.x*32 + (wave & 1)*16;
  int hf = (wave >> 1) * 64;
  int nA = nbase + row;
  int nclamp = nA < N_NODES ? nA : N_NODES-1;
  const float* xr = &x[(size_t)nclamp*H];
  s16x8 a[4];
  #pragma unroll
  for (int ks = 0; ks < 4; ks++) a[ks] = loadA_f32(xr + ks*32 + kg*8);

  f32x4 acc[4];
  #pragma unroll
  for (int t = 0; t < 4; t++) { acc[t][0]=0.f; acc[t][1]=0.f; acc[t][2]=0.f; acc[t][3]=0.f; }
  #pragma unroll
  for (int t = 0; t < 4; t++) {
    int col = hf + t*16 + row;
    #pragma unroll
    for (int ks = 0; ks < 4; ks++) {
      s16x8 b = *(const s16x8*)&embt[(size_t)col*128 + ks*32 + kg*8];
      acc[t] = MFMA16(a[ks], b, acc[t]);
    }
  }
  #pragma unroll
  for (int r = 0; r < 4; r++) {
    int nc = nbase + kg*4 + r;
    if (nc >= N_NODES) continue;
    #pragma unroll
    for (int t = 0; t < 4; t++) {
      int col = hf + t*16 + row;
      h_out[(size_t)nc*H + col] = sigf(acc[t][r]);
    }
  }
}

// ---------------- nodeA (MFMA): layer-0 pack tables ----------------
__global__ __launch_bounds__(256) void nodeA_mfma(
    const float* __restrict__ h, const unsigned short* __restrict__ wnt,
    unsigned short* __restrict__ spackb, unsigned short* __restrict__ tpackb)
{
  int tid = threadIdx.x, wave = tid >> 6, lane = tid & 63;
  int row = lane & 15, kg = lane >> 4;
  int nbase = blockIdx.x*32 + (wave & 1)*16;
  int ch0 = (wave >> 1) * 3;
  int nA = nbase + row;
  int nclamp = nA < N_NODES ? nA : N_NODES-1;
  const float* hr = &h[(size_t)nclamp*H];
  s16x8 a[4];
  #pragma unroll
  for (int ks = 0; ks < 4; ks++) a[ks] = loadA_f32(hr + ks*32 + kg*8);

  #pragma unroll
  for (int ci = 0; ci < 3; ci++) {
    int ch = ch0 + ci;
    f32x4 acc[8];
    #pragma unroll
    for (int t = 0; t < 8; t++) { acc[t][0]=0.f; acc[t][1]=0.f; acc[t][2]=0.f; acc[t][3]=0.f; }
    #pragma unroll
    for (int t = 0; t < 8; t++) {
      int col = (ch*8 + t)*16 + row;
      #pragma unroll
      for (int ks = 0; ks < 4; ks++) {
        s16x8 b = *(const s16x8*)&wnt[(size_t)col*128 + ks*32 + kg*8];
        acc[t] = MFMA16(a[ks], b, acc[t]);
      }
    }
    #pragma unroll
    for (int t = 0; t < 8; t++) {
      int c = t*16 + row;
      #pragma unroll
      for (int r = 0; r < 4; r++) {
        int nc = nbase + kg*4 + r;
        if (nc >= N_NODES) continue;
        unsigned short bv = f2bf(acc[t][r]);
        size_t base = (size_t)nc*512 + c*4;
        if (ch == 0)      spackb[base + 0] = bv;
        else if (ch == 1) tpackb[base + 0] = bv;
        else if (ch == 2) { spackb[base + 1] = bv; tpackb[base + 1] = bv; }
        else if (ch == 3) spackb[base + 2] = bv;
        else if (ch == 4) tpackb[base + 2] = bv;
        else              { spackb[base + 3] = bv; tpackb[base + 3] = bv; }
      }
    }
  }
}

// ---------------- fused edge: MFMA z + combine, pipelined phase D ----------------
__global__ __launch_bounds__(256) void fused_edge(
    float* __restrict__ h_acc,
    const unsigned short* __restrict__ csb, const unsigned short* __restrict__ pwb,
    const unsigned short* __restrict__ w1t, const unsigned short* __restrict__ w2t,
    const unsigned short* __restrict__ w2gt,
    const int* __restrict__ srcp, const int* __restrict__ tgtp,
    const float* __restrict__ edp,
    const unsigned short* __restrict__ spackb, const unsigned short* __restrict__ tpackb)
{
  __shared__ unsigned short gate[64*64];     // 8 KB, XOR-swizzled
  __shared__ unsigned short zb[64][132];     // 16.5 KB bf16 z
  __shared__ int   src_s[64];
  __shared__ int   tgt_s[64];
  __shared__ float rcp_s[64];
  __shared__ float msk_s[64];

  int tid  = threadIdx.x;
  int wave = tid >> 6, lane = tid & 63;
  int row  = lane & 15, kg = lane >> 4;
  int p0   = blockIdx.x * 64;

  if (tid < 64) {
    float r = edp[p0 + tid];
    rcp_s[tid] = 1.0f / r;
    msk_s[tid] = (r < 8.0f) ? 1.0f : 0.0f;
    src_s[tid] = srcp[p0 + tid];
    tgt_s[tid] = tgtp[p0 + tid];
  }

  int pos = p0 + wave*16 + row;
  s16x8 acs[2], apw[2];
  acs[0] = *(const s16x8*)&csb[(size_t)pos*64 + kg*8];
  acs[1] = *(const s16x8*)&csb[(size_t)pos*64 + 32 + kg*8];
  apw[0] = *(const s16x8*)&pwb[(size_t)pos*64 + kg*8];
  apw[1] = *(const s16x8*)&pwb[(size_t)pos*64 + 32 + kg*8];

  // phase A: S1 = pw @ W2g
  f32x4 acc1[4];
  #pragma unroll
  for (int nt = 0; nt < 4; nt++) { acc1[nt][0]=0.f; acc1[nt][1]=0.f; acc1[nt][2]=0.f; acc1[nt][3]=0.f; }
  #pragma unroll
  for (int nt = 0; nt < 4; nt++) {
    s16x8 b0 = *(const s16x8*)&w2gt[(size_t)(nt*16+row)*64 + kg*8];
    s16x8 b1 = *(const s16x8*)&w2gt[(size_t)(nt*16+row)*64 + 32 + kg*8];
    acc1[nt] = MFMA16(apw[0], b0, acc1[nt]);
    acc1[nt] = MFMA16(apw[1], b1, acc1[nt]);
  }

  // sigmoid -> gate LDS (C-layout scatter write, swizzled)
  #pragma unroll
  for (int nt = 0; nt < 4; nt++) {
    #pragma unroll
    for (int r = 0; r < 4; r++) {
      int grow = wave*16 + kg*4 + r;
      int gcol = nt*16 + row;
      int byt = (grow << 7) + (gcol << 1);
      byt ^= (grow & 7) << 4;
      *(unsigned short*)((char*)gate + byt) = f2bf(sigf(acc1[nt][r]));
    }
  }
  __syncthreads();

  // read gate in A-layout, pwg frags = pw * gate
  s16x8 apg[2];
  #pragma unroll
  for (int ks = 0; ks < 2; ks++) {
    int arow = wave*16 + row;
    int byt = (arow << 7) + ks*64 + kg*16;
    byt ^= (arow & 7) << 4;
    s16x8 g = *(s16x8*)((char*)gate + byt);
    s16x8 o;
    #pragma unroll
    for (int j = 0; j < 8; j++) {
      float v = bf2f((unsigned short)apw[ks][j]) * bf2f((unsigned short)g[j]);
      o[j] = (short)f2bf(v);
    }
    apg[ks] = o;
  }

  // phase B: az = cs@W1t + pwg@W2t
  f32x4 acc2[8];
  #pragma unroll
  for (int nt = 0; nt < 8; nt++) { acc2[nt][0]=0.f; acc2[nt][1]=0.f; acc2[nt][2]=0.f; acc2[nt][3]=0.f; }
  #pragma unroll
  for (int nt = 0; nt < 8; nt++) {
    #pragma unroll
    for (int ks = 0; ks < 2; ks++) {
      s16x8 b1 = *(const s16x8*)&w1t[(size_t)(nt*16+row)*64 + ks*32 + kg*8];
      acc2[nt] = MFMA16(acs[ks], b1, acc2[nt]);
      s16x8 b2 = *(const s16x8*)&w2t[(size_t)(nt*16+row)*64 + ks*32 + kg*8];
      acc2[nt] = MFMA16(apg[ks], b2, acc2[nt]);
    }
  }

  // phase C: az -> LDS zb bf16
  #pragma unroll
  for (int nt = 0; nt < 8; nt++) {
    #pragma unroll
    for (int r = 0; r < 4; r++) {
      zb[wave*16 + kg*4 + r][nt*16 + row] = f2bf(acc2[nt][r]);
    }
  }
  __syncthreads();

  // phase D: wave's 16 edges, software-pipelined batches of 4
  {
    int l = lane;
    int e0 = wave*16;
    int cur = src_s[e0];
    s16x8 sp = *(const s16x8*)&spackb[(size_t)cur*512 + l*8];
    float Ags0 = bf2f((unsigned short)sp[0]), Cgs0 = bf2f((unsigned short)sp[1]);
    float Ams0 = bf2f((unsigned short)sp[2]), Cms0 = bf2f((unsigned short)sp[3]);
    float Ags1 = bf2f((unsigned short)sp[4]), Cgs1 = bf2f((unsigned short)sp[5]);
    float Ams1 = bf2f((unsigned short)sp[6]), Cms1 = bf2f((unsigned short)sp[7]);
    float acc0 = 0.f, accB = 0.f;

    s16x8 tp[4]; unsigned int zz[4];
    #pragma unroll
    for (int b = 0; b < 4; b++) {
      tp[b] = *(const s16x8*)&tpackb[(size_t)tgt_s[e0+b]*512 + l*8];
      zz[b] = *(const unsigned int*)&zb[e0+b][2*l];
    }
    for (int eb = e0; eb < e0 + 16; eb += 4) {
      s16x8 tpn[4]; unsigned int zzn[4];
      if (eb + 4 < e0 + 16) {
        #pragma unroll
        for (int b = 0; b < 4; b++) {
          tpn[b] = *(const s16x8*)&tpackb[(size_t)tgt_s[eb+4+b]*512 + l*8];
          zzn[b] = *(const unsigned int*)&zb[eb+4+b][2*l];
        }
      }
      #pragma unroll
      for (int b = 0; b < 4; b++) {
        int e = eb + b;
        int sn = src_s[e];
        if (sn != cur) {   // wave-uniform (src-sorted)
          atomicAdd(&h_acc[(size_t)cur*H + 2*l],     acc0);
          atomicAdd(&h_acc[(size_t)cur*H + 2*l + 1], accB);
          acc0 = 0.f; accB = 0.f; cur = sn;
          sp = *(const s16x8*)&spackb[(size_t)cur*512 + l*8];
          Ags0 = bf2f((unsigned short)sp[0]); Cgs0 = bf2f((unsigned short)sp[1]);
          Ams0 = bf2f((unsigned short)sp[2]); Cms0 = bf2f((unsigned short)sp[3]);
          Ags1 = bf2f((unsigned short)sp[4]); Cgs1 = bf2f((unsigned short)sp[5]);
          Ams1 = bf2f((unsigned short)sp[6]); Cms1 = bf2f((unsigned short)sp[7]);
        }
        float rc = rcp_s[e], mk = msk_s[e];
        float z0 = bf2f((unsigned short)(zz[b] & 0xffffu));
        float z1 = bf2f((unsigned short)(zz[b] >> 16));
        float Bg0 = bf2f((unsigned short)tp[b][0]), Cg0 = bf2f((unsigned short)tp[b][1]);
        float Bm0 = bf2f((unsigned short)tp[b][2]), Cm0 = bf2f((unsigned short)tp[b][3]);
        float Bg1 = bf2f((unsigned short)tp[b][4]), Cg1 = bf2f((unsigned short)tp[b][5]);
        float Bm1 = bf2f((unsigned short)tp[b][6]), Cm1 = bf2f((unsigned short)tp[b][7]);
        float g0 = sigf(Ags0 + Bg0 + rc*(Cgs0 - Cg0));
        float m0 = eluf(Ams0 + Bm0 + rc*(Cms0 - Cm0));
        acc0 += g0 * m0 * z0 * mk;
        float g1 = sigf(Ags1 + Bg1 + rc*(Cgs1 - Cg1));
        float m1 = eluf(Ams1 + Bm1 + rc*(Cms1 - Cm1));
        accB += g1 * m1 * z1 * mk;
      }
      #pragma unroll
      for (int b = 0; b < 4; b++) { tp[b] = tpn[b]; zz[b] = zzn[b]; }
    }
    atomicAdd(&h_acc[(size_t)cur*H + 2*l],     acc0);
    atomicAdd(&h_acc[(size_t)cur*H + 2*l + 1], accB);
  }
}

// ---------------- node_next: psi/pool GEMMs + next-layer pack GEMM from LDS ----------------
__global__ __launch_bounds__(256) void node_next(
    float* __restrict__ h,                       // in/out (in-place update)
    const unsigned short* __restrict__ wpt,      // this layer p1/p2/psi
    const unsigned short* __restrict__ wnt,      // NEXT layer Wg/Wm
    const int* __restrict__ gidx, float* __restrict__ pooled,
    unsigned short* __restrict__ spackb, unsigned short* __restrict__ tpackb,
    int has_next)
{
  __shared__ unsigned short hb[32*128];          // 8 KB swizzled bf16 h_next
  int tid = threadIdx.x, wave = tid >> 6, lane = tid & 63;
  int row = lane & 15, kg = lane >> 4;
  int nh = wave & 1, hf = (wave >> 1)*64;
  int nbase = blockIdx.x*32 + nh*16;
  int nA = nbase + row;
  int nclamp = nA < N_NODES ? nA : N_NODES-1;
  const float* hr = &h[(size_t)nclamp*H];
  s16x8 a[4];
  #pragma unroll
  for (int ks = 0; ks < 4; ks++) a[ks] = loadA_f32(hr + ks*32 + kg*8);

  f32x4 acc1[4], acc2[4], acc3[4];
  #pragma unroll
  for (int t = 0; t < 4; t++) {
    #pragma unroll
    for (int r = 0; r < 4; r++) { acc1[t][r]=0.f; acc2[t][r]=0.f; acc3[t][r]=0.f; }
  }
  #pragma unroll
  for (int t = 0; t < 4; t++) {
    int col = hf + t*16 + row;
    #pragma unroll
    for (int ks = 0; ks < 4; ks++) {
      s16x8 b1 = *(const s16x8*)&wpt[(size_t)(col      )*128 + ks*32 + kg*8];
      s16x8 b2 = *(const s16x8*)&wpt[(size_t)(col + 128)*128 + ks*32 + kg*8];
      s16x8 b3 = *(const s16x8*)&wpt[(size_t)(col + 256)*128 + ks*32 + kg*8];
      acc1[t] = MFMA16(a[ks], b1, acc1[t]);
      acc2[t] = MFMA16(a[ks], b2, acc2[t]);
      acc3[t] = MFMA16(a[ks], b3, acc3[t]);
    }
  }

  int nc0 = nbase + kg*4;
  int g0 = (nc0     < N_NODES) ? gidx[nc0]     : -1;
  int g3 = (nc0 + 3 < N_NODES) ? gidx[nc0 + 3] : -2;
  if (g0 == g3) {
    #pragma unroll
    for (int t = 0; t < 4; t++) {
      int col = hf + t*16 + row;
      float s = 0.f;
      #pragma unroll
      for (int r = 0; r < 4; r++) s += eluf(acc1[t][r] * acc2[t][r]);
      atomicAdd(&pooled[g0*H + col], s);
      #pragma unroll
      for (int r = 0; r < 4; r++) {
        float v = eluf(acc3[t][r]);
        h[(size_t)(nc0 + r)*H + col] = v;
        int ln = nh*16 + kg*4 + r;
        int byt = (ln << 8) + (col << 1);
        byt ^= (ln & 7) << 4;
        *(unsigned short*)((char*)hb + byt) = f2bf(v);
      }
    }
  } else {
    #pragma unroll
    for (int r = 0; r < 4; r++) {
      int nc = nc0 + r;
      int ln = nh*16 + kg*4 + r;
      bool ok = nc < N_NODES;
      int g = ok ? gidx[nc] : 0;
      #pragma unroll
      for (int t = 0; t < 4; t++) {
        int col = hf + t*16 + row;
        float zp = ok ? eluf(acc1[t][r] * acc2[t][r]) : 0.f;
        if (ok) atomicAdd(&pooled[g*H + col], zp);
        float v = eluf(acc3[t][r]);
        if (ok) h[(size_t)nc*H + col] = v;
        int byt = (ln << 8) + (col << 1);
        byt ^= (ln & 7) << 4;
        *(unsigned short*)((char*)hb + byt) = f2bf(v);
      }
    }
  }
  if (!has_next) return;
  __syncthreads();

  // pack GEMM from LDS h_next: wave = (row-tile rt, col stride 2)
  int rt = wave & 1;
  int arow = rt*16 + row;
  s16x8 an[4];
  #pragma unroll
  for (int ks = 0; ks < 4; ks++) {
    int byt = (arow << 8) + ks*64 + kg*16;
    byt ^= (arow & 7) << 4;
    an[ks] = *(s16x8*)((char*)hb + byt);
  }
  int nb2 = blockIdx.x*32 + rt*16;
  for (int m = 0; m < 24; m++) {
    int jt = (wave >> 1) + m*2;     // 0..47
    int col = jt*16 + row;
    f32x4 acc; acc[0]=0.f; acc[1]=0.f; acc[2]=0.f; acc[3]=0.f;
    #pragma unroll
    for (int ks = 0; ks < 4; ks++) {
      s16x8 b = *(const s16x8*)&wnt[(size_t)col*128 + ks*32 + kg*8];
      acc = MFMA16(an[ks], b, acc);
    }
    int ch = jt >> 3;
    int c = (jt & 7)*16 + row;
    #pragma unroll
    for (int r = 0; r < 4; r++) {
      int nc = nb2 + kg*4 + r;
      if (nc >= N_NODES) continue;
      unsigned short bv = f2bf(acc[r]);
      size_t base = (size_t)nc*512 + c*4;
      if (ch == 0)      spackb[base + 0] = bv;
      else if (ch == 1) tpackb[base + 0] = bv;
      else if (ch == 2) { spackb[base + 1] = bv; tpackb[base + 1] = bv; }
      else if (ch == 3) spackb[base + 2] = bv;
      else if (ch == 4) tpackb[base + 2] = bv;
      else              { spackb[base + 3] = bv; tpackb[base + 3] = bv; }
    }
  }
}

// ---------------- final: y = elu(elu(pooled @ lr1) @ lr2) ----------------
__global__ __launch_bounds__(64) void final_kernel(
    const float* __restrict__ pooled, const float* __restrict__ lr1, const float* __restrict__ lr2,
    float* __restrict__ out)
{
  __shared__ float sp[128];
  __shared__ float y1[64];
  int g = blockIdx.x, tid = threadIdx.x;
  sp[tid]      = pooled[g*128 + tid];
  sp[tid + 64] = pooled[g*128 + 64 + tid];
  __syncthreads();
  float acc = 0.f;
  for (int k = 0; k < 128; k++) acc += sp[k] * lr1[k*64 + tid];
  y1[tid] = eluf(acc);
  __syncthreads();
  if (tid < 32) {
    float a2 = 0.f;
    for (int k = 0; k < 64; k++) a2 += y1[k] * lr2[k*32 + tid];
    out[g*32 + tid] = eluf(a2);
  }
}

extern "C" void kernel_launch(void* const* d_in, const int* in_sizes, int n_in,
                              void* d_out, int out_size, void* d_ws, size_t ws_size,
                              hipStream_t stream)
{
  const float* x    = (const float*)d_in[0];
  const float* ed   = (const float*)d_in[1];
  const float* cs   = (const float*)d_in[2];
  const float* pw   = (const float*)d_in[3];
  const float* embW = (const float*)d_in[4];
  const float* Wg   = (const float*)d_in[5];
  const float* Wm   = (const float*)d_in[6];
  const float* W1   = (const float*)d_in[7];
  const float* W2g  = (const float*)d_in[8];
  const float* W2   = (const float*)d_in[9];
  const float* p1   = (const float*)d_in[10];
  const float* p2   = (const float*)d_in[11];
  const float* psiW = (const float*)d_in[12];
  const float* lr1  = (const float*)d_in[13];
  const float* lr2  = (const float*)d_in[14];
  const int* esrc   = (const int*)d_in[15];
  const int* etgt   = (const int*)d_in[16];
  const int* gidx   = (const int*)d_in[17];

  float* h_b    = (float*)d_ws;                 // 1,280,000 f
  float* pooled = h_b + (size_t)N_NODES*H;      // 12,800 f
  unsigned short* spackb = (unsigned short*)(pooled + 100*H); // N_NODES*512 us
  unsigned short* tpackb = spackb + (size_t)N_NODES*512;      // N_NODES*512 us
  int* counts  = (int*)(tpackb + (size_t)N_NODES*512);
  int* offsets = counts + N_NODES;              // N_NODES+1
  int* cursor  = offsets + N_NODES + 1;
  int* perm    = cursor + N_NODES;              // N_EDGES
  int* srcp    = perm + N_EDGES;                // N_EDGES
  int* tgtp    = srcp + N_EDGES;                // N_EDGES
  float* edp   = (float*)(tgtp + N_EDGES);      // N_EDGES
  unsigned short* w1t  = (unsigned short*)(edp + N_EDGES); // 3*8192
  unsigned short* w2t  = w1t + 3*8192;
  unsigned short* w2gt = w2t + 3*8192;          // 3*4096
  unsigned short* embt = w2gt + 3*4096;         // 16384
  unsigned short* wnt  = embt + 16384;          // 3*98304
  unsigned short* wpt  = wnt + 3*98304;         // 3*49152
  unsigned short* csb  = wpt + 3*49152;         // N_EDGES*64
  unsigned short* pwb  = csb + (size_t)N_EDGES*64; // N_EDGES*64

  // one-time: edge sort by src + de-indirect + bf16 conversions
  hipMemsetAsync(counts, 0, N_NODES*sizeof(int), stream);
  hipMemsetAsync(pooled, 0, 100*H*sizeof(float), stream);
  hist_kernel<<<(N_EDGES+255)/256, 256, 0, stream>>>(esrc, counts);
  scan_kernel<<<1, 256, 0, stream>>>(counts, offsets);
  hipMemcpyAsync(cursor, offsets, N_NODES*sizeof(int), hipMemcpyDeviceToDevice, stream);
  scatter_kernel<<<(N_EDGES+255)/256, 256, 0, stream>>>(esrc, etgt, ed, cursor, perm, srcp, tgtp, edp);
  prep_edges<<<N_EDGES*8/256, 256, 0, stream>>>(cs, pw, perm, csb, pwb);
  prep_weights<<<208, 256, 0, stream>>>(W1, W2, W2g, embW, w1t, w2t, w2gt, embt);
  prep_nodew<<<(3*98304 + 3*49152 + 255)/256, 256, 0, stream>>>(Wg, Wm, p1, p2, psiW, wnt, wpt);

  embed_mfma<<<(N_NODES+31)/32, 256, 0, stream>>>(x, embt, h_b);
  nodeA_mfma<<<(N_NODES+31)/32, 256, 0, stream>>>(h_b, wnt, spackb, tpackb);

  for (int i = 0; i < 3; i++) {
    fused_edge<<<N_EDGES/64, 256, 0, stream>>>(h_b, csb, pwb,
        w1t + i*8192, w2t + i*8192, w2gt + i*4096,
        srcp, tgtp, edp, spackb, tpackb);
    node_next<<<(N_NODES+31)/32, 256, 0, stream>>>(h_b,
        wpt + i*49152, wnt + ((i+1) % 3)*98304,
        gidx, pooled, spackb, tpackb, (i < 2) ? 1 : 0);
  }
  final_kernel<<<100, 64, 0, stream>>>(pooled, lr1, lr2, (float*)d_out);
}

// Round 10
// 458.605 us; speedup vs baseline: 14.5933x; 1.0760x over previous
//
#include <hip/hip_runtime.h>
#include <math.h>

#define H 128
#define N_NODES 10000
#define N_EDGES 160000

typedef float f32x4 __attribute__((ext_vector_type(4)));
typedef short s16x8 __attribute__((ext_vector_type(8)));

__device__ __forceinline__ float sigf(float x){ return 1.0f/(1.0f + __expf(-x)); }
__device__ __forceinline__ float eluf(float x){ return x > 0.0f ? x : (__expf(x) - 1.0f); }

__device__ __forceinline__ unsigned short f2bf(float f){
  unsigned int u = __float_as_uint(f);
  unsigned int r = (u + 0x7fffu + ((u >> 16) & 1u)) >> 16;
  return (unsigned short)r;
}
__device__ __forceinline__ float bf2f(unsigned short s){
  return __uint_as_float(((unsigned int)s) << 16);
}

__device__ __forceinline__ f32x4 MFMA16(s16x8 a, s16x8 b, f32x4 c){
  return __builtin_amdgcn_mfma_f32_16x16x32_bf16(a, b, c, 0, 0, 0);
}

__device__ __forceinline__ s16x8 loadA_f32(const float* p){
  float4 a = *(const float4*)p;
  float4 b = *(const float4*)(p+4);
  s16x8 r;
  r[0]=(short)f2bf(a.x); r[1]=(short)f2bf(a.y); r[2]=(short)f2bf(a.z); r[3]=(short)f2bf(a.w);
  r[4]=(short)f2bf(b.x); r[5]=(short)f2bf(b.y); r[6]=(short)f2bf(b.z); r[7]=(short)f2bf(b.w);
  return r;
}

// ---------------- edge sort by (masked, src): hist(active) -> scan -> scatter ----------------
__global__ __launch_bounds__(256) void hist_kernel(
    const int* __restrict__ src, const float* __restrict__ ed, int* __restrict__ count)
{
  int e = blockIdx.x*256 + threadIdx.x;
  if (e < N_EDGES && ed[e] < 8.0f) atomicAdd(&count[src[e]], 1);
}

__global__ __launch_bounds__(256) void scan_kernel(
    const int* __restrict__ count, int* __restrict__ offsets)
{
  __shared__ int tmp[256];
  __shared__ int sbase;
  if (threadIdx.x == 0) sbase = 0;
  __syncthreads();
  for (int c0 = 0; c0 < N_NODES; c0 += 256) {
    int i = c0 + threadIdx.x;
    int v = (i < N_NODES) ? count[i] : 0;
    tmp[threadIdx.x] = v;
    __syncthreads();
    for (int off = 1; off < 256; off <<= 1) {
      int t = (threadIdx.x >= off) ? tmp[threadIdx.x - off] : 0;
      __syncthreads();
      tmp[threadIdx.x] += t;
      __syncthreads();
    }
    if (i < N_NODES) offsets[i] = sbase + tmp[threadIdx.x] - v;
    __syncthreads();
    if (threadIdx.x == 255) sbase += tmp[255];
    __syncthreads();
  }
  if (threadIdx.x == 0) offsets[N_NODES] = sbase;   // n_active
}

__global__ __launch_bounds__(256) void scatter_kernel(
    const int* __restrict__ src, const int* __restrict__ tgt, const float* __restrict__ ed,
    const int* __restrict__ offsets,
    int* __restrict__ cursor, int* __restrict__ mcur, int* __restrict__ perm,
    int* __restrict__ srcp, int* __restrict__ tgtp, float* __restrict__ edp)
{
  int e = blockIdx.x*256 + threadIdx.x;
  if (e < N_EDGES) {
    int s = src[e];
    float r = ed[e];
    int pos;
    if (r < 8.0f) pos = atomicAdd(&cursor[s], 1);
    else          pos = offsets[N_NODES] + atomicAdd(mcur, 1);
    perm[pos] = e;
    srcp[pos] = s;
    tgtp[pos] = tgt[e];
    edp[pos]  = r;
  }
}

// ---------------- prep_edges: permuted bf16 copies of cs, pw ----------------
__global__ __launch_bounds__(256) void prep_edges(
    const float* __restrict__ cs, const float* __restrict__ pw, const int* __restrict__ perm,
    unsigned short* __restrict__ csb, unsigned short* __restrict__ pwb)
{
  int idx = blockIdx.x*256 + threadIdx.x;   // over N_EDGES*8
  if (idx >= N_EDGES*8) return;
  int pos = idx >> 3, kc = idx & 7;
  int e = perm[pos];
  s16x8 c = loadA_f32(&cs[(size_t)e*64 + kc*8]);
  s16x8 p = loadA_f32(&pw[(size_t)e*64 + kc*8]);
  *(s16x8*)&csb[(size_t)pos*64 + kc*8] = c;
  *(s16x8*)&pwb[(size_t)pos*64 + kc*8] = p;
}

// ---------------- prep_weights: W1,W2,W2g,embW -> bf16 [col][k] ----------------
__global__ __launch_bounds__(256) void prep_weights(
    const float* __restrict__ W1, const float* __restrict__ W2, const float* __restrict__ W2g,
    const float* __restrict__ embW,
    unsigned short* __restrict__ w1t, unsigned short* __restrict__ w2t,
    unsigned short* __restrict__ w2gt, unsigned short* __restrict__ embt)
{
  int idx = blockIdx.x*256 + threadIdx.x;
  if (idx < 3*8192) {
    int l = idx / 8192, r = idx % 8192;
    int c = r >> 6, k = r & 63;
    w1t[idx] = f2bf(W1[l*8192 + k*128 + c]);
    w2t[idx] = f2bf(W2[l*8192 + k*128 + c]);
  } else if (idx < 3*8192 + 3*4096) {
    int idx2 = idx - 3*8192;
    int l = idx2 / 4096, r = idx2 % 4096;
    int c = r >> 6, k = r & 63;
    w2gt[idx2] = f2bf(W2g[l*4096 + k*64 + c]);
  } else {
    int idx3 = idx - (3*8192 + 3*4096);
    if (idx3 < 16384) {
      int c = idx3 >> 7, k = idx3 & 127;
      embt[idx3] = f2bf(embW[k*128 + c]);
    }
  }
}

// ---------------- prep_nodew: bf16 [col][k] transposes for node GEMMs ----------------
__global__ __launch_bounds__(256) void prep_nodew(
    const float* __restrict__ Wg, const float* __restrict__ Wm,
    const float* __restrict__ p1, const float* __restrict__ p2, const float* __restrict__ psiW,
    unsigned short* __restrict__ wnt, unsigned short* __restrict__ wpt)
{
  int idx = blockIdx.x*256 + threadIdx.x;
  if (idx < 3*98304) {
    int l = idx / 98304, r = idx % 98304;
    int j = r >> 7, k = r & 127;
    float v;
    if (j < 384) v = Wg[l*49152 + (j>>7)*16384 + k*128 + (j&127)];
    else { int jj = j - 384; v = Wm[l*49152 + (jj>>7)*16384 + k*128 + (jj&127)]; }
    wnt[idx] = f2bf(v);
  } else {
    int idx2 = idx - 3*98304;
    if (idx2 < 3*49152) {
      int l = idx2 / 49152, r = idx2 % 49152;
      int j = r >> 7, k = r & 127;
      float v;
      if (j < 128)      v = p1 [l*16384 + k*128 + j];
      else if (j < 256) v = p2 [l*16384 + k*128 + (j-128)];
      else              v = psiW[l*16384 + k*128 + (j-256)];
      wpt[idx2] = f2bf(v);
    }
  }
}

// ---------------- embed (MFMA): h = sigmoid(x @ emb_W) ----------------
__global__ __launch_bounds__(256) void embed_mfma(
    const float* __restrict__ x, const unsigned short* __restrict__ embt,
    float* __restrict__ h_out)
{
  int tid = threadIdx.x, wave = tid >> 6, lane = tid & 63;
  int row = lane & 15, kg = lane >> 4;
  int nbase = blockIdx.x*32 + (wave & 1)*16;
  int hf = (wave >> 1) * 64;
  int nA = nbase + row;
  int nclamp = nA < N_NODES ? nA : N_NODES-1;
  const float* xr = &x[(size_t)nclamp*H];
  s16x8 a[4];
  #pragma unroll
  for (int ks = 0; ks < 4; ks++) a[ks] = loadA_f32(xr + ks*32 + kg*8);

  f32x4 acc[4];
  #pragma unroll
  for (int t = 0; t < 4; t++) { acc[t][0]=0.f; acc[t][1]=0.f; acc[t][2]=0.f; acc[t][3]=0.f; }
  #pragma unroll
  for (int t = 0; t < 4; t++) {
    int col = hf + t*16 + row;
    #pragma unroll
    for (int ks = 0; ks < 4; ks++) {
      s16x8 b = *(const s16x8*)&embt[(size_t)col*128 + ks*32 + kg*8];
      acc[t] = MFMA16(a[ks], b, acc[t]);
    }
  }
  #pragma unroll
  for (int r = 0; r < 4; r++) {
    int nc = nbase + kg*4 + r;
    if (nc >= N_NODES) continue;
    #pragma unroll
    for (int t = 0; t < 4; t++) {
      int col = hf + t*16 + row;
      h_out[(size_t)nc*H + col] = sigf(acc[t][r]);
    }
  }
}

// ---------------- nodeA (MFMA): layer-0 pack tables, coalesced 8B pack stores ----------------
// ch: 0=Ag 1=Bg 2=Cg 3=Am 4=Bm 5=Cm ; spackb[n][c]={Ag,Cg,Am,Cm} tpackb[n][c]={Bg,Cg,Bm,Cm}
__global__ __launch_bounds__(256) void nodeA_mfma(
    const float* __restrict__ h, const unsigned short* __restrict__ wnt,
    unsigned short* __restrict__ spackb, unsigned short* __restrict__ tpackb)
{
  int tid = threadIdx.x, wave = tid >> 6, lane = tid & 63;
  int row = lane & 15, kg = lane >> 4;
  int nbase = blockIdx.x*32 + (wave & 1)*16;
  int tw = (wave >> 1) * 4;
  int nA = nbase + row;
  int nclamp = nA < N_NODES ? nA : N_NODES-1;
  const float* hr = &h[(size_t)nclamp*H];
  s16x8 a[4];
  #pragma unroll
  for (int ks = 0; ks < 4; ks++) a[ks] = loadA_f32(hr + ks*32 + kg*8);

  #pragma unroll
  for (int ti = 0; ti < 4; ti++) {
    int t = tw + ti;
    f32x4 acc[6];
    #pragma unroll
    for (int ch = 0; ch < 6; ch++) { acc[ch][0]=0.f; acc[ch][1]=0.f; acc[ch][2]=0.f; acc[ch][3]=0.f; }
    #pragma unroll
    for (int ch = 0; ch < 6; ch++) {
      int col = ch*128 + t*16 + row;
      #pragma unroll
      for (int ks = 0; ks < 4; ks++) {
        s16x8 b = *(const s16x8*)&wnt[(size_t)col*128 + ks*32 + kg*8];
        acc[ch] = MFMA16(a[ks], b, acc[ch]);
      }
    }
    int c = t*16 + row;
    #pragma unroll
    for (int r = 0; r < 4; r++) {
      int nc = nbase + kg*4 + r;
      if (nc >= N_NODES) continue;
      size_t base = (size_t)nc*512 + c*4;
      unsigned int s0 = (unsigned int)f2bf(acc[0][r]) | ((unsigned int)f2bf(acc[2][r]) << 16);
      unsigned int s1 = (unsigned int)f2bf(acc[3][r]) | ((unsigned int)f2bf(acc[5][r]) << 16);
      unsigned int t0 = (unsigned int)f2bf(acc[1][r]) | ((unsigned int)f2bf(acc[2][r]) << 16);
      unsigned int t1 = (unsigned int)f2bf(acc[4][r]) | ((unsigned int)f2bf(acc[5][r]) << 16);
      *(uint2*)&spackb[base] = make_uint2(s0, s1);
      *(uint2*)&tpackb[base] = make_uint2(t0, t1);
    }
  }
}

// ---------------- fused edge: MFMA z + combine; masked edges compacted to tail ----------------
__global__ __launch_bounds__(256) void fused_edge(
    float* __restrict__ h_acc,
    const unsigned short* __restrict__ csb, const unsigned short* __restrict__ pwb,
    const unsigned short* __restrict__ w1t, const unsigned short* __restrict__ w2t,
    const unsigned short* __restrict__ w2gt,
    const int* __restrict__ srcp, const int* __restrict__ tgtp,
    const float* __restrict__ edp, const int* __restrict__ nact,
    const unsigned short* __restrict__ spackb, const unsigned short* __restrict__ tpackb)
{
  __shared__ unsigned short gate[64*64];     // 8 KB, XOR-swizzled
  __shared__ unsigned short zb[64][132];     // 16.5 KB bf16 z
  __shared__ int   src_s[64];
  __shared__ int   tgt_s[64];
  __shared__ float rcp_s[64];
  __shared__ float msk_s[64];

  int p0 = blockIdx.x * 64;
  if (p0 >= *nact) return;                   // fully-masked tail block

  int tid  = threadIdx.x;
  int wave = tid >> 6, lane = tid & 63;
  int row  = lane & 15, kg = lane >> 4;

  if (tid < 64) {
    float r = edp[p0 + tid];
    rcp_s[tid] = 1.0f / r;
    msk_s[tid] = (r < 8.0f) ? 1.0f : 0.0f;
    src_s[tid] = srcp[p0 + tid];
    tgt_s[tid] = tgtp[p0 + tid];
  }

  int pos = p0 + wave*16 + row;
  s16x8 acs[2], apw[2];
  acs[0] = *(const s16x8*)&csb[(size_t)pos*64 + kg*8];
  acs[1] = *(const s16x8*)&csb[(size_t)pos*64 + 32 + kg*8];
  apw[0] = *(const s16x8*)&pwb[(size_t)pos*64 + kg*8];
  apw[1] = *(const s16x8*)&pwb[(size_t)pos*64 + 32 + kg*8];

  // phase A: S1 = pw @ W2g
  f32x4 acc1[4];
  #pragma unroll
  for (int nt = 0; nt < 4; nt++) { acc1[nt][0]=0.f; acc1[nt][1]=0.f; acc1[nt][2]=0.f; acc1[nt][3]=0.f; }
  #pragma unroll
  for (int nt = 0; nt < 4; nt++) {
    s16x8 b0 = *(const s16x8*)&w2gt[(size_t)(nt*16+row)*64 + kg*8];
    s16x8 b1 = *(const s16x8*)&w2gt[(size_t)(nt*16+row)*64 + 32 + kg*8];
    acc1[nt] = MFMA16(apw[0], b0, acc1[nt]);
    acc1[nt] = MFMA16(apw[1], b1, acc1[nt]);
  }

  // sigmoid -> gate LDS (C-layout scatter write, swizzled)
  #pragma unroll
  for (int nt = 0; nt < 4; nt++) {
    #pragma unroll
    for (int r = 0; r < 4; r++) {
      int grow = wave*16 + kg*4 + r;
      int gcol = nt*16 + row;
      int byt = (grow << 7) + (gcol << 1);
      byt ^= (grow & 7) << 4;
      *(unsigned short*)((char*)gate + byt) = f2bf(sigf(acc1[nt][r]));
    }
  }
  __syncthreads();

  // read gate in A-layout, pwg frags = pw * gate
  s16x8 apg[2];
  #pragma unroll
  for (int ks = 0; ks < 2; ks++) {
    int arow = wave*16 + row;
    int byt = (arow << 7) + ks*64 + kg*16;
    byt ^= (arow & 7) << 4;
    s16x8 g = *(s16x8*)((char*)gate + byt);
    s16x8 o;
    #pragma unroll
    for (int j = 0; j < 8; j++) {
      float v = bf2f((unsigned short)apw[ks][j]) * bf2f((unsigned short)g[j]);
      o[j] = (short)f2bf(v);
    }
    apg[ks] = o;
  }

  // phase B: az = cs@W1t + pwg@W2t
  f32x4 acc2[8];
  #pragma unroll
  for (int nt = 0; nt < 8; nt++) { acc2[nt][0]=0.f; acc2[nt][1]=0.f; acc2[nt][2]=0.f; acc2[nt][3]=0.f; }
  #pragma unroll
  for (int nt = 0; nt < 8; nt++) {
    #pragma unroll
    for (int ks = 0; ks < 2; ks++) {
      s16x8 b1 = *(const s16x8*)&w1t[(size_t)(nt*16+row)*64 + ks*32 + kg*8];
      acc2[nt] = MFMA16(acs[ks], b1, acc2[nt]);
      s16x8 b2 = *(const s16x8*)&w2t[(size_t)(nt*16+row)*64 + ks*32 + kg*8];
      acc2[nt] = MFMA16(apg[ks], b2, acc2[nt]);
    }
  }

  // phase C: az -> LDS zb bf16
  #pragma unroll
  for (int nt = 0; nt < 8; nt++) {
    #pragma unroll
    for (int r = 0; r < 4; r++) {
      zb[wave*16 + kg*4 + r][nt*16 + row] = f2bf(acc2[nt][r]);
    }
  }
  __syncthreads();

  // phase D: wave's 16 edges, batches of 4
  {
    int l = lane;
    int e0 = wave*16;
    int cur = src_s[e0];
    s16x8 sp = *(const s16x8*)&spackb[(size_t)cur*512 + l*8];
    float Ags0 = bf2f((unsigned short)sp[0]), Cgs0 = bf2f((unsigned short)sp[1]);
    float Ams0 = bf2f((unsigned short)sp[2]), Cms0 = bf2f((unsigned short)sp[3]);
    float Ags1 = bf2f((unsigned short)sp[4]), Cgs1 = bf2f((unsigned short)sp[5]);
    float Ams1 = bf2f((unsigned short)sp[6]), Cms1 = bf2f((unsigned short)sp[7]);
    float acc0 = 0.f, accB = 0.f;
    for (int eb = e0; eb < e0 + 16; eb += 4) {
      s16x8 tp[4]; unsigned int zz[4];
      #pragma unroll
      for (int b = 0; b < 4; b++) {
        int e = eb + b;
        tp[b] = *(const s16x8*)&tpackb[(size_t)tgt_s[e]*512 + l*8];
        zz[b] = *(const unsigned int*)&zb[e][2*l];
      }
      #pragma unroll
      for (int b = 0; b < 4; b++) {
        int e = eb + b;
        int sn = src_s[e];
        if (sn != cur) {   // wave-uniform (src-sorted)
          atomicAdd(&h_acc[(size_t)cur*H + 2*l],     acc0);
          atomicAdd(&h_acc[(size_t)cur*H + 2*l + 1], accB);
          acc0 = 0.f; accB = 0.f; cur = sn;
          sp = *(const s16x8*)&spackb[(size_t)cur*512 + l*8];
          Ags0 = bf2f((unsigned short)sp[0]); Cgs0 = bf2f((unsigned short)sp[1]);
          Ams0 = bf2f((unsigned short)sp[2]); Cms0 = bf2f((unsigned short)sp[3]);
          Ags1 = bf2f((unsigned short)sp[4]); Cgs1 = bf2f((unsigned short)sp[5]);
          Ams1 = bf2f((unsigned short)sp[6]); Cms1 = bf2f((unsigned short)sp[7]);
        }
        float rc = rcp_s[e], mk = msk_s[e];
        float z0 = bf2f((unsigned short)(zz[b] & 0xffffu));
        float z1 = bf2f((unsigned short)(zz[b] >> 16));
        float Bg0 = bf2f((unsigned short)tp[b][0]), Cg0 = bf2f((unsigned short)tp[b][1]);
        float Bm0 = bf2f((unsigned short)tp[b][2]), Cm0 = bf2f((unsigned short)tp[b][3]);
        float Bg1 = bf2f((unsigned short)tp[b][4]), Cg1 = bf2f((unsigned short)tp[b][5]);
        float Bm1 = bf2f((unsigned short)tp[b][6]), Cm1 = bf2f((unsigned short)tp[b][7]);
        float g0 = sigf(Ags0 + Bg0 + rc*(Cgs0 - Cg0));
        float m0 = eluf(Ams0 + Bm0 + rc*(Cms0 - Cm0));
        acc0 += g0 * m0 * z0 * mk;
        float g1 = sigf(Ags1 + Bg1 + rc*(Cgs1 - Cg1));
        float m1 = eluf(Ams1 + Bm1 + rc*(Cms1 - Cm1));
        accB += g1 * m1 * z1 * mk;
      }
    }
    atomicAdd(&h_acc[(size_t)cur*H + 2*l],     acc0);
    atomicAdd(&h_acc[(size_t)cur*H + 2*l + 1], accB);
  }
}

// ---------------- node_next: psi/pool GEMMs + next-layer pack GEMM from LDS ----------------
__global__ __launch_bounds__(256) void node_next(
    float* __restrict__ h,                       // in/out (in-place update)
    const unsigned short* __restrict__ wpt,      // this layer p1/p2/psi
    const unsigned short* __restrict__ wnt,      // NEXT layer Wg/Wm
    const int* __restrict__ gidx, float* __restrict__ pooled,
    unsigned short* __restrict__ spackb, unsigned short* __restrict__ tpackb,
    int has_next)
{
  __shared__ unsigned short hb[32*128];          // 8 KB swizzled bf16 h_next
  int tid = threadIdx.x, wave = tid >> 6, lane = tid & 63;
  int row = lane & 15, kg = lane >> 4;
  int nh = wave & 1, hf = (wave >> 1)*64;
  int nbase = blockIdx.x*32 + nh*16;
  int nA = nbase + row;
  int nclamp = nA < N_NODES ? nA : N_NODES-1;
  const float* hr = &h[(size_t)nclamp*H];
  s16x8 a[4];
  #pragma unroll
  for (int ks = 0; ks < 4; ks++) a[ks] = loadA_f32(hr + ks*32 + kg*8);

  f32x4 acc1[4], acc2[4], acc3[4];
  #pragma unroll
  for (int t = 0; t < 4; t++) {
    #pragma unroll
    for (int r = 0; r < 4; r++) { acc1[t][r]=0.f; acc2[t][r]=0.f; acc3[t][r]=0.f; }
  }
  #pragma unroll
  for (int t = 0; t < 4; t++) {
    int col = hf + t*16 + row;
    #pragma unroll
    for (int ks = 0; ks < 4; ks++) {
      s16x8 b1 = *(const s16x8*)&wpt[(size_t)(col      )*128 + ks*32 + kg*8];
      s16x8 b2 = *(const s16x8*)&wpt[(size_t)(col + 128)*128 + ks*32 + kg*8];
      s16x8 b3 = *(const s16x8*)&wpt[(size_t)(col + 256)*128 + ks*32 + kg*8];
      acc1[t] = MFMA16(a[ks], b1, acc1[t]);
      acc2[t] = MFMA16(a[ks], b2, acc2[t]);
      acc3[t] = MFMA16(a[ks], b3, acc3[t]);
    }
  }

  int nc0 = nbase + kg*4;
  int g0 = (nc0     < N_NODES) ? gidx[nc0]     : -1;
  int g3 = (nc0 + 3 < N_NODES) ? gidx[nc0 + 3] : -2;
  if (g0 == g3) {
    #pragma unroll
    for (int t = 0; t < 4; t++) {
      int col = hf + t*16 + row;
      float s = 0.f;
      #pragma unroll
      for (int r = 0; r < 4; r++) s += eluf(acc1[t][r] * acc2[t][r]);
      atomicAdd(&pooled[g0*H + col], s);
      #pragma unroll
      for (int r = 0; r < 4; r++) {
        float v = eluf(acc3[t][r]);
        h[(size_t)(nc0 + r)*H + col] = v;
        int ln = nh*16 + kg*4 + r;
        int byt = (ln << 8) + (col << 1);
        byt ^= (ln & 7) << 4;
        *(unsigned short*)((char*)hb + byt) = f2bf(v);
      }
    }
  } else {
    #pragma unroll
    for (int r = 0; r < 4; r++) {
      int nc = nc0 + r;
      int ln = nh*16 + kg*4 + r;
      bool ok = nc < N_NODES;
      int g = ok ? gidx[nc] : 0;
      #pragma unroll
      for (int t = 0; t < 4; t++) {
        int col = hf + t*16 + row;
        float zp = ok ? eluf(acc1[t][r] * acc2[t][r]) : 0.f;
        if (ok) atomicAdd(&pooled[g*H + col], zp);
        float v = eluf(acc3[t][r]);
        if (ok) h[(size_t)nc*H + col] = v;
        int byt = (ln << 8) + (col << 1);
        byt ^= (ln & 7) << 4;
        *(unsigned short*)((char*)hb + byt) = f2bf(v);
      }
    }
  }
  if (!has_next) return;
  __syncthreads();

  // pack GEMM from LDS h_next: wave -> (row-half rt, t-quad tw); 8B coalesced pack stores
  int rt = wave & 1;
  int tw = (wave >> 1) * 4;
  int arow = rt*16 + row;
  s16x8 an[4];
  #pragma unroll
  for (int ks = 0; ks < 4; ks++) {
    int byt = (arow << 8) + ks*64 + kg*16;
    byt ^= (arow & 7) << 4;
    an[ks] = *(s16x8*)((char*)hb + byt);
  }
  int nb2 = blockIdx.x*32 + rt*16;
  #pragma unroll
  for (int ti = 0; ti < 4; ti++) {
    int t = tw + ti;
    f32x4 acc[6];
    #pragma unroll
    for (int ch = 0; ch < 6; ch++) { acc[ch][0]=0.f; acc[ch][1]=0.f; acc[ch][2]=0.f; acc[ch][3]=0.f; }
    #pragma unroll
    for (int ch = 0; ch < 6; ch++) {
      int col = ch*128 + t*16 + row;
      #pragma unroll
      for (int ks = 0; ks < 4; ks++) {
        s16x8 b = *(const s16x8*)&wnt[(size_t)col*128 + ks*32 + kg*8];
        acc[ch] = MFMA16(an[ks], b, acc[ch]);
      }
    }
    int c = t*16 + row;
    #pragma unroll
    for (int r = 0; r < 4; r++) {
      int nc = nb2 + kg*4 + r;
      if (nc >= N_NODES) continue;
      size_t base = (size_t)nc*512 + c*4;
      unsigned int s0 = (unsigned int)f2bf(acc[0][r]) | ((unsigned int)f2bf(acc[2][r]) << 16);
      unsigned int s1 = (unsigned int)f2bf(acc[3][r]) | ((unsigned int)f2bf(acc[5][r]) << 16);
      unsigned int t0 = (unsigned int)f2bf(acc[1][r]) | ((unsigned int)f2bf(acc[2][r]) << 16);
      unsigned int t1 = (unsigned int)f2bf(acc[4][r]) | ((unsigned int)f2bf(acc[5][r]) << 16);
      *(uint2*)&spackb[base] = make_uint2(s0, s1);
      *(uint2*)&tpackb[base] = make_uint2(t0, t1);
    }
  }
}

// ---------------- final: y = elu(elu(pooled @ lr1) @ lr2) ----------------
__global__ __launch_bounds__(64) void final_kernel(
    const float* __restrict__ pooled, const float* __restrict__ lr1, const float* __restrict__ lr2,
    float* __restrict__ out)
{
  __shared__ float sp[128];
  __shared__ float y1[64];
  int g = blockIdx.x, tid = threadIdx.x;
  sp[tid]      = pooled[g*128 + tid];
  sp[tid + 64] = pooled[g*128 + 64 + tid];
  __syncthreads();
  float acc = 0.f;
  for (int k = 0; k < 128; k++) acc += sp[k] * lr1[k*64 + tid];
  y1[tid] = eluf(acc);
  __syncthreads();
  if (tid < 32) {
    float a2 = 0.f;
    for (int k = 0; k < 64; k++) a2 += y1[k] * lr2[k*32 + tid];
    out[g*32 + tid] = eluf(a2);
  }
}

extern "C" void kernel_launch(void* const* d_in, const int* in_sizes, int n_in,
                              void* d_out, int out_size, void* d_ws, size_t ws_size,
                              hipStream_t stream)
{
  const float* x    = (const float*)d_in[0];
  const float* ed   = (const float*)d_in[1];
  const float* cs   = (const float*)d_in[2];
  const float* pw   = (const float*)d_in[3];
  const float* embW = (const float*)d_in[4];
  const float* Wg   = (const float*)d_in[5];
  const float* Wm   = (const float*)d_in[6];
  const float* W1   = (const float*)d_in[7];
  const float* W2g  = (const float*)d_in[8];
  const float* W2   = (const float*)d_in[9];
  const float* p1   = (const float*)d_in[10];
  const float* p2   = (const float*)d_in[11];
  const float* psiW = (const float*)d_in[12];
  const float* lr1  = (const float*)d_in[13];
  const float* lr2  = (const float*)d_in[14];
  const int* esrc   = (const int*)d_in[15];
  const int* etgt   = (const int*)d_in[16];
  const int* gidx   = (const int*)d_in[17];

  float* h_b    = (float*)d_ws;                 // 1,280,000 f
  float* pooled = h_b + (size_t)N_NODES*H;      // 12,800 f
  unsigned short* spackb = (unsigned short*)(pooled + 100*H); // N_NODES*512 us
  unsigned short* tpackb = spackb + (size_t)N_NODES*512;      // N_NODES*512 us
  int* counts  = (int*)(tpackb + (size_t)N_NODES*512);
  int* offsets = counts + N_NODES;              // N_NODES+1 (offsets[N_NODES] = n_active)
  int* cursor  = offsets + N_NODES + 1;
  int* mcur    = cursor + N_NODES;              // 1
  int* perm    = mcur + 1;                      // N_EDGES
  int* srcp    = perm + N_EDGES;                // N_EDGES
  int* tgtp    = srcp + N_EDGES;                // N_EDGES
  float* edp   = (float*)(tgtp + N_EDGES);      // N_EDGES
  unsigned short* w1t  = (unsigned short*)(edp + N_EDGES); // 3*8192
  unsigned short* w2t  = w1t + 3*8192;
  unsigned short* w2gt = w2t + 3*8192;          // 3*4096
  unsigned short* embt = w2gt + 3*4096;         // 16384
  unsigned short* wnt  = embt + 16384;          // 3*98304
  unsigned short* wpt  = wnt + 3*98304;         // 3*49152
  unsigned short* csb  = wpt + 3*49152;         // N_EDGES*64
  unsigned short* pwb  = csb + (size_t)N_EDGES*64; // N_EDGES*64

  // one-time: edge sort by (masked, src) + de-indirect + bf16 conversions
  hipMemsetAsync(counts, 0, N_NODES*sizeof(int), stream);
  hipMemsetAsync(mcur, 0, sizeof(int), stream);
  hipMemsetAsync(pooled, 0, 100*H*sizeof(float), stream);
  hist_kernel<<<(N_EDGES+255)/256, 256, 0, stream>>>(esrc, ed, counts);
  scan_kernel<<<1, 256, 0, stream>>>(counts, offsets);
  hipMemcpyAsync(cursor, offsets, N_NODES*sizeof(int), hipMemcpyDeviceToDevice, stream);
  scatter_kernel<<<(N_EDGES+255)/256, 256, 0, stream>>>(esrc, etgt, ed, offsets,
      cursor, mcur, perm, srcp, tgtp, edp);
  prep_edges<<<N_EDGES*8/256, 256, 0, stream>>>(cs, pw, perm, csb, pwb);
  prep_weights<<<208, 256, 0, stream>>>(W1, W2, W2g, embW, w1t, w2t, w2gt, embt);
  prep_nodew<<<(3*98304 + 3*49152 + 255)/256, 256, 0, stream>>>(Wg, Wm, p1, p2, psiW, wnt, wpt);

  embed_mfma<<<(N_NODES+31)/32, 256, 0, stream>>>(x, embt, h_b);
  nodeA_mfma<<<(N_NODES+31)/32, 256, 0, stream>>>(h_b, wnt, spackb, tpackb);

  for (int i = 0; i < 3; i++) {
    fused_edge<<<N_EDGES/64, 256, 0, stream>>>(h_b, csb, pwb,
        w1t + i*8192, w2t + i*8192, w2gt + i*4096,
        srcp, tgtp, edp, offsets + N_NODES, spackb, tpackb);
    node_next<<<(N_NODES+31)/32, 256, 0, stream>>>(h_b,
        wpt + i*49152, wnt + ((i+1) % 3)*98304,
        gidx, pooled, spackb, tpackb, (i < 2) ? 1 : 0);
  }
  final_kernel<<<100, 64, 0, stream>>>(pooled, lr1, lr2, (float*)d_out);
}

// Round 11
// 428.371 us; speedup vs baseline: 15.6232x; 1.0706x over previous
//
#include <hip/hip_runtime.h>
#include <math.h>

#define H 128
#define N_NODES 10000
#define N_EDGES 160000

typedef float f32x4 __attribute__((ext_vector_type(4)));
typedef short s16x8 __attribute__((ext_vector_type(8)));

__device__ __forceinline__ float sigf(float x){ return 1.0f/(1.0f + __expf(-x)); }
__device__ __forceinline__ float eluf(float x){ return x > 0.0f ? x : (__expf(x) - 1.0f); }

__device__ __forceinline__ unsigned short f2bf(float f){
  unsigned int u = __float_as_uint(f);
  unsigned int r = (u + 0x7fffu + ((u >> 16) & 1u)) >> 16;
  return (unsigned short)r;
}
__device__ __forceinline__ float bf2f(unsigned short s){
  return __uint_as_float(((unsigned int)s) << 16);
}

__device__ __forceinline__ f32x4 MFMA16(s16x8 a, s16x8 b, f32x4 c){
  return __builtin_amdgcn_mfma_f32_16x16x32_bf16(a, b, c, 0, 0, 0);
}

__device__ __forceinline__ s16x8 loadA_f32(const float* p){
  float4 a = *(const float4*)p;
  float4 b = *(const float4*)(p+4);
  s16x8 r;
  r[0]=(short)f2bf(a.x); r[1]=(short)f2bf(a.y); r[2]=(short)f2bf(a.z); r[3]=(short)f2bf(a.w);
  r[4]=(short)f2bf(b.x); r[5]=(short)f2bf(b.y); r[6]=(short)f2bf(b.z); r[7]=(short)f2bf(b.w);
  return r;
}

// ---------------- edge sort by (masked, src): hist(active) -> scan -> scatter ----------------
__global__ __launch_bounds__(256) void hist_kernel(
    const int* __restrict__ src, const float* __restrict__ ed, int* __restrict__ count)
{
  int e = blockIdx.x*256 + threadIdx.x;
  if (e < N_EDGES && ed[e] < 8.0f) atomicAdd(&count[src[e]], 1);
}

__global__ __launch_bounds__(256) void scan_kernel(
    const int* __restrict__ count, int* __restrict__ offsets)
{
  __shared__ int tmp[256];
  __shared__ int sbase;
  if (threadIdx.x == 0) sbase = 0;
  __syncthreads();
  for (int c0 = 0; c0 < N_NODES; c0 += 256) {
    int i = c0 + threadIdx.x;
    int v = (i < N_NODES) ? count[i] : 0;
    tmp[threadIdx.x] = v;
    __syncthreads();
    for (int off = 1; off < 256; off <<= 1) {
      int t = (threadIdx.x >= off) ? tmp[threadIdx.x - off] : 0;
      __syncthreads();
      tmp[threadIdx.x] += t;
      __syncthreads();
    }
    if (i < N_NODES) offsets[i] = sbase + tmp[threadIdx.x] - v;
    __syncthreads();
    if (threadIdx.x == 255) sbase += tmp[255];
    __syncthreads();
  }
  if (threadIdx.x == 0) offsets[N_NODES] = sbase;   // n_active
}

__global__ __launch_bounds__(256) void scatter_kernel(
    const int* __restrict__ src, const int* __restrict__ tgt, const float* __restrict__ ed,
    const int* __restrict__ offsets,
    int* __restrict__ cursor, int* __restrict__ mcur, int* __restrict__ perm,
    int* __restrict__ srcp, int* __restrict__ tgtp, float* __restrict__ edp)
{
  int e = blockIdx.x*256 + threadIdx.x;
  if (e < N_EDGES) {
    int s = src[e];
    float r = ed[e];
    int pos;
    if (r < 8.0f) pos = atomicAdd(&cursor[s], 1);
    else          pos = offsets[N_NODES] + atomicAdd(mcur, 1);
    perm[pos] = e;
    srcp[pos] = s;
    tgtp[pos] = tgt[e];
    edp[pos]  = r;
  }
}

// ---------------- prep_edges: permuted bf16 copies of cs, pw ----------------
__global__ __launch_bounds__(256) void prep_edges(
    const float* __restrict__ cs, const float* __restrict__ pw, const int* __restrict__ perm,
    unsigned short* __restrict__ csb, unsigned short* __restrict__ pwb)
{
  int idx = blockIdx.x*256 + threadIdx.x;   // over N_EDGES*8
  if (idx >= N_EDGES*8) return;
  int pos = idx >> 3, kc = idx & 7;
  int e = perm[pos];
  s16x8 c = loadA_f32(&cs[(size_t)e*64 + kc*8]);
  s16x8 p = loadA_f32(&pw[(size_t)e*64 + kc*8]);
  *(s16x8*)&csb[(size_t)pos*64 + kc*8] = c;
  *(s16x8*)&pwb[(size_t)pos*64 + kc*8] = p;
}

// ---------------- prep_weights: W1,W2,W2g,embW -> bf16 [col][k] ----------------
__global__ __launch_bounds__(256) void prep_weights(
    const float* __restrict__ W1, const float* __restrict__ W2, const float* __restrict__ W2g,
    const float* __restrict__ embW,
    unsigned short* __restrict__ w1t, unsigned short* __restrict__ w2t,
    unsigned short* __restrict__ w2gt, unsigned short* __restrict__ embt)
{
  int idx = blockIdx.x*256 + threadIdx.x;
  if (idx < 3*8192) {
    int l = idx / 8192, r = idx % 8192;
    int c = r >> 6, k = r & 63;
    w1t[idx] = f2bf(W1[l*8192 + k*128 + c]);
    w2t[idx] = f2bf(W2[l*8192 + k*128 + c]);
  } else if (idx < 3*8192 + 3*4096) {
    int idx2 = idx - 3*8192;
    int l = idx2 / 4096, r = idx2 % 4096;
    int c = r >> 6, k = r & 63;
    w2gt[idx2] = f2bf(W2g[l*4096 + k*64 + c]);
  } else {
    int idx3 = idx - (3*8192 + 3*4096);
    if (idx3 < 16384) {
      int c = idx3 >> 7, k = idx3 & 127;
      embt[idx3] = f2bf(embW[k*128 + c]);
    }
  }
}

// ---------------- prep_nodew: bf16 [col][k] transposes for node GEMMs ----------------
__global__ __launch_bounds__(256) void prep_nodew(
    const float* __restrict__ Wg, const float* __restrict__ Wm,
    const float* __restrict__ p1, const float* __restrict__ p2, const float* __restrict__ psiW,
    unsigned short* __restrict__ wnt, unsigned short* __restrict__ wpt)
{
  int idx = blockIdx.x*256 + threadIdx.x;
  if (idx < 3*98304) {
    int l = idx / 98304, r = idx % 98304;
    int j = r >> 7, k = r & 127;
    float v;
    if (j < 384) v = Wg[l*49152 + (j>>7)*16384 + k*128 + (j&127)];
    else { int jj = j - 384; v = Wm[l*49152 + (jj>>7)*16384 + k*128 + (jj&127)]; }
    wnt[idx] = f2bf(v);
  } else {
    int idx2 = idx - 3*98304;
    if (idx2 < 3*49152) {
      int l = idx2 / 49152, r = idx2 % 49152;
      int j = r >> 7, k = r & 127;
      float v;
      if (j < 128)      v = p1 [l*16384 + k*128 + j];
      else if (j < 256) v = p2 [l*16384 + k*128 + (j-128)];
      else              v = psiW[l*16384 + k*128 + (j-256)];
      wpt[idx2] = f2bf(v);
    }
  }
}

// ---------------- embed_pack: h = sig(x@embW) + layer-0 pack GEMM, 16 nodes/block ----------------
__global__ __launch_bounds__(256) void embed_pack(
    const float* __restrict__ x, const unsigned short* __restrict__ embt,
    const unsigned short* __restrict__ wnt,
    float* __restrict__ h_out,
    unsigned short* __restrict__ spackb, unsigned short* __restrict__ tpackb)
{
  __shared__ unsigned short hb[16*128];          // 4 KB swizzled bf16 h
  int tid = threadIdx.x, wave = tid >> 6, lane = tid & 63;
  int row = lane & 15, kg = lane >> 4;
  int nbase = blockIdx.x*16;
  const float* xr = &x[(size_t)(nbase + row)*H];
  s16x8 a[4];
  #pragma unroll
  for (int ks = 0; ks < 4; ks++) a[ks] = loadA_f32(xr + ks*32 + kg*8);

  f32x4 acc[2];
  #pragma unroll
  for (int ti = 0; ti < 2; ti++) { acc[ti][0]=0.f; acc[ti][1]=0.f; acc[ti][2]=0.f; acc[ti][3]=0.f; }
  #pragma unroll
  for (int ti = 0; ti < 2; ti++) {
    int col = (wave*2 + ti)*16 + row;
    #pragma unroll
    for (int ks = 0; ks < 4; ks++) {
      s16x8 b = *(const s16x8*)&embt[(size_t)col*128 + ks*32 + kg*8];
      acc[ti] = MFMA16(a[ks], b, acc[ti]);
    }
  }
  #pragma unroll
  for (int ti = 0; ti < 2; ti++) {
    int col = (wave*2 + ti)*16 + row;
    #pragma unroll
    for (int r = 0; r < 4; r++) {
      int ln = kg*4 + r;
      float v = sigf(acc[ti][r]);
      h_out[(size_t)(nbase + ln)*H + col] = v;
      int byt = (ln << 8) + (col << 1);
      byt ^= (ln & 7) << 4;
      *(unsigned short*)((char*)hb + byt) = f2bf(v);
    }
  }
  __syncthreads();

  // pack GEMM from LDS
  s16x8 an[4];
  #pragma unroll
  for (int ks = 0; ks < 4; ks++) {
    int byt = (row << 8) + ks*64 + kg*16;
    byt ^= (row & 7) << 4;
    an[ks] = *(s16x8*)((char*)hb + byt);
  }
  #pragma unroll
  for (int ti = 0; ti < 2; ti++) {
    int t = wave*2 + ti;
    f32x4 pacc[6];
    #pragma unroll
    for (int ch = 0; ch < 6; ch++) { pacc[ch][0]=0.f; pacc[ch][1]=0.f; pacc[ch][2]=0.f; pacc[ch][3]=0.f; }
    #pragma unroll
    for (int ch = 0; ch < 6; ch++) {
      int col = ch*128 + t*16 + row;
      #pragma unroll
      for (int ks = 0; ks < 4; ks++) {
        s16x8 b = *(const s16x8*)&wnt[(size_t)col*128 + ks*32 + kg*8];
        pacc[ch] = MFMA16(an[ks], b, pacc[ch]);
      }
    }
    int c = t*16 + row;
    #pragma unroll
    for (int r = 0; r < 4; r++) {
      int nc = nbase + kg*4 + r;
      size_t base = (size_t)nc*512 + c*4;
      unsigned int s0 = (unsigned int)f2bf(pacc[0][r]) | ((unsigned int)f2bf(pacc[2][r]) << 16);
      unsigned int s1 = (unsigned int)f2bf(pacc[3][r]) | ((unsigned int)f2bf(pacc[5][r]) << 16);
      unsigned int t0 = (unsigned int)f2bf(pacc[1][r]) | ((unsigned int)f2bf(pacc[2][r]) << 16);
      unsigned int t1 = (unsigned int)f2bf(pacc[4][r]) | ((unsigned int)f2bf(pacc[5][r]) << 16);
      *(uint2*)&spackb[base] = make_uint2(s0, s1);
      *(uint2*)&tpackb[base] = make_uint2(t0, t1);
    }
  }
}

// ---------------- fused edge: MFMA z + combine; gate/zb LDS union (17.9 KB) ----------------
__global__ __launch_bounds__(256) void fused_edge(
    float* __restrict__ h_acc,
    const unsigned short* __restrict__ csb, const unsigned short* __restrict__ pwb,
    const unsigned short* __restrict__ w1t, const unsigned short* __restrict__ w2t,
    const unsigned short* __restrict__ w2gt,
    const int* __restrict__ srcp, const int* __restrict__ tgtp,
    const float* __restrict__ edp, const int* __restrict__ nact,
    const unsigned short* __restrict__ spackb, const unsigned short* __restrict__ tpackb)
{
  __shared__ unsigned short zb[64][132];     // 16.9 KB; first 8 KB doubles as gate
  __shared__ int   src_s[64];
  __shared__ int   tgt_s[64];
  __shared__ float rcp_s[64];
  __shared__ float msk_s[64];
  unsigned short* gate = &zb[0][0];

  int p0 = blockIdx.x * 64;
  if (p0 >= *nact) return;                   // fully-masked tail block

  int tid  = threadIdx.x;
  int wave = tid >> 6, lane = tid & 63;
  int row  = lane & 15, kg = lane >> 4;

  if (tid < 64) {
    float r = edp[p0 + tid];
    rcp_s[tid] = 1.0f / r;
    msk_s[tid] = (r < 8.0f) ? 1.0f : 0.0f;
    src_s[tid] = srcp[p0 + tid];
    tgt_s[tid] = tgtp[p0 + tid];
  }

  int pos = p0 + wave*16 + row;
  s16x8 acs[2], apw[2];
  acs[0] = *(const s16x8*)&csb[(size_t)pos*64 + kg*8];
  acs[1] = *(const s16x8*)&csb[(size_t)pos*64 + 32 + kg*8];
  apw[0] = *(const s16x8*)&pwb[(size_t)pos*64 + kg*8];
  apw[1] = *(const s16x8*)&pwb[(size_t)pos*64 + 32 + kg*8];

  // phase A: S1 = pw @ W2g
  f32x4 acc1[4];
  #pragma unroll
  for (int nt = 0; nt < 4; nt++) { acc1[nt][0]=0.f; acc1[nt][1]=0.f; acc1[nt][2]=0.f; acc1[nt][3]=0.f; }
  #pragma unroll
  for (int nt = 0; nt < 4; nt++) {
    s16x8 b0 = *(const s16x8*)&w2gt[(size_t)(nt*16+row)*64 + kg*8];
    s16x8 b1 = *(const s16x8*)&w2gt[(size_t)(nt*16+row)*64 + 32 + kg*8];
    acc1[nt] = MFMA16(apw[0], b0, acc1[nt]);
    acc1[nt] = MFMA16(apw[1], b1, acc1[nt]);
  }

  // sigmoid -> gate LDS (C-layout scatter write, swizzled)
  #pragma unroll
  for (int nt = 0; nt < 4; nt++) {
    #pragma unroll
    for (int r = 0; r < 4; r++) {
      int grow = wave*16 + kg*4 + r;
      int gcol = nt*16 + row;
      int byt = (grow << 7) + (gcol << 1);
      byt ^= (grow & 7) << 4;
      *(unsigned short*)((char*)gate + byt) = f2bf(sigf(acc1[nt][r]));
    }
  }
  __syncthreads();

  // read gate in A-layout, pwg frags = pw * gate
  s16x8 apg[2];
  #pragma unroll
  for (int ks = 0; ks < 2; ks++) {
    int arow = wave*16 + row;
    int byt = (arow << 7) + ks*64 + kg*16;
    byt ^= (arow & 7) << 4;
    s16x8 g = *(s16x8*)((char*)gate + byt);
    s16x8 o;
    #pragma unroll
    for (int j = 0; j < 8; j++) {
      float v = bf2f((unsigned short)apw[ks][j]) * bf2f((unsigned short)g[j]);
      o[j] = (short)f2bf(v);
    }
    apg[ks] = o;
  }
  __syncthreads();   // all waves done reading gate before zb overwrites it

  // phase B: az = cs@W1t + pwg@W2t
  f32x4 acc2[8];
  #pragma unroll
  for (int nt = 0; nt < 8; nt++) { acc2[nt][0]=0.f; acc2[nt][1]=0.f; acc2[nt][2]=0.f; acc2[nt][3]=0.f; }
  #pragma unroll
  for (int nt = 0; nt < 8; nt++) {
    #pragma unroll
    for (int ks = 0; ks < 2; ks++) {
      s16x8 b1 = *(const s16x8*)&w1t[(size_t)(nt*16+row)*64 + ks*32 + kg*8];
      acc2[nt] = MFMA16(acs[ks], b1, acc2[nt]);
      s16x8 b2 = *(const s16x8*)&w2t[(size_t)(nt*16+row)*64 + ks*32 + kg*8];
      acc2[nt] = MFMA16(apg[ks], b2, acc2[nt]);
    }
  }

  // phase C: az -> LDS zb bf16
  #pragma unroll
  for (int nt = 0; nt < 8; nt++) {
    #pragma unroll
    for (int r = 0; r < 4; r++) {
      zb[wave*16 + kg*4 + r][nt*16 + row] = f2bf(acc2[nt][r]);
    }
  }
  __syncthreads();

  // phase D: wave's 16 edges, batches of 4
  {
    int l = lane;
    int e0 = wave*16;
    int cur = src_s[e0];
    s16x8 sp = *(const s16x8*)&spackb[(size_t)cur*512 + l*8];
    float Ags0 = bf2f((unsigned short)sp[0]), Cgs0 = bf2f((unsigned short)sp[1]);
    float Ams0 = bf2f((unsigned short)sp[2]), Cms0 = bf2f((unsigned short)sp[3]);
    float Ags1 = bf2f((unsigned short)sp[4]), Cgs1 = bf2f((unsigned short)sp[5]);
    float Ams1 = bf2f((unsigned short)sp[6]), Cms1 = bf2f((unsigned short)sp[7]);
    float acc0 = 0.f, accB = 0.f;
    for (int eb = e0; eb < e0 + 16; eb += 4) {
      s16x8 tp[4]; unsigned int zz[4];
      #pragma unroll
      for (int b = 0; b < 4; b++) {
        int e = eb + b;
        tp[b] = *(const s16x8*)&tpackb[(size_t)tgt_s[e]*512 + l*8];
        zz[b] = *(const unsigned int*)&zb[e][2*l];
      }
      #pragma unroll
      for (int b = 0; b < 4; b++) {
        int e = eb + b;
        int sn = src_s[e];
        if (sn != cur) {   // wave-uniform (src-sorted)
          atomicAdd(&h_acc[(size_t)cur*H + 2*l],     acc0);
          atomicAdd(&h_acc[(size_t)cur*H + 2*l + 1], accB);
          acc0 = 0.f; accB = 0.f; cur = sn;
          sp = *(const s16x8*)&spackb[(size_t)cur*512 + l*8];
          Ags0 = bf2f((unsigned short)sp[0]); Cgs0 = bf2f((unsigned short)sp[1]);
          Ams0 = bf2f((unsigned short)sp[2]); Cms0 = bf2f((unsigned short)sp[3]);
          Ags1 = bf2f((unsigned short)sp[4]); Cgs1 = bf2f((unsigned short)sp[5]);
          Ams1 = bf2f((unsigned short)sp[6]); Cms1 = bf2f((unsigned short)sp[7]);
        }
        float rc = rcp_s[e], mk = msk_s[e];
        float z0 = bf2f((unsigned short)(zz[b] & 0xffffu));
        float z1 = bf2f((unsigned short)(zz[b] >> 16));
        float Bg0 = bf2f((unsigned short)tp[b][0]), Cg0 = bf2f((unsigned short)tp[b][1]);
        float Bm0 = bf2f((unsigned short)tp[b][2]), Cm0 = bf2f((unsigned short)tp[b][3]);
        float Bg1 = bf2f((unsigned short)tp[b][4]), Cg1 = bf2f((unsigned short)tp[b][5]);
        float Bm1 = bf2f((unsigned short)tp[b][6]), Cm1 = bf2f((unsigned short)tp[b][7]);
        float g0 = sigf(Ags0 + Bg0 + rc*(Cgs0 - Cg0));
        float m0 = eluf(Ams0 + Bm0 + rc*(Cms0 - Cm0));
        acc0 += g0 * m0 * z0 * mk;
        float g1 = sigf(Ags1 + Bg1 + rc*(Cgs1 - Cg1));
        float m1 = eluf(Ams1 + Bm1 + rc*(Cms1 - Cm1));
        accB += g1 * m1 * z1 * mk;
      }
    }
    atomicAdd(&h_acc[(size_t)cur*H + 2*l],     acc0);
    atomicAdd(&h_acc[(size_t)cur*H + 2*l + 1], accB);
  }
}

// ---------------- node_next: 16 nodes/block; psi/pool GEMMs + next-layer pack GEMM ----------------
__global__ __launch_bounds__(256) void node_next(
    float* __restrict__ h,                       // in/out (in-place update)
    const unsigned short* __restrict__ wpt,      // this layer p1/p2/psi
    const unsigned short* __restrict__ wnt,      // NEXT layer Wg/Wm
    const int* __restrict__ gidx, float* __restrict__ pooled,
    unsigned short* __restrict__ spackb, unsigned short* __restrict__ tpackb,
    int has_next)
{
  __shared__ unsigned short hb[16*128];          // 4 KB swizzled bf16 h_next
  int tid = threadIdx.x, wave = tid >> 6, lane = tid & 63;
  int row = lane & 15, kg = lane >> 4;
  int nbase = blockIdx.x*16;
  const float* hr = &h[(size_t)(nbase + row)*H];
  s16x8 a[4];
  #pragma unroll
  for (int ks = 0; ks < 4; ks++) a[ks] = loadA_f32(hr + ks*32 + kg*8);

  f32x4 acc1[2], acc2[2], acc3[2];
  #pragma unroll
  for (int ti = 0; ti < 2; ti++) {
    #pragma unroll
    for (int r = 0; r < 4; r++) { acc1[ti][r]=0.f; acc2[ti][r]=0.f; acc3[ti][r]=0.f; }
  }
  #pragma unroll
  for (int ti = 0; ti < 2; ti++) {
    int col = (wave*2 + ti)*16 + row;
    #pragma unroll
    for (int ks = 0; ks < 4; ks++) {
      s16x8 b1 = *(const s16x8*)&wpt[(size_t)(col      )*128 + ks*32 + kg*8];
      s16x8 b2 = *(const s16x8*)&wpt[(size_t)(col + 128)*128 + ks*32 + kg*8];
      s16x8 b3 = *(const s16x8*)&wpt[(size_t)(col + 256)*128 + ks*32 + kg*8];
      acc1[ti] = MFMA16(a[ks], b1, acc1[ti]);
      acc2[ti] = MFMA16(a[ks], b2, acc2[ti]);
      acc3[ti] = MFMA16(a[ks], b3, acc3[ti]);
    }
  }

  int nc0 = nbase + kg*4;
  int g0 = gidx[nc0], g3 = gidx[nc0 + 3];
  if (g0 == g3) {
    #pragma unroll
    for (int ti = 0; ti < 2; ti++) {
      int col = (wave*2 + ti)*16 + row;
      float s = 0.f;
      #pragma unroll
      for (int r = 0; r < 4; r++) s += eluf(acc1[ti][r] * acc2[ti][r]);
      atomicAdd(&pooled[g0*H + col], s);
      #pragma unroll
      for (int r = 0; r < 4; r++) {
        int ln = kg*4 + r;
        float v = eluf(acc3[ti][r]);
        h[(size_t)(nc0 + r)*H + col] = v;
        int byt = (ln << 8) + (col << 1);
        byt ^= (ln & 7) << 4;
        *(unsigned short*)((char*)hb + byt) = f2bf(v);
      }
    }
  } else {
    #pragma unroll
    for (int r = 0; r < 4; r++) {
      int nc = nc0 + r;
      int ln = kg*4 + r;
      int g = gidx[nc];
      #pragma unroll
      for (int ti = 0; ti < 2; ti++) {
        int col = (wave*2 + ti)*16 + row;
        float zp = eluf(acc1[ti][r] * acc2[ti][r]);
        atomicAdd(&pooled[g*H + col], zp);
        float v = eluf(acc3[ti][r]);
        h[(size_t)nc*H + col] = v;
        int byt = (ln << 8) + (col << 1);
        byt ^= (ln & 7) << 4;
        *(unsigned short*)((char*)hb + byt) = f2bf(v);
      }
    }
  }
  if (!has_next) return;
  __syncthreads();

  // pack GEMM from LDS h_next; 8B coalesced pack stores
  s16x8 an[4];
  #pragma unroll
  for (int ks = 0; ks < 4; ks++) {
    int byt = (row << 8) + ks*64 + kg*16;
    byt ^= (row & 7) << 4;
    an[ks] = *(s16x8*)((char*)hb + byt);
  }
  #pragma unroll
  for (int ti = 0; ti < 2; ti++) {
    int t = wave*2 + ti;
    f32x4 pacc[6];
    #pragma unroll
    for (int ch = 0; ch < 6; ch++) { pacc[ch][0]=0.f; pacc[ch][1]=0.f; pacc[ch][2]=0.f; pacc[ch][3]=0.f; }
    #pragma unroll
    for (int ch = 0; ch < 6; ch++) {
      int col = ch*128 + t*16 + row;
      #pragma unroll
      for (int ks = 0; ks < 4; ks++) {
        s16x8 b = *(const s16x8*)&wnt[(size_t)col*128 + ks*32 + kg*8];
        pacc[ch] = MFMA16(an[ks], b, pacc[ch]);
      }
    }
    int c = t*16 + row;
    #pragma unroll
    for (int r = 0; r < 4; r++) {
      int nc = nbase + kg*4 + r;
      size_t base = (size_t)nc*512 + c*4;
      unsigned int s0 = (unsigned int)f2bf(pacc[0][r]) | ((unsigned int)f2bf(pacc[2][r]) << 16);
      unsigned int s1 = (unsigned int)f2bf(pacc[3][r]) | ((unsigned int)f2bf(pacc[5][r]) << 16);
      unsigned int t0 = (unsigned int)f2bf(pacc[1][r]) | ((unsigned int)f2bf(pacc[2][r]) << 16);
      unsigned int t1 = (unsigned int)f2bf(pacc[4][r]) | ((unsigned int)f2bf(pacc[5][r]) << 16);
      *(uint2*)&spackb[base] = make_uint2(s0, s1);
      *(uint2*)&tpackb[base] = make_uint2(t0, t1);
    }
  }
}

// ---------------- final: y = elu(elu(pooled @ lr1) @ lr2) ----------------
__global__ __launch_bounds__(64) void final_kernel(
    const float* __restrict__ pooled, const float* __restrict__ lr1, const float* __restrict__ lr2,
    float* __restrict__ out)
{
  __shared__ float sp[128];
  __shared__ float y1[64];
  int g = blockIdx.x, tid = threadIdx.x;
  sp[tid]      = pooled[g*128 + tid];
  sp[tid + 64] = pooled[g*128 + 64 + tid];
  __syncthreads();
  float acc = 0.f;
  for (int k = 0; k < 128; k++) acc += sp[k] * lr1[k*64 + tid];
  y1[tid] = eluf(acc);
  __syncthreads();
  if (tid < 32) {
    float a2 = 0.f;
    for (int k = 0; k < 64; k++) a2 += y1[k] * lr2[k*32 + tid];
    out[g*32 + tid] = eluf(a2);
  }
}

extern "C" void kernel_launch(void* const* d_in, const int* in_sizes, int n_in,
                              void* d_out, int out_size, void* d_ws, size_t ws_size,
                              hipStream_t stream)
{
  const float* x    = (const float*)d_in[0];
  const float* ed   = (const float*)d_in[1];
  const float* cs   = (const float*)d_in[2];
  const float* pw   = (const float*)d_in[3];
  const float* embW = (const float*)d_in[4];
  const float* Wg   = (const float*)d_in[5];
  const float* Wm   = (const float*)d_in[6];
  const float* W1   = (const float*)d_in[7];
  const float* W2g  = (const float*)d_in[8];
  const float* W2   = (const float*)d_in[9];
  const float* p1   = (const float*)d_in[10];
  const float* p2   = (const float*)d_in[11];
  const float* psiW = (const float*)d_in[12];
  const float* lr1  = (const float*)d_in[13];
  const float* lr2  = (const float*)d_in[14];
  const int* esrc   = (const int*)d_in[15];
  const int* etgt   = (const int*)d_in[16];
  const int* gidx   = (const int*)d_in[17];

  float* h_b    = (float*)d_ws;                 // 1,280,000 f
  float* pooled = h_b + (size_t)N_NODES*H;      // 12,800 f
  unsigned short* spackb = (unsigned short*)(pooled + 100*H); // N_NODES*512 us
  unsigned short* tpackb = spackb + (size_t)N_NODES*512;      // N_NODES*512 us
  int* counts  = (int*)(tpackb + (size_t)N_NODES*512);
  int* offsets = counts + N_NODES;              // N_NODES+1 (offsets[N_NODES] = n_active)
  int* cursor  = offsets + N_NODES + 1;
  int* mcur    = cursor + N_NODES;              // 1
  int* perm    = mcur + 1;                      // N_EDGES
  int* srcp    = perm + N_EDGES;                // N_EDGES
  int* tgtp    = srcp + N_EDGES;                // N_EDGES
  float* edp   = (float*)(tgtp + N_EDGES);      // N_EDGES
  unsigned short* w1t  = (unsigned short*)(edp + N_EDGES); // 3*8192
  unsigned short* w2t  = w1t + 3*8192;
  unsigned short* w2gt = w2t + 3*8192;          // 3*4096
  unsigned short* embt = w2gt + 3*4096;         // 16384
  unsigned short* wnt  = embt + 16384;          // 3*98304
  unsigned short* wpt  = wnt + 3*98304;         // 3*49152
  unsigned short* csb  = wpt + 3*49152;         // N_EDGES*64
  unsigned short* pwb  = csb + (size_t)N_EDGES*64; // N_EDGES*64

  // one-time: edge sort by (masked, src) + de-indirect + bf16 conversions
  hipMemsetAsync(counts, 0, N_NODES*sizeof(int), stream);
  hipMemsetAsync(mcur, 0, sizeof(int), stream);
  hipMemsetAsync(pooled, 0, 100*H*sizeof(float), stream);
  hist_kernel<<<(N_EDGES+255)/256, 256, 0, stream>>>(esrc, ed, counts);
  scan_kernel<<<1, 256, 0, stream>>>(counts, offsets);
  hipMemcpyAsync(cursor, offsets, N_NODES*sizeof(int), hipMemcpyDeviceToDevice, stream);
  scatter_kernel<<<(N_EDGES+255)/256, 256, 0, stream>>>(esrc, etgt, ed, offsets,
      cursor, mcur, perm, srcp, tgtp, edp);
  prep_edges<<<N_EDGES*8/256, 256, 0, stream>>>(cs, pw, perm, csb, pwb);
  prep_weights<<<208, 256, 0, stream>>>(W1, W2, W2g, embW, w1t, w2t, w2gt, embt);
  prep_nodew<<<(3*98304 + 3*49152 + 255)/256, 256, 0, stream>>>(Wg, Wm, p1, p2, psiW, wnt, wpt);

  embed_pack<<<N_NODES/16, 256, 0, stream>>>(x, embt, wnt, h_b, spackb, tpackb);

  for (int i = 0; i < 3; i++) {
    fused_edge<<<N_EDGES/64, 256, 0, stream>>>(h_b, csb, pwb,
        w1t + i*8192, w2t + i*8192, w2gt + i*4096,
        srcp, tgtp, edp, offsets + N_NODES, spackb, tpackb);
    node_next<<<N_NODES/16, 256, 0, stream>>>(h_b,
        wpt + i*49152, wnt + ((i+1) % 3)*98304,
        gidx, pooled, spackb, tpackb, (i < 2) ? 1 : 0);
  }
  final_kernel<<<100, 64, 0, stream>>>(pooled, lr1, lr2, (float*)d_out);
}